// Round 11
// baseline (326.290 us; speedup 1.0000x reference)
//
#include <hip/hip_runtime.h>
#include <cstdint>
#include <cstddef>

// Problem constants (fixed by the reference)
#define B_  2
#define T_  1024
#define C_  2048
#define H_  32
#define BT_ (B_*T_)
static constexpr float EPS_GN = 1e-5f * 64.0f;

using short8 = __attribute__((ext_vector_type(8))) short;
using f32x4  = __attribute__((ext_vector_type(4))) float;
typedef unsigned short bfu16;

__device__ __forceinline__ bfu16 f2b(float f) {
  uint32_t x = __float_as_uint(f);
  uint32_t r = (x + 0x7FFFu + ((x >> 16) & 1u)) >> 16;
  return (bfu16)r;
}
__device__ __forceinline__ float b2f(bfu16 h) {
  return __uint_as_float(((uint32_t)h) << 16);
}

__device__ __forceinline__ void gload16(const bfu16* g, bfu16* l) {
  __builtin_amdgcn_global_load_lds((__attribute__((address_space(1))) void*)g,
                                   (__attribute__((address_space(3))) void*)l,
                                   16, 0, 0);
}

// ---------------------------------------------------------------------------
// gemm256 (round-7 proven schedule, FROZEN): 256x256 tile, BK=64, 512 thr
// (8 waves 2Mx4N), dbuf LDS 128KB. STAGE_A(next); vmcnt(4); barrier; per-ks
// {STAGE_B(next) at ks==1; ds_read frags; MFMA}; barrier.
// LDS XOR-swizzle: source col ^((row&7)<<3), read col ^((lane&7)<<3).
// XCD-aware bijective block swizzle (nwg % 8 == 0 required).
// kSplit==1: batched over z (A=aArr[z], Bt+=z*bStr, out+=z*oStr).
// kSplit>1 : z = K-chunk of A/Bt (out+=z*oStr, f32 partials).
// ---------------------------------------------------------------------------
struct G256P {
  const bfu16* Bt; float* of;
  size_t bStr, oStr;
  int ldk, nkt, kSplit;
  const bfu16* aArr[4];
};

__global__ __launch_bounds__(512, 2)
void gemm256(G256P p)
{
  extern __shared__ __align__(16) bfu16 sm[];   // A0,A1,B0,B1 each 256*64
  const int tid  = threadIdx.x;
  const int nwg = gridDim.x * gridDim.y * gridDim.z;
  int lin = blockIdx.x + gridDim.x * (blockIdx.y + gridDim.y * blockIdx.z);
  lin = (lin & 7) * (nwg >> 3) + (lin >> 3);
  const int bx = lin % gridDim.x;
  const int by = (lin / gridDim.x) % gridDim.y;
  const int z  = lin / (gridDim.x * gridDim.y);
  const int m0   = by * 256, n0 = bx * 256;
  const int lane = tid & 63;
  const int wv   = tid >> 6;
  const int wm   = wv >> 2, wn = wv & 3;
  const int ldk  = p.ldk;

  const bfu16* A;
  size_t koff;
  if (p.kSplit > 1) { A = p.aArr[0]; koff = (size_t)z * p.nkt * 64; }
  else              { A = p.aArr[z]; koff = 0; }
  const bfu16* Bt = p.Bt + (size_t)z * p.bStr;

  const int srow = tid >> 3;        // 0..63
  const int scol = (tid & 7) * 8;   // 0..56
  const int sswz = (srow & 7) << 3; // source-side inverse swizzle
  const bfu16* gA = A  + (size_t)(m0 + srow) * ldk + koff + (scol ^ sswz);
  const bfu16* gB = Bt + (size_t)(n0 + srow) * ldk + koff + (scol ^ sswz);

  auto STAGE_A = [&](bfu16* dst, int kt) {
    const bfu16* g = gA + (size_t)kt * 64;
    bfu16* l = dst + srow * 64 + scol;
#pragma unroll
    for (int it = 0; it < 4; ++it)
      gload16(g + (size_t)it * 64 * ldk, l + it * 4096);
  };
  auto STAGE_B = [&](bfu16* dst, int kt) {
    const bfu16* g = gB + (size_t)kt * 64;
    bfu16* l = dst + srow * 64 + scol;
#pragma unroll
    for (int it = 0; it < 4; ++it)
      gload16(g + (size_t)it * 64 * ldk, l + it * 4096);
  };

  f32x4 acc[8][4];
  const f32x4 zero = {0.f, 0.f, 0.f, 0.f};
#pragma unroll
  for (int i = 0; i < 8; ++i)
#pragma unroll
    for (int j = 0; j < 4; ++j) acc[i][j] = zero;

  STAGE_A(sm, 0);
  STAGE_B(sm + 32768, 0);           // 8 outstanding

  const int rswz = (lane & 7) << 3; // read-side swizzle

  for (int kt = 0; kt < p.nkt; ++kt) {
    bfu16* curA = sm + (kt & 1) * 16384;
    bfu16* curB = sm + 32768 + (kt & 1) * 16384;
    bfu16* nxtA = sm + ((kt & 1) ^ 1) * 16384;
    bfu16* nxtB = sm + 32768 + ((kt & 1) ^ 1) * 16384;
    const bool more = (kt + 1 < p.nkt);
    if (more) {
      STAGE_A(nxtA, kt + 1);                       // 12 outstanding
      asm volatile("s_waitcnt vmcnt(4)" ::: "memory");  // cur buf landed
    } else {
      asm volatile("s_waitcnt vmcnt(0)" ::: "memory");
    }
    __builtin_amdgcn_s_barrier();

#pragma unroll
    for (int ks = 0; ks < 2; ++ks) {
      if (ks == 1 && more) STAGE_B(nxtB, kt + 1);
      const int ko = (ks * 32 + (lane >> 4) * 8) ^ rswz;
      short8 a[8], b[4];
#pragma unroll
      for (int i = 0; i < 8; ++i)
        a[i] = *(const short8*)(curA + (wm * 128 + i * 16 + (lane & 15)) * 64 + ko);
#pragma unroll
      for (int j = 0; j < 4; ++j)
        b[j] = *(const short8*)(curB + (wn * 64 + j * 16 + (lane & 15)) * 64 + ko);
      __builtin_amdgcn_s_setprio(1);
#pragma unroll
      for (int i = 0; i < 8; ++i)
#pragma unroll
        for (int j = 0; j < 4; ++j)
          acc[i][j] = __builtin_amdgcn_mfma_f32_16x16x32_bf16(a[i], b[j], acc[i][j], 0, 0, 0);
      __builtin_amdgcn_s_setprio(0);
    }
    __builtin_amdgcn_s_barrier();
  }

  float* o = p.of + (size_t)z * p.oStr;
  const int cb = n0 + wn * 64 + (lane & 15);
  const int rb = m0 + wm * 128 + ((lane >> 4) << 2);
#pragma unroll
  for (int i = 0; i < 8; ++i)
#pragma unroll
    for (int j = 0; j < 4; ++j) {
      int col = cb + j * 16;
#pragma unroll
      for (int q = 0; q < 4; ++q)
        o[(size_t)(rb + i * 16 + q) * 2048 + col] = acc[i][j][q];
    }
}

// ---------------------------------------------------------------------------
// 128x128 GEMM for the small/odd shapes.
// MODE 4: of = -exp(vArr[0][col] + acc)   (fused lw = -exp(w))
// MODE 5: split-K partials
// ---------------------------------------------------------------------------
struct GemmP {
  const bfu16* A; const bfu16* Bt;
  float* of; bfu16* ob;
  const bfu16* xh; const bfu16* xxh;
  int ldk, kIters, kChunk, ldo;
  size_t pStride, aStr, bStr, oStr;
  const float* vArr[5];
};

template<int MODE>
__global__ __launch_bounds__(256)
void gemm_k(GemmP p)
{
  __shared__ alignas(16) bfu16 As[128*64];
  __shared__ alignas(16) bfu16 Bs[128*64];
  const int tid  = threadIdx.x;
  const int z    = blockIdx.z;
  const int m0   = blockIdx.y * 128, n0 = blockIdx.x * 128;
  const int lane = tid & 63;
  const int wv   = tid >> 6;
  const int wr   = (wv >> 1) * 64, wc = (wv & 1) * 64;

  const bfu16* A  = p.A;
  const bfu16* Bt = p.Bt;
  size_t koff = 0;
  if constexpr (MODE == 5) { koff = (size_t)z * p.kChunk; }

  f32x4 acc[4][4];
  const f32x4 zero = {0.f, 0.f, 0.f, 0.f};
#pragma unroll
  for (int i = 0; i < 4; ++i)
#pragma unroll
    for (int j = 0; j < 4; ++j) acc[i][j] = zero;

  const int srow = tid >> 3;
  const int scol = (tid & 7) * 8;
  const int ldk  = p.ldk;

  for (int kb = 0; kb < p.kIters; ++kb) {
    const bfu16* ga = A  + (size_t)m0 * ldk + koff + kb * 64;
    const bfu16* gb = Bt + (size_t)n0 * ldk + koff + kb * 64;
#pragma unroll
    for (int it = 0; it < 4; ++it) {
      int r = it * 32 + srow;
      gload16(ga + (size_t)r * ldk + scol, As + r * 64 + scol);
      gload16(gb + (size_t)r * ldk + scol, Bs + r * 64 + scol);
    }
    __syncthreads();
#pragma unroll
    for (int kk = 0; kk < 2; ++kk) {
      const int ko = kk * 32 + (lane >> 4) * 8;
      short8 a[4], b[4];
#pragma unroll
      for (int i = 0; i < 4; ++i)
        a[i] = *(const short8*)(As + (wr + i * 16 + (lane & 15)) * 64 + ko);
#pragma unroll
      for (int j = 0; j < 4; ++j)
        b[j] = *(const short8*)(Bs + (wc + j * 16 + (lane & 15)) * 64 + ko);
#pragma unroll
      for (int i = 0; i < 4; ++i)
#pragma unroll
        for (int j = 0; j < 4; ++j)
          acc[i][j] = __builtin_amdgcn_mfma_f32_16x16x32_bf16(a[i], b[j], acc[i][j], 0, 0, 0);
    }
    __syncthreads();
  }

  const int cb = n0 + wc + (lane & 15);
  const int rb = m0 + wr + ((lane >> 4) << 2);
#pragma unroll
  for (int i = 0; i < 4; ++i) {
#pragma unroll
    for (int j = 0; j < 4; ++j) {
      int col = cb + j * 16;
#pragma unroll
      for (int q = 0; q < 4; ++q) {
        int row = rb + i * 16 + q;
        float v = acc[i][j][q];
        if constexpr (MODE == 4) {
          p.of[(size_t)row * p.ldo + col] = -__expf(p.vArr[0][col] + v);
        } else if constexpr (MODE == 5) {
          p.of[(size_t)z * p.pStride + (size_t)row * p.ldo + col] = v;
        }
      }
    }
  }
}

// ---------------------------------------------------------------------------
// Token-mix GEMM, fused over the 5 mix-factors f (one launch, 256 blocks):
// per block, loop f: stage mtan[f]/w2T[f] tiles, MFMA, epilogue
// xmix[f] = bf16(xh + xxh*(maa_f + acc)). xh/xxh tile re-reads hit L1/L2.
// ---------------------------------------------------------------------------
__global__ __launch_bounds__(256)
void gemm_tm(GemmP p)
{
  __shared__ alignas(16) bfu16 As[128*64];
  __shared__ alignas(16) bfu16 Bs[128*64];
  const int tid  = threadIdx.x;
  const int m0   = blockIdx.y * 128, n0 = blockIdx.x * 128;
  const int lane = tid & 63;
  const int wv   = tid >> 6;
  const int wr   = (wv >> 1) * 64, wc = (wv & 1) * 64;
  const int srow = tid >> 3;
  const int scol = (tid & 7) * 8;

  const int cb = n0 + wc + (lane & 15);
  const int rb = m0 + wr + ((lane >> 4) << 2);

  for (int f = 0; f < 5; ++f) {
    const bfu16* A  = p.A  + (size_t)f * p.aStr;
    const bfu16* Bt = p.Bt + (size_t)f * p.bStr;
    if (f) __syncthreads();            // all waves done reading prev tiles
#pragma unroll
    for (int it = 0; it < 4; ++it) {
      int r = it * 32 + srow;
      gload16(A  + (size_t)(m0 + r) * 64 + scol, As + r * 64 + scol);
      gload16(Bt + (size_t)(n0 + r) * 64 + scol, Bs + r * 64 + scol);
    }
    __syncthreads();                   // vmcnt(0) drained by compiler

    f32x4 acc[4][4];
    const f32x4 zero = {0.f, 0.f, 0.f, 0.f};
#pragma unroll
    for (int i = 0; i < 4; ++i)
#pragma unroll
      for (int j = 0; j < 4; ++j) acc[i][j] = zero;
#pragma unroll
    for (int kk = 0; kk < 2; ++kk) {
      const int ko = kk * 32 + (lane >> 4) * 8;
      short8 a[4], b[4];
#pragma unroll
      for (int i = 0; i < 4; ++i)
        a[i] = *(const short8*)(As + (wr + i * 16 + (lane & 15)) * 64 + ko);
#pragma unroll
      for (int j = 0; j < 4; ++j)
        b[j] = *(const short8*)(Bs + (wc + j * 16 + (lane & 15)) * 64 + ko);
#pragma unroll
      for (int i = 0; i < 4; ++i)
#pragma unroll
        for (int j = 0; j < 4; ++j)
          acc[i][j] = __builtin_amdgcn_mfma_f32_16x16x32_bf16(a[i], b[j], acc[i][j], 0, 0, 0);
    }

    bfu16* ob = p.ob + (size_t)f * p.oStr;
    const float* maa = p.vArr[f];
#pragma unroll
    for (int i = 0; i < 4; ++i)
#pragma unroll
      for (int j = 0; j < 4; ++j) {
        int col = cb + j * 16;
#pragma unroll
        for (int q = 0; q < 4; ++q) {
          int row = rb + i * 16 + q;
          size_t idx = (size_t)row * C_ + col;
          ob[idx] = f2b(b2f(p.xh[idx]) + b2f(p.xxh[idx]) * (maa[col] + acc[i][j][q]));
        }
      }
  }
}

// ---------------------------------------------------------------------------
// split-K reduce + tanh -> bf16.  OUT=0: mtan scatter [f][row][d]; OUT=1: wtan.
// NS = number of K-chunks to sum.
// ---------------------------------------------------------------------------
template<int OUT, int NS>
__global__ __launch_bounds__(256)
void redk_tanh(const float* __restrict__ part, size_t pStr, int ldo, int ncols,
               bfu16* __restrict__ out)
{
  int id = blockIdx.x * 256 + threadIdx.x;
  int row = id / ncols, col = id % ncols;
  if (row >= BT_) return;
  float v = 0.f;
#pragma unroll
  for (int s = 0; s < NS; ++s) v += part[(size_t)s * pStr + (size_t)row * ldo + col];
  bfu16 tv = f2b(tanhf(v));
  if constexpr (OUT == 0)
    out[((size_t)(col >> 5) * BT_ + row) * 64 + (col & 31)] = tv;
  else
    out[(size_t)row * 64 + col] = tv;
}

__global__ __launch_bounds__(256)
void redk_sum4(const float* __restrict__ p0, float* __restrict__ out)
{
  size_t i = ((size_t)blockIdx.x * 256 + threadIdx.x) * 4;
  const size_t str = (size_t)2048 * 2048;
  float4 a = *(const float4*)(p0 + i);
  float4 b = *(const float4*)(p0 + str + i);
  float4 c = *(const float4*)(p0 + 2 * str + i);
  float4 d = *(const float4*)(p0 + 3 * str + i);
  a.x += b.x + c.x + d.x; a.y += b.y + c.y + d.y;
  a.z += b.z + c.z + d.z; a.w += b.w + c.w + d.w;
  *(float4*)(out + i) = a;
}

// ---------------------------------------------------------------------------
// f32 [R][Cc] -> bf16 dst[c*ldd + r], batched over z. Rows [R,Rpad) zeroed.
// Write phase vectorized: each thread packs 2 consecutive r into one u32.
// (Requires 32-aligned Rpad/ldd even — true for all uses.)
// ---------------------------------------------------------------------------
struct TrP { const float* src[5]; bfu16* dst; size_t dStr; int R, Cc, Rpad, ldd; };

__global__ __launch_bounds__(256)
void transpose_k(TrP p)
{
  __shared__ float tile[32][33];
  const float* src = p.src[blockIdx.z];
  bfu16* dst = p.dst + (size_t)blockIdx.z * p.dStr;
  const int tx = threadIdx.x & 31, ty = threadIdx.x >> 5;
  const int r0 = blockIdx.y * 32, c0 = blockIdx.x * 32;
#pragma unroll
  for (int i = 0; i < 4; ++i) {
    int r = r0 + ty + i * 8, c = c0 + tx;
    tile[ty + i * 8][tx] = (r < p.R && c < p.Cc) ? src[(size_t)r * p.Cc + c] : 0.f;
  }
  __syncthreads();
  const int cl  = threadIdx.x >> 4;        // 0..15
  const int rp2 = (threadIdx.x & 15) * 2;  // 0,2,..,30
#pragma unroll
  for (int pass = 0; pass < 2; ++pass) {
    int c = c0 + cl + pass * 16;
    int r = r0 + rp2;
    if (c < p.Cc && r < p.Rpad) {
      uint32_t val = (uint32_t)f2b(tile[rp2][cl + pass * 16])
                   | ((uint32_t)f2b(tile[rp2 + 1][cl + pass * 16]) << 16);
      *(uint32_t*)(dst + (size_t)c * p.ldd + r) = val;
    }
  }
}

// ---------------------------------------------------------------------------
// xx = shift(x) - x (bf16) ; xxx = bf16(x + xx*maa_x) ; xh = bf16(x)
// ---------------------------------------------------------------------------
__global__ __launch_bounds__(256)
void prep_xx(const float* __restrict__ x, const float* __restrict__ maa_x,
             bfu16* __restrict__ xxh, bfu16* __restrict__ xxx,
             bfu16* __restrict__ xh)
{
  size_t i = ((size_t)blockIdx.x * 256 + threadIdx.x) * 4;
  int c  = (int)(i & (C_ - 1));
  int bt = (int)(i >> 11);
  int t  = bt & (T_ - 1);
  float4 xv = *(const float4*)(x + i);
  float4 xp = {0.f, 0.f, 0.f, 0.f};
  if (t > 0) xp = *(const float4*)(x + i - C_);
  float4 mx = *(const float4*)(maa_x + c);
  float dx = xp.x - xv.x, dy = xp.y - xv.y, dz = xp.z - xv.z, dw = xp.w - xv.w;
  uint2 w0;
  w0.x = (uint32_t)f2b(dx) | ((uint32_t)f2b(dy) << 16);
  w0.y = (uint32_t)f2b(dz) | ((uint32_t)f2b(dw) << 16);
  *(uint2*)(xxh + i) = w0;
  uint2 w1;
  w1.x = (uint32_t)f2b(xv.x + dx * mx.x) | ((uint32_t)f2b(xv.y + dy * mx.y) << 16);
  w1.y = (uint32_t)f2b(xv.z + dz * mx.z) | ((uint32_t)f2b(xv.w + dw * mx.w) << 16);
  *(uint2*)(xxx + i) = w1;
  uint2 w2;
  w2.x = (uint32_t)f2b(xv.x) | ((uint32_t)f2b(xv.y) << 16);
  w2.y = (uint32_t)f2b(xv.z) | ((uint32_t)f2b(xv.w) << 16);
  *(uint2*)(xh + i) = w2;
}

// ---------------------------------------------------------------------------
// WKV6 chunked scan, chunk L=32. w input is ALREADY lw = -exp(w).
// ---------------------------------------------------------------------------
#define S32 68   // LDS row stride (floats) for 32-row tiles

__global__ __launch_bounds__(256)
void wkv_a32(const float* __restrict__ r, const float* __restrict__ k,
             const float* __restrict__ v, const float* __restrict__ w,
             const float* __restrict__ u, float* __restrict__ rp,
             float* __restrict__ y, float* __restrict__ U, float* __restrict__ G)
{
  __shared__ float rw[32 * S32];
  __shared__ float kk[32 * S32];
  __shared__ float vv[32 * S32];
  __shared__ float Ps[32 * S32];
  __shared__ float red[256];
  __shared__ float diag[32];
  __shared__ float Gl[64];

  const int blk = blockIdx.x;
  const int bh = blk >> 5, c = blk & 31;
  const int b = bh >> 5, h = bh & 31;
  const int tid = threadIdx.x;
  const size_t gbase = ((size_t)(b * T_ + c * 32)) * C_ + h * 64;

  {
    const int t = tid >> 3, q = tid & 7;
    const size_t g = gbase + (size_t)t * C_ + q * 8;
    const int l = t * S32 + q * 8;
    *(float4*)(rw + l)     = *(const float4*)(r + g);
    *(float4*)(rw + l + 4) = *(const float4*)(r + g + 4);
    *(float4*)(kk + l)     = *(const float4*)(k + g);
    *(float4*)(kk + l + 4) = *(const float4*)(k + g + 4);
    *(float4*)(vv + l)     = *(const float4*)(v + g);
    *(float4*)(vv + l + 4) = *(const float4*)(v + g + 4);
    *(float4*)(Ps + l)     = *(const float4*)(w + g);
    *(float4*)(Ps + l + 4) = *(const float4*)(w + g + 4);
  }
  __syncthreads();

  // segmented prefix over t (4 segments of 8), per-j
  {
    const int seg = tid >> 6, j = tid & 63;
    float loc = 0.f;
#pragma unroll
    for (int tt = 0; tt < 8; ++tt) loc += Ps[(seg * 8 + tt) * S32 + j];
    red[seg * 64 + j] = loc;
  }
  __syncthreads();
  {
    const int seg = tid >> 6, j = tid & 63;
    float cs = 0.f;
    for (int s = 0; s < seg; ++s) cs += red[s * 64 + j];
    const float uj = u[h * 64 + j];
#pragma unroll
    for (int tt = 0; tt < 8; ++tt) {
      const int a = (seg * 8 + tt) * S32 + j;
      float lw = Ps[a];
      float rv = rw[a] * __expf(cs);
      rw[a] = rv;
      cs += lw;
      float kv = kk[a] * __expf(-cs);
      kk[a] = kv;
      Ps[a] = rv * kv * uj * __expf(lw);   // D (exact)
    }
    if (seg == 3) {
      float Gj = __expf(cs);
      Gl[j] = Gj;
      G[((size_t)bh * 32 + c) * 64 + j] = Gj;
    }
  }
  __syncthreads();

  // diag[t] = sum_j D[t][j]
  {
    const int t = tid & 31, q = tid >> 5;
    float s = 0.f;
#pragma unroll
    for (int jj = 0; jj < 8; ++jj) s += Ps[t * S32 + q * 8 + jj];
    red[q * 32 + t] = s;
  }
  __syncthreads();
  if (tid < 32) {
    float d = 0.f;
#pragma unroll
    for (int q = 0; q < 8; ++q) d += red[q * 32 + tid];
    diag[tid] = d;
  }
  __syncthreads();

  // scores: 2x2 tiles over 16x16 thread grid, lower-tri
  {
    const int tq = tid >> 4, sq = tid & 15;
    float a00 = 0.f, a01 = 0.f, a10 = 0.f, a11 = 0.f;
    if (sq <= tq) {
      for (int j = 0; j < 64; j += 4) {
        float4 r0 = *(const float4*)(rw + (2 * tq + 0) * S32 + j);
        float4 r1 = *(const float4*)(rw + (2 * tq + 1) * S32 + j);
        float4 k0 = *(const float4*)(kk + (2 * sq + 0) * S32 + j);
        float4 k1 = *(const float4*)(kk + (2 * sq + 1) * S32 + j);
        a00 += r0.x * k0.x + r0.y * k0.y + r0.z * k0.z + r0.w * k0.w;
        a01 += r0.x * k1.x + r0.y * k1.y + r0.z * k1.z + r0.w * k1.w;
        a10 += r1.x * k0.x + r1.y * k0.y + r1.z * k0.z + r1.w * k0.w;
        a11 += r1.x * k1.x + r1.y * k1.y + r1.z * k1.z + r1.w * k1.w;
      }
    }
    __syncthreads();
    if (sq <= tq) {
      const float av[2][2] = {{a00, a01}, {a10, a11}};
#pragma unroll
      for (int tt = 0; tt < 2; ++tt)
#pragma unroll
        for (int ss = 0; ss < 2; ++ss) {
          int t = 2 * tq + tt, s = 2 * sq + ss;
          Ps[t * S32 + s] = (s < t) ? av[tt][ss] : (s == t ? diag[t] : 0.f);
        }
    }
  }
  __syncthreads();

  // O_intra[t][i] = sum_{s<=t} P[t][s] * v[s][i]  -> y
  {
    const int tq = tid >> 4, iq = tid & 15;
    float o0[4] = {0.f, 0.f, 0.f, 0.f}, o1[4] = {0.f, 0.f, 0.f, 0.f};
    const int tmax = 2 * tq + 1;
    for (int s = 0; s <= tmax; ++s) {
      float4 vx = *(const float4*)(vv + s * S32 + iq * 4);
      float p0 = Ps[(2 * tq + 0) * S32 + s];
      float p1 = Ps[(2 * tq + 1) * S32 + s];
      o0[0] += p0 * vx.x; o0[1] += p0 * vx.y; o0[2] += p0 * vx.z; o0[3] += p0 * vx.w;
      o1[0] += p1 * vx.x; o1[1] += p1 * vx.y; o1[2] += p1 * vx.z; o1[3] += p1 * vx.w;
    }
    float4 w0 = {o0[0], o0[1], o0[2], o0[3]};
    float4 w1 = {o1[0], o1[1], o1[2], o1[3]};
    *(float4*)(y + gbase + (size_t)(2 * tq + 0) * C_ + iq * 4) = w0;
    *(float4*)(y + gbase + (size_t)(2 * tq + 1) * C_ + iq * 4) = w1;
  }

  // U[j][i] = G[j] * sum_s k~[s][j] * v[s][i]
  {
    const int jq = tid >> 4, iq = tid & 15;
    float ua[4][4] = {{0.f}};
    for (int s = 0; s < 32; ++s) {
      float4 kx = *(const float4*)(kk + s * S32 + jq * 4);
      float4 vx = *(const float4*)(vv + s * S32 + iq * 4);
      ua[0][0] += kx.x * vx.x; ua[0][1] += kx.x * vx.y; ua[0][2] += kx.x * vx.z; ua[0][3] += kx.x * vx.w;
      ua[1][0] += kx.y * vx.x; ua[1][1] += kx.y * vx.y; ua[1][2] += kx.y * vx.z; ua[1][3] += kx.y * vx.w;
      ua[2][0] += kx.z * vx.x; ua[2][1] += kx.z * vx.y; ua[2][2] += kx.z * vx.z; ua[2][3] += kx.z * vx.w;
      ua[3][0] += kx.w * vx.x; ua[3][1] += kx.w * vx.y; ua[3][2] += kx.w * vx.z; ua[3][3] += kx.w * vx.w;
    }
    const size_t ub = ((size_t)bh * 32 + c) * 4096;
#pragma unroll
    for (int jj = 0; jj < 4; ++jj) {
      float g = Gl[jq * 4 + jj];
      float4 uv = {ua[jj][0] * g, ua[jj][1] * g, ua[jj][2] * g, ua[jj][3] * g};
      *(float4*)(U + ub + (size_t)(jq * 4 + jj) * 64 + iq * 4) = uv;
    }
  }

  // write r' back (for phase C)
  {
    const int t = tid >> 3, q = tid & 7;
    const size_t g = gbase + (size_t)t * C_ + q * 8;
    const int l = t * S32 + q * 8;
    *(float4*)(rp + g)     = *(const float4*)(rw + l);
    *(float4*)(rp + g + 4) = *(const float4*)(rw + l + 4);
  }
}

// ---------------------------------------------------------------------------
// State scan: S_{c+1} = G_c*S_c + U_c. 256 blocks (bh x j-quarter), one
// float4 of i per thread, no LDS, no barriers.
// ---------------------------------------------------------------------------
__global__ __launch_bounds__(256)
void wkv_b32(const float* __restrict__ U, const float* __restrict__ G,
             float* __restrict__ Sbuf)
{
  const int bh = blockIdx.x >> 2, jq = blockIdx.x & 3;
  const int tid = threadIdx.x;
  const int j = jq * 16 + (tid >> 4);
  const int i = (tid & 15) * 4;
  float4 S = {0.f, 0.f, 0.f, 0.f};
  for (int c = 0; c < 32; ++c) {
    const size_t cb = ((size_t)bh * 32 + c);
    float g = G[cb * 64 + j];
    const size_t idx = cb * 4096 + (size_t)j * 64 + i;
    *(float4*)(Sbuf + idx) = S;
    float4 uv = *(const float4*)(U + idx);
    S.x = g * S.x + uv.x; S.y = g * S.y + uv.y;
    S.z = g * S.z + uv.z; S.w = g * S.w + uv.w;
  }
}

// ---------------------------------------------------------------------------
// Phase C + fused GroupNorm*silu(g) -> bf16 ygb.
// ---------------------------------------------------------------------------
__global__ __launch_bounds__(256)
void wkv_c32(const float* __restrict__ rp, const float* __restrict__ Sbuf,
             const float* __restrict__ y, const float* __restrict__ gpre,
             const float* __restrict__ lng, const float* __restrict__ lnb,
             bfu16* __restrict__ yg)
{
  __shared__ float Sl[64 * S32];
  __shared__ float rl[32 * S32];
  const int blk = blockIdx.x;
  const int bh = blk >> 5, c = blk & 31;
  const int b = bh >> 5, h = bh & 31;
  const int tid = threadIdx.x;
  const size_t gbase = ((size_t)(b * T_ + c * 32)) * C_ + h * 64;
  {
    const int j = tid >> 2, q = tid & 3;     // S: 64 rows x 64 cols
    const size_t sb = ((size_t)bh * 32 + c) * 4096 + (size_t)j * 64 + q * 16;
    const int l = j * S32 + q * 16;
#pragma unroll
    for (int p = 0; p < 4; ++p)
      *(float4*)(Sl + l + p * 4) = *(const float4*)(Sbuf + sb + p * 4);
    const int t = tid >> 3, q8 = tid & 7;    // r': 32 rows x 64 cols
    const size_t gr = gbase + (size_t)t * C_ + q8 * 8;
    const int lr = t * S32 + q8 * 8;
    *(float4*)(rl + lr)     = *(const float4*)(rp + gr);
    *(float4*)(rl + lr + 4) = *(const float4*)(rp + gr + 4);
  }
  __syncthreads();
  const int tq = tid >> 4, iq = tid & 15;
  float o0[4] = {0.f, 0.f, 0.f, 0.f}, o1[4] = {0.f, 0.f, 0.f, 0.f};
  for (int j = 0; j < 64; ++j) {
    float4 sv = *(const float4*)(Sl + j * S32 + iq * 4);
    float r0 = rl[(2 * tq + 0) * S32 + j];
    float r1 = rl[(2 * tq + 1) * S32 + j];
    o0[0] += r0 * sv.x; o0[1] += r0 * sv.y; o0[2] += r0 * sv.z; o0[3] += r0 * sv.w;
    o1[0] += r1 * sv.x; o1[1] += r1 * sv.y; o1[2] += r1 * sv.z; o1[3] += r1 * sv.w;
  }
#pragma unroll
  for (int rr = 0; rr < 2; ++rr) {
    float* o = rr ? o1 : o0;
    const size_t rowb = gbase + (size_t)(2 * tq + rr) * C_;
    float4 yi = *(const float4*)(y + rowb + iq * 4);
    float yv[4] = {yi.x + o[0], yi.y + o[1], yi.z + o[2], yi.w + o[3]};
    float s = yv[0] + yv[1] + yv[2] + yv[3];
    float sq = yv[0] * yv[0] + yv[1] * yv[1] + yv[2] * yv[2] + yv[3] * yv[3];
#pragma unroll
    for (int m = 1; m < 16; m <<= 1) {
      s  += __shfl_xor(s, m, 64);
      sq += __shfl_xor(sq, m, 64);
    }
    float mu  = s * (1.f / 64.f);
    float var = sq * (1.f / 64.f) - mu * mu;
    float rs  = rsqrtf(var + EPS_GN);
    float4 gp = *(const float4*)(gpre + rowb + iq * 4);
    const float gpv[4] = {gp.x, gp.y, gp.z, gp.w};
    uint32_t pk[2];
    ushort hw[4];
#pragma unroll
    for (int e = 0; e < 4; ++e) {
      int cidx = h * 64 + iq * 4 + e;
      float yn = (yv[e] - mu) * rs * lng[cidx] + lnb[cidx];
      float gs = gpv[e] / (1.f + __expf(-gpv[e]));
      hw[e] = f2b(yn * gs);
    }
    pk[0] = (uint32_t)hw[0] | ((uint32_t)hw[1] << 16);
    pk[1] = (uint32_t)hw[2] | ((uint32_t)hw[3] << 16);
    *(uint2*)(yg + rowb + iq * 4) = make_uint2(pk[0], pk[1]);
  }
}

// ---------------------------------------------------------------------------
extern "C" void kernel_launch(void* const* d_in, const int* in_sizes, int n_in,
                              void* d_out, int out_size, void* d_ws, size_t ws_size,
                              hipStream_t stream)
{
  const float* x      = (const float*)d_in[0];
  const float* maa_x  = (const float*)d_in[1];
  const float* maa_w  = (const float*)d_in[2];
  const float* maa_k  = (const float*)d_in[3];
  const float* maa_v  = (const float*)d_in[4];
  const float* maa_r  = (const float*)d_in[5];
  const float* maa_g  = (const float*)d_in[6];
  const float* tdec   = (const float*)d_in[7];
  const float* u      = (const float*)d_in[8];
  const float* maa_w1 = (const float*)d_in[9];
  const float* maa_w2 = (const float*)d_in[10];
  const float* td_w1  = (const float*)d_in[11];
  const float* td_w2  = (const float*)d_in[12];
  const float* lng = (const float*)d_in[18];
  const float* lnb = (const float*)d_in[19];
  float* out = (float*)d_out;

  char* wsp = (char*)d_ws;
  auto alloc = [&](size_t bytes) -> char* {
    char* p = wsp;
    wsp += (bytes + 255) & ~(size_t)255;
    return p;
  };

  bfu16* WT0 = (bfu16*)alloc((size_t)5 * 2048 * 2048 * 2);  // WT[z] = WT0 + z*4M
  bfu16* w1T  = (bfu16*)alloc((size_t)256 * 2048 * 2);
  bfu16* tw1T = (bfu16*)alloc((size_t)128 * 2048 * 2);
  bfu16* tw2T = (bfu16*)alloc((size_t)2048 * 64 * 2);
  bfu16* w2T  = (bfu16*)alloc((size_t)5 * 2048 * 64 * 2);
  float* ybuf = (float*)alloc((size_t)BT_ * C_ * 4);
  bfu16* xxh  = (bfu16*)alloc((size_t)BT_ * C_ * 2);
  bfu16* xxx  = (bfu16*)alloc((size_t)BT_ * C_ * 2);
  bfu16* xh   = (bfu16*)alloc((size_t)BT_ * C_ * 2);
  bfu16* mtan = (bfu16*)alloc((size_t)5 * BT_ * 64 * 2);
  bfu16* xmix0 = (bfu16*)alloc((size_t)5 * BT_ * C_ * 2); // xmix[f] = xmix0 + f*BT*C
  float* rbuf = (float*)alloc((size_t)4 * BT_ * C_ * 4);  // r,k,v,g contiguous
  float* kbuf = rbuf + (size_t)BT_ * C_;
  float* vbuf = kbuf + (size_t)BT_ * C_;
  float* gbuf = vbuf + (size_t)BT_ * C_;
  float* wbuf = (float*)alloc((size_t)BT_ * C_ * 4);
  bfu16* wtan = (bfu16*)alloc((size_t)BT_ * 64 * 2);
  float* Sbuf = (float*)alloc((size_t)64 * 32 * 4096 * 4);  // 32 MB
  float* Gbuf = (float*)alloc((size_t)64 * 32 * 64 * 4);    // 512 KB
  // Aliases (dead-by-then, stream-ordered):
  bfu16* ygb  = xxx;
  float* Ubuf = (float*)(xmix0 + (size_t)1 * BT_ * C_);  // 32MB over xmix[1..4]
  float* part1 = rbuf;   // m-path split-K partials [8][BT][256] (pre-GEMM)
  float* part3 = wbuf;   // w-path split-K partials [16][BT][128] (pre-MODE4)
  float* partW = rbuf;   // Wo K-split partials [4][2048][2048] (post-wkv_c)

  // mtan K-pad must stay zero (pad cols multiply real B rows)
  hipMemsetAsync(mtan, 0, (size_t)5 * BT_ * 64 * 2, stream);

  dim3 tb(256);

  // ---- transposes (f32 -> bf16, [R][C] -> dst[c][r]) ----
  {
    TrP p{}; for (int i = 0; i < 5; ++i) p.src[i] = (const float*)d_in[13 + i];
    p.dst = WT0; p.dStr = (size_t)2048 * 2048; p.R = 2048; p.Cc = 2048; p.Rpad = 2048; p.ldd = 2048;
    transpose_k<<<dim3(64, 64, 5), tb, 0, stream>>>(p);
  }
  {
    TrP p{}; p.src[0] = maa_w1; p.dst = w1T; p.dStr = 0;
    p.R = 2048; p.Cc = 160; p.Rpad = 2048; p.ldd = 2048;
    transpose_k<<<dim3(5, 64, 1), tb, 0, stream>>>(p);
  }
  {
    TrP p{}; p.src[0] = td_w1; p.dst = tw1T; p.dStr = 0;
    p.R = 2048; p.Cc = 64; p.Rpad = 2048; p.ldd = 2048;
    transpose_k<<<dim3(2, 64, 1), tb, 0, stream>>>(p);
  }
  {
    TrP p{}; p.src[0] = td_w2; p.dst = tw2T; p.dStr = 0;
    p.R = 64; p.Cc = 2048; p.Rpad = 64; p.ldd = 64;
    transpose_k<<<dim3(64, 2, 1), tb, 0, stream>>>(p);
  }
  {
    TrP p{}; for (int f = 0; f < 5; ++f) p.src[f] = maa_w2 + (size_t)f * 32 * 2048;
    p.dst = w2T; p.dStr = (size_t)2048 * 64;
    p.R = 32; p.Cc = 2048; p.Rpad = 64; p.ldd = 64;
    transpose_k<<<dim3(64, 2, 5), tb, 0, stream>>>(p);
  }

  // ---- token shift + xxx + xh ----
  prep_xx<<<dim3((BT_ * C_ / 4) / 256), tb, 0, stream>>>(x, maa_x, xxh, xxx, xh);

  // ---- m-path: split-K GEMM (xxx @ maa_w1) ----
  {
    GemmP p{}; p.A = xxx; p.Bt = w1T; p.ldk = 2048; p.kIters = 4; p.kChunk = 256;
    p.ldo = 256; p.pStride = (size_t)BT_ * 256; p.of = part1;
    gemm_k<5><<<dim3(2, 16, 8), tb, 0, stream>>>(p);
  }
  redk_tanh<0, 8><<<dim3(BT_ * 160 / 256), tb, 0, stream>>>(part1, (size_t)BT_ * 256, 256, 160, mtan);

  // ---- token-mix: fused-over-f GEMM with xh+xxh epilogue ----
  {
    GemmP p{}; p.A = mtan; p.Bt = w2T; p.ldk = 64;
    p.aStr = (size_t)BT_ * 64; p.bStr = (size_t)2048 * 64; p.oStr = (size_t)BT_ * C_;
    p.ob = xmix0; p.xh = xh; p.xxh = xxh;
    p.vArr[0] = maa_w; p.vArr[1] = maa_k; p.vArr[2] = maa_v; p.vArr[3] = maa_r; p.vArr[4] = maa_g;
    gemm_tm<<<dim3(16, 16), tb, 0, stream>>>(p);
  }

  // ---- r,k,v,g: batched-4 256^2 swizzled GEMMs (frozen champion) ----
  {
    G256P p{}; p.Bt = WT0; p.ldk = 2048; p.nkt = 32; p.kSplit = 1;
    p.bStr = (size_t)2048 * 2048; p.oStr = (size_t)BT_ * C_; p.of = rbuf;
    p.aArr[0] = xmix0 + (size_t)3 * BT_ * C_;  // xr
    p.aArr[1] = xmix0 + (size_t)1 * BT_ * C_;  // xk
    p.aArr[2] = xmix0 + (size_t)2 * BT_ * C_;  // xv
    p.aArr[3] = xmix0 + (size_t)4 * BT_ * C_;  // xg
    gemm256<<<dim3(8, 8, 4), dim3(512), 131072, stream>>>(p);
  }

  // ---- w-path: split-K thin GEMM (xw @ td_w1), 16 chunks -> 256 blocks ----
  {
    GemmP p{}; p.A = xmix0; p.Bt = tw1T; p.ldk = 2048; p.kIters = 2; p.kChunk = 128;
    p.ldo = 128; p.pStride = (size_t)BT_ * 128; p.of = part3;
    gemm_k<5><<<dim3(1, 16, 16), tb, 0, stream>>>(p);
  }
  redk_tanh<1, 16><<<dim3(BT_ * 64 / 256), tb, 0, stream>>>(part3, (size_t)BT_ * 128, 128, 64, wtan);

  // ---- w-path: wbuf = lw = -exp(tdec + wtan @ td_w2)  (fused) ----
  {
    GemmP p{}; p.A = wtan; p.Bt = tw2T; p.ldk = 64; p.kIters = 1;
    p.of = wbuf; p.ldo = 2048; p.vArr[0] = tdec;
    gemm_k<4><<<dim3(16, 16, 1), tb, 0, stream>>>(p);
  }

  // ---- chunked WKV6 (L=32) + fused GroupNorm*silu ----
  wkv_a32<<<dim3(2048), tb, 0, stream>>>(rbuf, kbuf, vbuf, wbuf, u, rbuf, ybuf, Ubuf, Gbuf);
  wkv_b32<<<dim3(256),  tb, 0, stream>>>(Ubuf, Gbuf, Sbuf);
  wkv_c32<<<dim3(2048), tb, 0, stream>>>(rbuf, Sbuf, ybuf, gbuf, lng, lnb, ygb);

  // ---- out = yg @ Wo  (256^2 frozen schedule, K-split 4 -> sum) ----
  {
    G256P p{}; p.Bt = WT0 + (size_t)4 * 2048 * 2048; p.ldk = 2048;
    p.nkt = 8; p.kSplit = 4;
    p.bStr = 0; p.oStr = (size_t)2048 * 2048; p.of = partW;
    p.aArr[0] = ygb;
    gemm256<<<dim3(8, 8, 4), dim3(512), 131072, stream>>>(p);
  }
  redk_sum4<<<dim3(4096), tb, 0, stream>>>(partW, out);
}

// Round 12
// 305.599 us; speedup vs baseline: 1.0677x; 1.0677x over previous
//
#include <hip/hip_runtime.h>
#include <cstdint>
#include <cstddef>

// Problem constants (fixed by the reference)
#define B_  2
#define T_  1024
#define C_  2048
#define H_  32
#define BT_ (B_*T_)
static constexpr float EPS_GN = 1e-5f * 64.0f;

using short8 = __attribute__((ext_vector_type(8))) short;
using f32x4  = __attribute__((ext_vector_type(4))) float;
typedef unsigned short bfu16;

__device__ __forceinline__ bfu16 f2b(float f) {
  uint32_t x = __float_as_uint(f);
  uint32_t r = (x + 0x7FFFu + ((x >> 16) & 1u)) >> 16;
  return (bfu16)r;
}
__device__ __forceinline__ float b2f(bfu16 h) {
  return __uint_as_float(((uint32_t)h) << 16);
}

__device__ __forceinline__ void gload16(const bfu16* g, bfu16* l) {
  __builtin_amdgcn_global_load_lds((__attribute__((address_space(1))) void*)g,
                                   (__attribute__((address_space(3))) void*)l,
                                   16, 0, 0);
}

// ---------------------------------------------------------------------------
// gemm256 (round-7 proven schedule, FROZEN): 256x256 tile, BK=64, 512 thr
// (8 waves 2Mx4N), dbuf LDS 128KB. STAGE_A(next); vmcnt(4); barrier; per-ks
// {STAGE_B(next) at ks==1; ds_read frags; MFMA}; barrier.
// LDS XOR-swizzle: source col ^((row&7)<<3), read col ^((lane&7)<<3).
// XCD-aware bijective block swizzle (nwg % 8 == 0 required).
// ---------------------------------------------------------------------------
struct G256P {
  const bfu16* Bt; float* of;
  size_t bStr, oStr;
  int ldk, nkt, kSplit;
  const bfu16* aArr[4];
};

__global__ __launch_bounds__(512, 2)
void gemm256(G256P p)
{
  extern __shared__ __align__(16) bfu16 sm[];   // A0,A1,B0,B1 each 256*64
  const int tid  = threadIdx.x;
  const int nwg = gridDim.x * gridDim.y * gridDim.z;
  int lin = blockIdx.x + gridDim.x * (blockIdx.y + gridDim.y * blockIdx.z);
  lin = (lin & 7) * (nwg >> 3) + (lin >> 3);
  const int bx = lin % gridDim.x;
  const int by = (lin / gridDim.x) % gridDim.y;
  const int z  = lin / (gridDim.x * gridDim.y);
  const int m0   = by * 256, n0 = bx * 256;
  const int lane = tid & 63;
  const int wv   = tid >> 6;
  const int wm   = wv >> 2, wn = wv & 3;
  const int ldk  = p.ldk;

  const bfu16* A;
  size_t koff;
  if (p.kSplit > 1) { A = p.aArr[0]; koff = (size_t)z * p.nkt * 64; }
  else              { A = p.aArr[z]; koff = 0; }
  const bfu16* Bt = p.Bt + (size_t)z * p.bStr;

  const int srow = tid >> 3;        // 0..63
  const int scol = (tid & 7) * 8;   // 0..56
  const int sswz = (srow & 7) << 3; // source-side inverse swizzle
  const bfu16* gA = A  + (size_t)(m0 + srow) * ldk + koff + (scol ^ sswz);
  const bfu16* gB = Bt + (size_t)(n0 + srow) * ldk + koff + (scol ^ sswz);

  auto STAGE_A = [&](bfu16* dst, int kt) {
    const bfu16* g = gA + (size_t)kt * 64;
    bfu16* l = dst + srow * 64 + scol;
#pragma unroll
    for (int it = 0; it < 4; ++it)
      gload16(g + (size_t)it * 64 * ldk, l + it * 4096);
  };
  auto STAGE_B = [&](bfu16* dst, int kt) {
    const bfu16* g = gB + (size_t)kt * 64;
    bfu16* l = dst + srow * 64 + scol;
#pragma unroll
    for (int it = 0; it < 4; ++it)
      gload16(g + (size_t)it * 64 * ldk, l + it * 4096);
  };

  f32x4 acc[8][4];
  const f32x4 zero = {0.f, 0.f, 0.f, 0.f};
#pragma unroll
  for (int i = 0; i < 8; ++i)
#pragma unroll
    for (int j = 0; j < 4; ++j) acc[i][j] = zero;

  STAGE_A(sm, 0);
  STAGE_B(sm + 32768, 0);           // 8 outstanding

  const int rswz = (lane & 7) << 3; // read-side swizzle

  for (int kt = 0; kt < p.nkt; ++kt) {
    bfu16* curA = sm + (kt & 1) * 16384;
    bfu16* curB = sm + 32768 + (kt & 1) * 16384;
    bfu16* nxtA = sm + ((kt & 1) ^ 1) * 16384;
    bfu16* nxtB = sm + 32768 + ((kt & 1) ^ 1) * 16384;
    const bool more = (kt + 1 < p.nkt);
    if (more) {
      STAGE_A(nxtA, kt + 1);                       // 12 outstanding
      asm volatile("s_waitcnt vmcnt(4)" ::: "memory");  // cur buf landed
    } else {
      asm volatile("s_waitcnt vmcnt(0)" ::: "memory");
    }
    __builtin_amdgcn_s_barrier();

#pragma unroll
    for (int ks = 0; ks < 2; ++ks) {
      if (ks == 1 && more) STAGE_B(nxtB, kt + 1);
      const int ko = (ks * 32 + (lane >> 4) * 8) ^ rswz;
      short8 a[8], b[4];
#pragma unroll
      for (int i = 0; i < 8; ++i)
        a[i] = *(const short8*)(curA + (wm * 128 + i * 16 + (lane & 15)) * 64 + ko);
#pragma unroll
      for (int j = 0; j < 4; ++j)
        b[j] = *(const short8*)(curB + (wn * 64 + j * 16 + (lane & 15)) * 64 + ko);
      __builtin_amdgcn_s_setprio(1);
#pragma unroll
      for (int i = 0; i < 8; ++i)
#pragma unroll
        for (int j = 0; j < 4; ++j)
          acc[i][j] = __builtin_amdgcn_mfma_f32_16x16x32_bf16(a[i], b[j], acc[i][j], 0, 0, 0);
      __builtin_amdgcn_s_setprio(0);
    }
    __builtin_amdgcn_s_barrier();
  }

  float* o = p.of + (size_t)z * p.oStr;
  const int cb = n0 + wn * 64 + (lane & 15);
  const int rb = m0 + wm * 128 + ((lane >> 4) << 2);
#pragma unroll
  for (int i = 0; i < 8; ++i)
#pragma unroll
    for (int j = 0; j < 4; ++j) {
      int col = cb + j * 16;
#pragma unroll
      for (int q = 0; q < 4; ++q)
        o[(size_t)(rb + i * 16 + q) * 2048 + col] = acc[i][j][q];
    }
}

// ---------------------------------------------------------------------------
// 128x128 GEMM for the small/odd shapes.
// MODE 4: of = -exp(vArr[0][col] + acc)   (fused lw = -exp(w))
// MODE 5: split-K partials
// MODE 7: batched-5 token-mix epilogue (x and xx both bf16)
// ---------------------------------------------------------------------------
struct GemmP {
  const bfu16* A; const bfu16* Bt;
  float* of; bfu16* ob;
  const bfu16* xh; const bfu16* xxh;
  int ldk, kIters, kChunk, ldo;
  size_t pStride, aStr, bStr, oStr;
  const float* vArr[5];
};

template<int MODE>
__global__ __launch_bounds__(256)
void gemm_k(GemmP p)
{
  __shared__ alignas(16) bfu16 As[128*64];
  __shared__ alignas(16) bfu16 Bs[128*64];
  const int tid  = threadIdx.x;
  const int z    = blockIdx.z;
  const int m0   = blockIdx.y * 128, n0 = blockIdx.x * 128;
  const int lane = tid & 63;
  const int wv   = tid >> 6;
  const int wr   = (wv >> 1) * 64, wc = (wv & 1) * 64;

  const bfu16* A  = p.A;
  const bfu16* Bt = p.Bt;
  size_t koff = 0;
  if constexpr (MODE == 7) { A += (size_t)z * p.aStr; Bt += (size_t)z * p.bStr; }
  if constexpr (MODE == 5) { koff = (size_t)z * p.kChunk; }

  f32x4 acc[4][4];
  const f32x4 zero = {0.f, 0.f, 0.f, 0.f};
#pragma unroll
  for (int i = 0; i < 4; ++i)
#pragma unroll
    for (int j = 0; j < 4; ++j) acc[i][j] = zero;

  const int srow = tid >> 3;
  const int scol = (tid & 7) * 8;
  const int ldk  = p.ldk;

  for (int kb = 0; kb < p.kIters; ++kb) {
    const bfu16* ga = A  + (size_t)m0 * ldk + koff + kb * 64;
    const bfu16* gb = Bt + (size_t)n0 * ldk + koff + kb * 64;
#pragma unroll
    for (int it = 0; it < 4; ++it) {
      int r = it * 32 + srow;
      gload16(ga + (size_t)r * ldk + scol, As + r * 64 + scol);
      gload16(gb + (size_t)r * ldk + scol, Bs + r * 64 + scol);
    }
    __syncthreads();
#pragma unroll
    for (int kk = 0; kk < 2; ++kk) {
      const int ko = kk * 32 + (lane >> 4) * 8;
      short8 a[4], b[4];
#pragma unroll
      for (int i = 0; i < 4; ++i)
        a[i] = *(const short8*)(As + (wr + i * 16 + (lane & 15)) * 64 + ko);
#pragma unroll
      for (int j = 0; j < 4; ++j)
        b[j] = *(const short8*)(Bs + (wc + j * 16 + (lane & 15)) * 64 + ko);
#pragma unroll
      for (int i = 0; i < 4; ++i)
#pragma unroll
        for (int j = 0; j < 4; ++j)
          acc[i][j] = __builtin_amdgcn_mfma_f32_16x16x32_bf16(a[i], b[j], acc[i][j], 0, 0, 0);
    }
    __syncthreads();
  }

  const int cb = n0 + wc + (lane & 15);
  const int rb = m0 + wr + ((lane >> 4) << 2);
#pragma unroll
  for (int i = 0; i < 4; ++i) {
#pragma unroll
    for (int j = 0; j < 4; ++j) {
      int col = cb + j * 16;
#pragma unroll
      for (int q = 0; q < 4; ++q) {
        int row = rb + i * 16 + q;
        float v = acc[i][j][q];
        if constexpr (MODE == 4) {
          p.of[(size_t)row * p.ldo + col] = -__expf(p.vArr[0][col] + v);
        } else if constexpr (MODE == 5) {
          p.of[(size_t)z * p.pStride + (size_t)row * p.ldo + col] = v;
        } else if constexpr (MODE == 7) {
          size_t idx = (size_t)row * C_ + col;
          (p.ob + (size_t)z * p.oStr)[idx] =
              f2b(b2f(p.xh[idx]) + b2f(p.xxh[idx]) * (p.vArr[z][col] + v));
        }
      }
    }
  }
}

// ---------------------------------------------------------------------------
// split-K reduce + tanh -> bf16.  OUT=0: mtan scatter [f][row][d]; OUT=1: wtan.
// NS = number of K-chunks to sum.
// ---------------------------------------------------------------------------
template<int OUT, int NS>
__global__ __launch_bounds__(256)
void redk_tanh(const float* __restrict__ part, size_t pStr, int ldo, int ncols,
               bfu16* __restrict__ out)
{
  int id = blockIdx.x * 256 + threadIdx.x;
  int row = id / ncols, col = id % ncols;
  if (row >= BT_) return;
  float v = 0.f;
#pragma unroll
  for (int s = 0; s < NS; ++s) v += part[(size_t)s * pStr + (size_t)row * ldo + col];
  bfu16 tv = f2b(tanhf(v));
  if constexpr (OUT == 0)
    out[((size_t)(col >> 5) * BT_ + row) * 64 + (col & 31)] = tv;
  else
    out[(size_t)row * 64 + col] = tv;
}

__global__ __launch_bounds__(256)
void redk_sum4(const float* __restrict__ p0, float* __restrict__ out)
{
  size_t i = ((size_t)blockIdx.x * 256 + threadIdx.x) * 4;
  const size_t str = (size_t)2048 * 2048;
  float4 a = *(const float4*)(p0 + i);
  float4 b = *(const float4*)(p0 + str + i);
  float4 c = *(const float4*)(p0 + 2 * str + i);
  float4 d = *(const float4*)(p0 + 3 * str + i);
  a.x += b.x + c.x + d.x; a.y += b.y + c.y + d.y;
  a.z += b.z + c.z + d.z; a.w += b.w + c.w + d.w;
  *(float4*)(out + i) = a;
}

// ---------------------------------------------------------------------------
// All weight transposes in ONE launch. 13 jobs, flattened block index,
// wave-uniform job lookup; per-block body identical to the proven
// round-9 transpose (scalar bf16 writes). f32 [R][Cc] -> bf16 dst[c*ldd+r],
// rows [R,Rpad) zero-filled.
// ---------------------------------------------------------------------------
struct TrJob { const float* src; bfu16* dst; int R, Cc, Rpad, ldd, gx, start; };
struct TrAllP { TrJob j[13]; };

__global__ __launch_bounds__(256)
void transpose_all(TrAllP p)
{
  __shared__ float tile[32][33];
  const int bid = blockIdx.x;
  int k = 0;
#pragma unroll
  for (int t = 1; t < 13; ++t) if (bid >= p.j[t].start) k = t;
  const TrJob jb = p.j[k];
  const int local = bid - jb.start;
  const int bx = local % jb.gx, by = local / jb.gx;
  const int tx = threadIdx.x & 31, ty = threadIdx.x >> 5;
  const int r0 = by * 32, c0 = bx * 32;
#pragma unroll
  for (int i = 0; i < 4; ++i) {
    int r = r0 + ty + i * 8, c = c0 + tx;
    tile[ty + i * 8][tx] = (r < jb.R && c < jb.Cc) ? jb.src[(size_t)r * jb.Cc + c] : 0.f;
  }
  __syncthreads();
#pragma unroll
  for (int i = 0; i < 4; ++i) {
    int c = c0 + ty + i * 8, r = r0 + tx;
    if (c < jb.Cc && r < jb.Rpad) jb.dst[(size_t)c * jb.ldd + r] = f2b(tile[tx][ty + i * 8]);
  }
}

// ---------------------------------------------------------------------------
// xx = shift(x) - x (bf16) ; xxx = bf16(x + xx*maa_x) ; xh = bf16(x)
// ---------------------------------------------------------------------------
__global__ __launch_bounds__(256)
void prep_xx(const float* __restrict__ x, const float* __restrict__ maa_x,
             bfu16* __restrict__ xxh, bfu16* __restrict__ xxx,
             bfu16* __restrict__ xh)
{
  size_t i = ((size_t)blockIdx.x * 256 + threadIdx.x) * 4;
  int c  = (int)(i & (C_ - 1));
  int bt = (int)(i >> 11);
  int t  = bt & (T_ - 1);
  float4 xv = *(const float4*)(x + i);
  float4 xp = {0.f, 0.f, 0.f, 0.f};
  if (t > 0) xp = *(const float4*)(x + i - C_);
  float4 mx = *(const float4*)(maa_x + c);
  float dx = xp.x - xv.x, dy = xp.y - xv.y, dz = xp.z - xv.z, dw = xp.w - xv.w;
  uint2 w0;
  w0.x = (uint32_t)f2b(dx) | ((uint32_t)f2b(dy) << 16);
  w0.y = (uint32_t)f2b(dz) | ((uint32_t)f2b(dw) << 16);
  *(uint2*)(xxh + i) = w0;
  uint2 w1;
  w1.x = (uint32_t)f2b(xv.x + dx * mx.x) | ((uint32_t)f2b(xv.y + dy * mx.y) << 16);
  w1.y = (uint32_t)f2b(xv.z + dz * mx.z) | ((uint32_t)f2b(xv.w + dw * mx.w) << 16);
  *(uint2*)(xxx + i) = w1;
  uint2 w2;
  w2.x = (uint32_t)f2b(xv.x) | ((uint32_t)f2b(xv.y) << 16);
  w2.y = (uint32_t)f2b(xv.z) | ((uint32_t)f2b(xv.w) << 16);
  *(uint2*)(xh + i) = w2;
}

// ---------------------------------------------------------------------------
// WKV6 chunked scan, chunk L=32. w input is ALREADY lw = -exp(w).
// ---------------------------------------------------------------------------
#define S32 68   // LDS row stride (floats) for 32-row tiles

__global__ __launch_bounds__(256)
void wkv_a32(const float* __restrict__ r, const float* __restrict__ k,
             const float* __restrict__ v, const float* __restrict__ w,
             const float* __restrict__ u, float* __restrict__ rp,
             float* __restrict__ y, float* __restrict__ U, float* __restrict__ G)
{
  __shared__ float rw[32 * S32];
  __shared__ float kk[32 * S32];
  __shared__ float vv[32 * S32];
  __shared__ float Ps[32 * S32];
  __shared__ float red[256];
  __shared__ float diag[32];
  __shared__ float Gl[64];

  const int blk = blockIdx.x;
  const int bh = blk >> 5, c = blk & 31;
  const int b = bh >> 5, h = bh & 31;
  const int tid = threadIdx.x;
  const size_t gbase = ((size_t)(b * T_ + c * 32)) * C_ + h * 64;

  {
    const int t = tid >> 3, q = tid & 7;
    const size_t g = gbase + (size_t)t * C_ + q * 8;
    const int l = t * S32 + q * 8;
    *(float4*)(rw + l)     = *(const float4*)(r + g);
    *(float4*)(rw + l + 4) = *(const float4*)(r + g + 4);
    *(float4*)(kk + l)     = *(const float4*)(k + g);
    *(float4*)(kk + l + 4) = *(const float4*)(k + g + 4);
    *(float4*)(vv + l)     = *(const float4*)(v + g);
    *(float4*)(vv + l + 4) = *(const float4*)(v + g + 4);
    *(float4*)(Ps + l)     = *(const float4*)(w + g);
    *(float4*)(Ps + l + 4) = *(const float4*)(w + g + 4);
  }
  __syncthreads();

  // segmented prefix over t (4 segments of 8), per-j
  {
    const int seg = tid >> 6, j = tid & 63;
    float loc = 0.f;
#pragma unroll
    for (int tt = 0; tt < 8; ++tt) loc += Ps[(seg * 8 + tt) * S32 + j];
    red[seg * 64 + j] = loc;
  }
  __syncthreads();
  {
    const int seg = tid >> 6, j = tid & 63;
    float cs = 0.f;
    for (int s = 0; s < seg; ++s) cs += red[s * 64 + j];
    const float uj = u[h * 64 + j];
#pragma unroll
    for (int tt = 0; tt < 8; ++tt) {
      const int a = (seg * 8 + tt) * S32 + j;
      float lw = Ps[a];
      float rv = rw[a] * __expf(cs);
      rw[a] = rv;
      cs += lw;
      float kv = kk[a] * __expf(-cs);
      kk[a] = kv;
      Ps[a] = rv * kv * uj * __expf(lw);   // D (exact)
    }
    if (seg == 3) {
      float Gj = __expf(cs);
      Gl[j] = Gj;
      G[((size_t)bh * 32 + c) * 64 + j] = Gj;
    }
  }
  __syncthreads();

  // diag[t] = sum_j D[t][j]
  {
    const int t = tid & 31, q = tid >> 5;
    float s = 0.f;
#pragma unroll
    for (int jj = 0; jj < 8; ++jj) s += Ps[t * S32 + q * 8 + jj];
    red[q * 32 + t] = s;
  }
  __syncthreads();
  if (tid < 32) {
    float d = 0.f;
#pragma unroll
    for (int q = 0; q < 8; ++q) d += red[q * 32 + tid];
    diag[tid] = d;
  }
  __syncthreads();

  // scores: 2x2 tiles over 16x16 thread grid, lower-tri
  {
    const int tq = tid >> 4, sq = tid & 15;
    float a00 = 0.f, a01 = 0.f, a10 = 0.f, a11 = 0.f;
    if (sq <= tq) {
      for (int j = 0; j < 64; j += 4) {
        float4 r0 = *(const float4*)(rw + (2 * tq + 0) * S32 + j);
        float4 r1 = *(const float4*)(rw + (2 * tq + 1) * S32 + j);
        float4 k0 = *(const float4*)(kk + (2 * sq + 0) * S32 + j);
        float4 k1 = *(const float4*)(kk + (2 * sq + 1) * S32 + j);
        a00 += r0.x * k0.x + r0.y * k0.y + r0.z * k0.z + r0.w * k0.w;
        a01 += r0.x * k1.x + r0.y * k1.y + r0.z * k1.z + r0.w * k1.w;
        a10 += r1.x * k0.x + r1.y * k0.y + r1.z * k0.z + r1.w * k0.w;
        a11 += r1.x * k1.x + r1.y * k1.y + r1.z * k1.z + r1.w * k1.w;
      }
    }
    __syncthreads();
    if (sq <= tq) {
      const float av[2][2] = {{a00, a01}, {a10, a11}};
#pragma unroll
      for (int tt = 0; tt < 2; ++tt)
#pragma unroll
        for (int ss = 0; ss < 2; ++ss) {
          int t = 2 * tq + tt, s = 2 * sq + ss;
          Ps[t * S32 + s] = (s < t) ? av[tt][ss] : (s == t ? diag[t] : 0.f);
        }
    }
  }
  __syncthreads();

  // O_intra[t][i] = sum_{s<=t} P[t][s] * v[s][i]  -> y
  {
    const int tq = tid >> 4, iq = tid & 15;
    float o0[4] = {0.f, 0.f, 0.f, 0.f}, o1[4] = {0.f, 0.f, 0.f, 0.f};
    const int tmax = 2 * tq + 1;
    for (int s = 0; s <= tmax; ++s) {
      float4 vx = *(const float4*)(vv + s * S32 + iq * 4);
      float p0 = Ps[(2 * tq + 0) * S32 + s];
      float p1 = Ps[(2 * tq + 1) * S32 + s];
      o0[0] += p0 * vx.x; o0[1] += p0 * vx.y; o0[2] += p0 * vx.z; o0[3] += p0 * vx.w;
      o1[0] += p1 * vx.x; o1[1] += p1 * vx.y; o1[2] += p1 * vx.z; o1[3] += p1 * vx.w;
    }
    float4 w0 = {o0[0], o0[1], o0[2], o0[3]};
    float4 w1 = {o1[0], o1[1], o1[2], o1[3]};
    *(float4*)(y + gbase + (size_t)(2 * tq + 0) * C_ + iq * 4) = w0;
    *(float4*)(y + gbase + (size_t)(2 * tq + 1) * C_ + iq * 4) = w1;
  }

  // U[j][i] = G[j] * sum_s k~[s][j] * v[s][i]
  {
    const int jq = tid >> 4, iq = tid & 15;
    float ua[4][4] = {{0.f}};
    for (int s = 0; s < 32; ++s) {
      float4 kx = *(const float4*)(kk + s * S32 + jq * 4);
      float4 vx = *(const float4*)(vv + s * S32 + iq * 4);
      ua[0][0] += kx.x * vx.x; ua[0][1] += kx.x * vx.y; ua[0][2] += kx.x * vx.z; ua[0][3] += kx.x * vx.w;
      ua[1][0] += kx.y * vx.x; ua[1][1] += kx.y * vx.y; ua[1][2] += kx.y * vx.z; ua[1][3] += kx.y * vx.w;
      ua[2][0] += kx.z * vx.x; ua[2][1] += kx.z * vx.y; ua[2][2] += kx.z * vx.z; ua[2][3] += kx.z * vx.w;
      ua[3][0] += kx.w * vx.x; ua[3][1] += kx.w * vx.y; ua[3][2] += kx.w * vx.z; ua[3][3] += kx.w * vx.w;
    }
    const size_t ub = ((size_t)bh * 32 + c) * 4096;
#pragma unroll
    for (int jj = 0; jj < 4; ++jj) {
      float g = Gl[jq * 4 + jj];
      float4 uv = {ua[jj][0] * g, ua[jj][1] * g, ua[jj][2] * g, ua[jj][3] * g};
      *(float4*)(U + ub + (size_t)(jq * 4 + jj) * 64 + iq * 4) = uv;
    }
  }

  // write r' back (for phase C)
  {
    const int t = tid >> 3, q = tid & 7;
    const size_t g = gbase + (size_t)t * C_ + q * 8;
    const int l = t * S32 + q * 8;
    *(float4*)(rp + g)     = *(const float4*)(rw + l);
    *(float4*)(rp + g + 4) = *(const float4*)(rw + l + 4);
  }
}

// ---------------------------------------------------------------------------
// State scan: S_{c+1} = G_c*S_c + U_c. 256 blocks (bh x j-quarter), one
// float4 of i per thread, no LDS, no barriers.
// ---------------------------------------------------------------------------
__global__ __launch_bounds__(256)
void wkv_b32(const float* __restrict__ U, const float* __restrict__ G,
             float* __restrict__ Sbuf)
{
  const int bh = blockIdx.x >> 2, jq = blockIdx.x & 3;
  const int tid = threadIdx.x;
  const int j = jq * 16 + (tid >> 4);
  const int i = (tid & 15) * 4;
  float4 S = {0.f, 0.f, 0.f, 0.f};
  for (int c = 0; c < 32; ++c) {
    const size_t cb = ((size_t)bh * 32 + c);
    float g = G[cb * 64 + j];
    const size_t idx = cb * 4096 + (size_t)j * 64 + i;
    *(float4*)(Sbuf + idx) = S;
    float4 uv = *(const float4*)(U + idx);
    S.x = g * S.x + uv.x; S.y = g * S.y + uv.y;
    S.z = g * S.z + uv.z; S.w = g * S.w + uv.w;
  }
}

// ---------------------------------------------------------------------------
// Phase C + fused GroupNorm*silu(g) -> bf16 ygb.
// ---------------------------------------------------------------------------
__global__ __launch_bounds__(256)
void wkv_c32(const float* __restrict__ rp, const float* __restrict__ Sbuf,
             const float* __restrict__ y, const float* __restrict__ gpre,
             const float* __restrict__ lng, const float* __restrict__ lnb,
             bfu16* __restrict__ yg)
{
  __shared__ float Sl[64 * S32];
  __shared__ float rl[32 * S32];
  const int blk = blockIdx.x;
  const int bh = blk >> 5, c = blk & 31;
  const int b = bh >> 5, h = bh & 31;
  const int tid = threadIdx.x;
  const size_t gbase = ((size_t)(b * T_ + c * 32)) * C_ + h * 64;
  {
    const int j = tid >> 2, q = tid & 3;     // S: 64 rows x 64 cols
    const size_t sb = ((size_t)bh * 32 + c) * 4096 + (size_t)j * 64 + q * 16;
    const int l = j * S32 + q * 16;
#pragma unroll
    for (int p = 0; p < 4; ++p)
      *(float4*)(Sl + l + p * 4) = *(const float4*)(Sbuf + sb + p * 4);
    const int t = tid >> 3, q8 = tid & 7;    // r': 32 rows x 64 cols
    const size_t gr = gbase + (size_t)t * C_ + q8 * 8;
    const int lr = t * S32 + q8 * 8;
    *(float4*)(rl + lr)     = *(const float4*)(rp + gr);
    *(float4*)(rl + lr + 4) = *(const float4*)(rp + gr + 4);
  }
  __syncthreads();
  const int tq = tid >> 4, iq = tid & 15;
  float o0[4] = {0.f, 0.f, 0.f, 0.f}, o1[4] = {0.f, 0.f, 0.f, 0.f};
  for (int j = 0; j < 64; ++j) {
    float4 sv = *(const float4*)(Sl + j * S32 + iq * 4);
    float r0 = rl[(2 * tq + 0) * S32 + j];
    float r1 = rl[(2 * tq + 1) * S32 + j];
    o0[0] += r0 * sv.x; o0[1] += r0 * sv.y; o0[2] += r0 * sv.z; o0[3] += r0 * sv.w;
    o1[0] += r1 * sv.x; o1[1] += r1 * sv.y; o1[2] += r1 * sv.z; o1[3] += r1 * sv.w;
  }
#pragma unroll
  for (int rr = 0; rr < 2; ++rr) {
    float* o = rr ? o1 : o0;
    const size_t rowb = gbase + (size_t)(2 * tq + rr) * C_;
    float4 yi = *(const float4*)(y + rowb + iq * 4);
    float yv[4] = {yi.x + o[0], yi.y + o[1], yi.z + o[2], yi.w + o[3]};
    float s = yv[0] + yv[1] + yv[2] + yv[3];
    float sq = yv[0] * yv[0] + yv[1] * yv[1] + yv[2] * yv[2] + yv[3] * yv[3];
#pragma unroll
    for (int m = 1; m < 16; m <<= 1) {
      s  += __shfl_xor(s, m, 64);
      sq += __shfl_xor(sq, m, 64);
    }
    float mu  = s * (1.f / 64.f);
    float var = sq * (1.f / 64.f) - mu * mu;
    float rs  = rsqrtf(var + EPS_GN);
    float4 gp = *(const float4*)(gpre + rowb + iq * 4);
    const float gpv[4] = {gp.x, gp.y, gp.z, gp.w};
    uint32_t pk[2];
    ushort hw[4];
#pragma unroll
    for (int e = 0; e < 4; ++e) {
      int cidx = h * 64 + iq * 4 + e;
      float yn = (yv[e] - mu) * rs * lng[cidx] + lnb[cidx];
      float gs = gpv[e] / (1.f + __expf(-gpv[e]));
      hw[e] = f2b(yn * gs);
    }
    pk[0] = (uint32_t)hw[0] | ((uint32_t)hw[1] << 16);
    pk[1] = (uint32_t)hw[2] | ((uint32_t)hw[3] << 16);
    *(uint2*)(yg + rowb + iq * 4) = make_uint2(pk[0], pk[1]);
  }
}

// ---------------------------------------------------------------------------
extern "C" void kernel_launch(void* const* d_in, const int* in_sizes, int n_in,
                              void* d_out, int out_size, void* d_ws, size_t ws_size,
                              hipStream_t stream)
{
  const float* x      = (const float*)d_in[0];
  const float* maa_x  = (const float*)d_in[1];
  const float* maa_w  = (const float*)d_in[2];
  const float* maa_k  = (const float*)d_in[3];
  const float* maa_v  = (const float*)d_in[4];
  const float* maa_r  = (const float*)d_in[5];
  const float* maa_g  = (const float*)d_in[6];
  const float* tdec   = (const float*)d_in[7];
  const float* u      = (const float*)d_in[8];
  const float* maa_w1 = (const float*)d_in[9];
  const float* maa_w2 = (const float*)d_in[10];
  const float* td_w1  = (const float*)d_in[11];
  const float* td_w2  = (const float*)d_in[12];
  const float* lng = (const float*)d_in[18];
  const float* lnb = (const float*)d_in[19];
  float* out = (float*)d_out;

  char* wsp = (char*)d_ws;
  auto alloc = [&](size_t bytes) -> char* {
    char* p = wsp;
    wsp += (bytes + 255) & ~(size_t)255;
    return p;
  };

  bfu16* WT0 = (bfu16*)alloc((size_t)5 * 2048 * 2048 * 2);  // WT[z] = WT0 + z*4M
  bfu16* w1T  = (bfu16*)alloc((size_t)256 * 2048 * 2);
  bfu16* tw1T = (bfu16*)alloc((size_t)128 * 2048 * 2);
  bfu16* tw2T = (bfu16*)alloc((size_t)2048 * 64 * 2);
  bfu16* w2T  = (bfu16*)alloc((size_t)5 * 2048 * 64 * 2);
  float* ybuf = (float*)alloc((size_t)BT_ * C_ * 4);
  bfu16* xxh  = (bfu16*)alloc((size_t)BT_ * C_ * 2);
  bfu16* xxx  = (bfu16*)alloc((size_t)BT_ * C_ * 2);
  bfu16* xh   = (bfu16*)alloc((size_t)BT_ * C_ * 2);
  bfu16* mtan = (bfu16*)alloc((size_t)5 * BT_ * 64 * 2);
  bfu16* xmix0 = (bfu16*)alloc((size_t)5 * BT_ * C_ * 2); // xmix[f] = xmix0 + f*BT*C
  float* rbuf = (float*)alloc((size_t)4 * BT_ * C_ * 4);  // r,k,v,g contiguous
  float* kbuf = rbuf + (size_t)BT_ * C_;
  float* vbuf = kbuf + (size_t)BT_ * C_;
  float* gbuf = vbuf + (size_t)BT_ * C_;
  float* wbuf = (float*)alloc((size_t)BT_ * C_ * 4);
  bfu16* wtan = (bfu16*)alloc((size_t)BT_ * 64 * 2);
  float* Sbuf = (float*)alloc((size_t)64 * 32 * 4096 * 4);  // 32 MB
  float* Gbuf = (float*)alloc((size_t)64 * 32 * 64 * 4);    // 512 KB
  // Aliases (dead-by-then, stream-ordered):
  bfu16* ygb  = xxx;
  float* Ubuf = (float*)(xmix0 + (size_t)1 * BT_ * C_);  // 32MB over xmix[1..4]
  float* part1 = rbuf;   // m-path split-K partials [8][BT][256] (pre-GEMM)
  float* part3 = wbuf;   // w-path split-K partials [16][BT][128] (pre-MODE4)
  float* partW = rbuf;   // Wo K-split partials [4][2048][2048] (post-wkv_c)

  // mtan K-pad must stay zero (pad cols multiply real B rows)
  hipMemsetAsync(mtan, 0, (size_t)5 * BT_ * 64 * 2, stream);

  dim3 tb(256);

  // ---- all weight transposes, one launch (13 jobs) ----
  {
    TrAllP p{};
    int s = 0;
    for (int i = 0; i < 5; ++i) {
      p.j[i] = TrJob{ (const float*)d_in[13 + i], WT0 + (size_t)i * 2048 * 2048,
                      2048, 2048, 2048, 2048, 64, s };
      s += 64 * 64;
    }
    p.j[5] = TrJob{ maa_w1, w1T, 2048, 160, 2048, 2048, 5, s };  s += 5 * 64;
    p.j[6] = TrJob{ td_w1, tw1T, 2048, 64, 2048, 2048, 2, s };   s += 2 * 64;
    p.j[7] = TrJob{ td_w2, tw2T, 64, 2048, 64, 64, 64, s };      s += 64 * 2;
    for (int f = 0; f < 5; ++f) {
      p.j[8 + f] = TrJob{ maa_w2 + (size_t)f * 32 * 2048, w2T + (size_t)f * 2048 * 64,
                          32, 2048, 64, 64, 64, s };
      s += 64 * 2;
    }
    transpose_all<<<dim3(s), tb, 0, stream>>>(p);
  }

  // ---- token shift + xxx + xh ----
  prep_xx<<<dim3((BT_ * C_ / 4) / 256), tb, 0, stream>>>(x, maa_x, xxh, xxx, xh);

  // ---- m-path: split-K GEMM (xxx @ maa_w1) ----
  {
    GemmP p{}; p.A = xxx; p.Bt = w1T; p.ldk = 2048; p.kIters = 4; p.kChunk = 256;
    p.ldo = 256; p.pStride = (size_t)BT_ * 256; p.of = part1;
    gemm_k<5><<<dim3(2, 16, 8), tb, 0, stream>>>(p);
  }
  redk_tanh<0, 8><<<dim3(BT_ * 160 / 256), tb, 0, stream>>>(part1, (size_t)BT_ * 256, 256, 160, mtan);

  // ---- token-mix: batched-5 (mtan[f] @ w2T[f]) with xh+xxh epilogue ----
  {
    GemmP p{}; p.A = mtan; p.Bt = w2T; p.ldk = 64; p.kIters = 1;
    p.aStr = (size_t)BT_ * 64; p.bStr = (size_t)2048 * 64; p.oStr = (size_t)BT_ * C_;
    p.ob = xmix0; p.xh = xh; p.xxh = xxh;
    p.vArr[0] = maa_w; p.vArr[1] = maa_k; p.vArr[2] = maa_v; p.vArr[3] = maa_r; p.vArr[4] = maa_g;
    gemm_k<7><<<dim3(16, 16, 5), tb, 0, stream>>>(p);
  }

  // ---- r,k,v,g: batched-4 256^2 swizzled GEMMs (frozen champion) ----
  {
    G256P p{}; p.Bt = WT0; p.ldk = 2048; p.nkt = 32; p.kSplit = 1;
    p.bStr = (size_t)2048 * 2048; p.oStr = (size_t)BT_ * C_; p.of = rbuf;
    p.aArr[0] = xmix0 + (size_t)3 * BT_ * C_;  // xr
    p.aArr[1] = xmix0 + (size_t)1 * BT_ * C_;  // xk
    p.aArr[2] = xmix0 + (size_t)2 * BT_ * C_;  // xv
    p.aArr[3] = xmix0 + (size_t)4 * BT_ * C_;  // xg
    gemm256<<<dim3(8, 8, 4), dim3(512), 131072, stream>>>(p);
  }

  // ---- w-path: split-K thin GEMM (xw @ td_w1), 16 chunks -> 256 blocks ----
  {
    GemmP p{}; p.A = xmix0; p.Bt = tw1T; p.ldk = 2048; p.kIters = 2; p.kChunk = 128;
    p.ldo = 128; p.pStride = (size_t)BT_ * 128; p.of = part3;
    gemm_k<5><<<dim3(1, 16, 16), tb, 0, stream>>>(p);
  }
  redk_tanh<1, 16><<<dim3(BT_ * 64 / 256), tb, 0, stream>>>(part3, (size_t)BT_ * 128, 128, 64, wtan);

  // ---- w-path: wbuf = lw = -exp(tdec + wtan @ td_w2)  (fused) ----
  {
    GemmP p{}; p.A = wtan; p.Bt = tw2T; p.ldk = 64; p.kIters = 1;
    p.of = wbuf; p.ldo = 2048; p.vArr[0] = tdec;
    gemm_k<4><<<dim3(16, 16, 1), tb, 0, stream>>>(p);
  }

  // ---- chunked WKV6 (L=32) + fused GroupNorm*silu ----
  wkv_a32<<<dim3(2048), tb, 0, stream>>>(rbuf, kbuf, vbuf, wbuf, u, rbuf, ybuf, Ubuf, Gbuf);
  wkv_b32<<<dim3(256),  tb, 0, stream>>>(Ubuf, Gbuf, Sbuf);
  wkv_c32<<<dim3(2048), tb, 0, stream>>>(rbuf, Sbuf, ybuf, gbuf, lng, lnb, ygb);

  // ---- out = yg @ Wo  (256^2 frozen schedule, K-split 4 -> sum) ----
  {
    G256P p{}; p.Bt = WT0 + (size_t)4 * 2048 * 2048; p.ldk = 2048;
    p.nkt = 8; p.kSplit = 4;
    p.bStr = 0; p.oStr = (size_t)2048 * 2048; p.of = partW;
    p.aArr[0] = ygb;
    gemm256<<<dim3(8, 8, 4), dim3(512), 131072, stream>>>(p);
  }
  redk_sum4<<<dim3(4096), tb, 0, stream>>>(partW, out);
}

// Round 13
// 294.353 us; speedup vs baseline: 1.1085x; 1.0382x over previous
//
#include <hip/hip_runtime.h>
#include <cstdint>
#include <cstddef>

// Problem constants (fixed by the reference)
#define B_  2
#define T_  1024
#define C_  2048
#define H_  32
#define BT_ (B_*T_)
static constexpr float EPS_GN = 1e-5f * 64.0f;

using short8 = __attribute__((ext_vector_type(8))) short;
using f32x4  = __attribute__((ext_vector_type(4))) float;
typedef unsigned short bfu16;

__device__ __forceinline__ bfu16 f2b(float f) {
  uint32_t x = __float_as_uint(f);
  uint32_t r = (x + 0x7FFFu + ((x >> 16) & 1u)) >> 16;
  return (bfu16)r;
}
__device__ __forceinline__ float b2f(bfu16 h) {
  return __uint_as_float(((uint32_t)h) << 16);
}
__device__ __forceinline__ float b2fu(uint32_t w) {   // low half of packed
  return __uint_as_float(w << 16);
}

__device__ __forceinline__ void gload16(const bfu16* g, bfu16* l) {
  __builtin_amdgcn_global_load_lds((__attribute__((address_space(1))) void*)g,
                                   (__attribute__((address_space(3))) void*)l,
                                   16, 0, 0);
}

// ---------------------------------------------------------------------------
// gemm256 (round-7 proven schedule, FROZEN): 256x256 tile, BK=64, 512 thr
// (8 waves 2Mx4N), dbuf LDS 128KB. STAGE_A(next); vmcnt(4); barrier; per-ks
// {STAGE_B(next) at ks==1; ds_read frags; MFMA}; barrier.
// LDS XOR-swizzle: source col ^((row&7)<<3), read col ^((lane&7)<<3).
// XCD-aware bijective block swizzle (nwg % 8 == 0 required).
// OB=0: f32 output (p.of). OB=1: bf16 output (p.ob) -- split-K partials.
// ---------------------------------------------------------------------------
struct G256P {
  const bfu16* Bt; float* of; bfu16* ob;
  size_t bStr, oStr;
  int ldk, nkt, kSplit;
  const bfu16* aArr[4];
};

template<int OB>
__global__ __launch_bounds__(512, 2)
void gemm256(G256P p)
{
  extern __shared__ __align__(16) bfu16 sm[];   // A0,A1,B0,B1 each 256*64
  const int tid  = threadIdx.x;
  const int nwg = gridDim.x * gridDim.y * gridDim.z;
  int lin = blockIdx.x + gridDim.x * (blockIdx.y + gridDim.y * blockIdx.z);
  lin = (lin & 7) * (nwg >> 3) + (lin >> 3);
  const int bx = lin % gridDim.x;
  const int by = (lin / gridDim.x) % gridDim.y;
  const int z  = lin / (gridDim.x * gridDim.y);
  const int m0   = by * 256, n0 = bx * 256;
  const int lane = tid & 63;
  const int wv   = tid >> 6;
  const int wm   = wv >> 2, wn = wv & 3;
  const int ldk  = p.ldk;

  const bfu16* A;
  size_t koff;
  if (p.kSplit > 1) { A = p.aArr[0]; koff = (size_t)z * p.nkt * 64; }
  else              { A = p.aArr[z]; koff = 0; }
  const bfu16* Bt = p.Bt + (size_t)z * p.bStr;

  const int srow = tid >> 3;        // 0..63
  const int scol = (tid & 7) * 8;   // 0..56
  const int sswz = (srow & 7) << 3; // source-side inverse swizzle
  const bfu16* gA = A  + (size_t)(m0 + srow) * ldk + koff + (scol ^ sswz);
  const bfu16* gB = Bt + (size_t)(n0 + srow) * ldk + koff + (scol ^ sswz);

  auto STAGE_A = [&](bfu16* dst, int kt) {
    const bfu16* g = gA + (size_t)kt * 64;
    bfu16* l = dst + srow * 64 + scol;
#pragma unroll
    for (int it = 0; it < 4; ++it)
      gload16(g + (size_t)it * 64 * ldk, l + it * 4096);
  };
  auto STAGE_B = [&](bfu16* dst, int kt) {
    const bfu16* g = gB + (size_t)kt * 64;
    bfu16* l = dst + srow * 64 + scol;
#pragma unroll
    for (int it = 0; it < 4; ++it)
      gload16(g + (size_t)it * 64 * ldk, l + it * 4096);
  };

  f32x4 acc[8][4];
  const f32x4 zero = {0.f, 0.f, 0.f, 0.f};
#pragma unroll
  for (int i = 0; i < 8; ++i)
#pragma unroll
    for (int j = 0; j < 4; ++j) acc[i][j] = zero;

  STAGE_A(sm, 0);
  STAGE_B(sm + 32768, 0);           // 8 outstanding

  const int rswz = (lane & 7) << 3; // read-side swizzle

  for (int kt = 0; kt < p.nkt; ++kt) {
    bfu16* curA = sm + (kt & 1) * 16384;
    bfu16* curB = sm + 32768 + (kt & 1) * 16384;
    bfu16* nxtA = sm + ((kt & 1) ^ 1) * 16384;
    bfu16* nxtB = sm + 32768 + ((kt & 1) ^ 1) * 16384;
    const bool more = (kt + 1 < p.nkt);
    if (more) {
      STAGE_A(nxtA, kt + 1);                       // 12 outstanding
      asm volatile("s_waitcnt vmcnt(4)" ::: "memory");  // cur buf landed
    } else {
      asm volatile("s_waitcnt vmcnt(0)" ::: "memory");
    }
    __builtin_amdgcn_s_barrier();

#pragma unroll
    for (int ks = 0; ks < 2; ++ks) {
      if (ks == 1 && more) STAGE_B(nxtB, kt + 1);
      const int ko = (ks * 32 + (lane >> 4) * 8) ^ rswz;
      short8 a[8], b[4];
#pragma unroll
      for (int i = 0; i < 8; ++i)
        a[i] = *(const short8*)(curA + (wm * 128 + i * 16 + (lane & 15)) * 64 + ko);
#pragma unroll
      for (int j = 0; j < 4; ++j)
        b[j] = *(const short8*)(curB + (wn * 64 + j * 16 + (lane & 15)) * 64 + ko);
      __builtin_amdgcn_s_setprio(1);
#pragma unroll
      for (int i = 0; i < 8; ++i)
#pragma unroll
        for (int j = 0; j < 4; ++j)
          acc[i][j] = __builtin_amdgcn_mfma_f32_16x16x32_bf16(a[i], b[j], acc[i][j], 0, 0, 0);
      __builtin_amdgcn_s_setprio(0);
    }
    __builtin_amdgcn_s_barrier();
  }

  const int cb = n0 + wn * 64 + (lane & 15);
  const int rb = m0 + wm * 128 + ((lane >> 4) << 2);
  if constexpr (OB == 0) {
    float* o = p.of + (size_t)z * p.oStr;
#pragma unroll
    for (int i = 0; i < 8; ++i)
#pragma unroll
      for (int j = 0; j < 4; ++j) {
        int col = cb + j * 16;
#pragma unroll
        for (int q = 0; q < 4; ++q)
          o[(size_t)(rb + i * 16 + q) * 2048 + col] = acc[i][j][q];
      }
  } else {
    bfu16* o = p.ob + (size_t)z * p.oStr;
#pragma unroll
    for (int i = 0; i < 8; ++i)
#pragma unroll
      for (int j = 0; j < 4; ++j) {
        int col = cb + j * 16;
#pragma unroll
        for (int q = 0; q < 4; ++q)
          o[(size_t)(rb + i * 16 + q) * 2048 + col] = f2b(acc[i][j][q]);
      }
  }
}

// ---------------------------------------------------------------------------
// 128x128 GEMM for the small/odd shapes.
// MODE 4: of = -exp(vArr[0][col] + acc)   (fused lw = -exp(w))
// MODE 6: split-K bf16 partials
// MODE 7: batched-5 token-mix epilogue (x and xx both bf16)
// ---------------------------------------------------------------------------
struct GemmP {
  const bfu16* A; const bfu16* Bt;
  float* of; bfu16* ob;
  const bfu16* xh; const bfu16* xxh;
  int ldk, kIters, kChunk, ldo;
  size_t pStride, aStr, bStr, oStr;
  const float* vArr[5];
};

template<int MODE>
__global__ __launch_bounds__(256)
void gemm_k(GemmP p)
{
  __shared__ alignas(16) bfu16 As[128*64];
  __shared__ alignas(16) bfu16 Bs[128*64];
  const int tid  = threadIdx.x;
  const int z    = blockIdx.z;
  const int m0   = blockIdx.y * 128, n0 = blockIdx.x * 128;
  const int lane = tid & 63;
  const int wv   = tid >> 6;
  const int wr   = (wv >> 1) * 64, wc = (wv & 1) * 64;

  const bfu16* A  = p.A;
  const bfu16* Bt = p.Bt;
  size_t koff = 0;
  if constexpr (MODE == 7) { A += (size_t)z * p.aStr; Bt += (size_t)z * p.bStr; }
  if constexpr (MODE == 6) { koff = (size_t)z * p.kChunk; }

  f32x4 acc[4][4];
  const f32x4 zero = {0.f, 0.f, 0.f, 0.f};
#pragma unroll
  for (int i = 0; i < 4; ++i)
#pragma unroll
    for (int j = 0; j < 4; ++j) acc[i][j] = zero;

  const int srow = tid >> 3;
  const int scol = (tid & 7) * 8;
  const int ldk  = p.ldk;

  for (int kb = 0; kb < p.kIters; ++kb) {
    const bfu16* ga = A  + (size_t)m0 * ldk + koff + kb * 64;
    const bfu16* gb = Bt + (size_t)n0 * ldk + koff + kb * 64;
#pragma unroll
    for (int it = 0; it < 4; ++it) {
      int r = it * 32 + srow;
      gload16(ga + (size_t)r * ldk + scol, As + r * 64 + scol);
      gload16(gb + (size_t)r * ldk + scol, Bs + r * 64 + scol);
    }
    __syncthreads();
#pragma unroll
    for (int kk = 0; kk < 2; ++kk) {
      const int ko = kk * 32 + (lane >> 4) * 8;
      short8 a[4], b[4];
#pragma unroll
      for (int i = 0; i < 4; ++i)
        a[i] = *(const short8*)(As + (wr + i * 16 + (lane & 15)) * 64 + ko);
#pragma unroll
      for (int j = 0; j < 4; ++j)
        b[j] = *(const short8*)(Bs + (wc + j * 16 + (lane & 15)) * 64 + ko);
#pragma unroll
      for (int i = 0; i < 4; ++i)
#pragma unroll
        for (int j = 0; j < 4; ++j)
          acc[i][j] = __builtin_amdgcn_mfma_f32_16x16x32_bf16(a[i], b[j], acc[i][j], 0, 0, 0);
    }
    __syncthreads();
  }

  const int cb = n0 + wc + (lane & 15);
  const int rb = m0 + wr + ((lane >> 4) << 2);
#pragma unroll
  for (int i = 0; i < 4; ++i) {
#pragma unroll
    for (int j = 0; j < 4; ++j) {
      int col = cb + j * 16;
#pragma unroll
      for (int q = 0; q < 4; ++q) {
        int row = rb + i * 16 + q;
        float v = acc[i][j][q];
        if constexpr (MODE == 4) {
          p.of[(size_t)row * p.ldo + col] = -__expf(p.vArr[0][col] + v);
        } else if constexpr (MODE == 6) {
          p.ob[(size_t)z * p.pStride + (size_t)row * p.ldo + col] = f2b(v);
        } else if constexpr (MODE == 7) {
          size_t idx = (size_t)row * C_ + col;
          (p.ob + (size_t)z * p.oStr)[idx] =
              f2b(b2f(p.xh[idx]) + b2f(p.xxh[idx]) * (p.vArr[z][col] + v));
        }
      }
    }
  }
}

// ---------------------------------------------------------------------------
// split-K reduce (bf16 partials) + tanh -> bf16.
// OUT=0: mtan scatter [f][row][d]; OUT=1: wtan.  NS = K-chunk count.
// ---------------------------------------------------------------------------
template<int OUT, int NS>
__global__ __launch_bounds__(256)
void redk_tanh(const bfu16* __restrict__ part, size_t pStr, int ldo, int ncols,
               bfu16* __restrict__ out)
{
  int id = blockIdx.x * 256 + threadIdx.x;
  int row = id / ncols, col = id % ncols;
  if (row >= BT_) return;
  float v = 0.f;
#pragma unroll
  for (int s = 0; s < NS; ++s) v += b2f(part[(size_t)s * pStr + (size_t)row * ldo + col]);
  bfu16 tv = f2b(tanhf(v));
  if constexpr (OUT == 0)
    out[((size_t)(col >> 5) * BT_ + row) * 64 + (col & 31)] = tv;
  else
    out[(size_t)row * 64 + col] = tv;
}

// sum of 4 bf16 partial planes -> f32 out
__global__ __launch_bounds__(256)
void redk_sum4(const bfu16* __restrict__ p0, float* __restrict__ out)
{
  size_t i = ((size_t)blockIdx.x * 256 + threadIdx.x) * 4;
  const size_t str = (size_t)2048 * 2048;
  uint2 a = *(const uint2*)(p0 + i);
  uint2 b = *(const uint2*)(p0 + str + i);
  uint2 c = *(const uint2*)(p0 + 2 * str + i);
  uint2 d = *(const uint2*)(p0 + 3 * str + i);
  float4 r;
  r.x = b2fu(a.x & 0xffffu) + b2fu(b.x & 0xffffu) + b2fu(c.x & 0xffffu) + b2fu(d.x & 0xffffu);
  r.y = b2fu(a.x >> 16)     + b2fu(b.x >> 16)     + b2fu(c.x >> 16)     + b2fu(d.x >> 16);
  r.z = b2fu(a.y & 0xffffu) + b2fu(b.y & 0xffffu) + b2fu(c.y & 0xffffu) + b2fu(d.y & 0xffffu);
  r.w = b2fu(a.y >> 16)     + b2fu(b.y >> 16)     + b2fu(c.y >> 16)     + b2fu(d.y >> 16);
  *(float4*)(out + i) = r;
}

// ---------------------------------------------------------------------------
// All weight transposes (13 jobs) + prep_xx (blocks >= prepStart) in ONE
// launch. Transpose: f32 [R][Cc] -> bf16 dst[c*ldd+r], rows [R,Rpad) zeroed.
// Prep: xx = shift(x)-x (bf16); xxx = bf16(x+xx*maa_x); xh = bf16(x).
// ---------------------------------------------------------------------------
struct TrJob { const float* src; bfu16* dst; int R, Cc, Rpad, ldd, gx, start; };
struct TrAllP {
  TrJob j[13];
  const float* x; const float* maa_x;
  bfu16* xxh; bfu16* xxx; bfu16* xh;
  int prepStart;
};

__global__ __launch_bounds__(256)
void transpose_all(TrAllP p)
{
  __shared__ float tile[32][33];
  const int bid = blockIdx.x;
  if (bid >= p.prepStart) {
    size_t i = ((size_t)(bid - p.prepStart) * 256 + threadIdx.x) * 4;
    int c  = (int)(i & (C_ - 1));
    int bt = (int)(i >> 11);
    int t  = bt & (T_ - 1);
    float4 xv = *(const float4*)(p.x + i);
    float4 xp = {0.f, 0.f, 0.f, 0.f};
    if (t > 0) xp = *(const float4*)(p.x + i - C_);
    float4 mx = *(const float4*)(p.maa_x + c);
    float dx = xp.x - xv.x, dy = xp.y - xv.y, dz = xp.z - xv.z, dw = xp.w - xv.w;
    uint2 w0;
    w0.x = (uint32_t)f2b(dx) | ((uint32_t)f2b(dy) << 16);
    w0.y = (uint32_t)f2b(dz) | ((uint32_t)f2b(dw) << 16);
    *(uint2*)(p.xxh + i) = w0;
    uint2 w1;
    w1.x = (uint32_t)f2b(xv.x + dx * mx.x) | ((uint32_t)f2b(xv.y + dy * mx.y) << 16);
    w1.y = (uint32_t)f2b(xv.z + dz * mx.z) | ((uint32_t)f2b(xv.w + dw * mx.w) << 16);
    *(uint2*)(p.xxx + i) = w1;
    uint2 w2;
    w2.x = (uint32_t)f2b(xv.x) | ((uint32_t)f2b(xv.y) << 16);
    w2.y = (uint32_t)f2b(xv.z) | ((uint32_t)f2b(xv.w) << 16);
    *(uint2*)(p.xh + i) = w2;
    return;
  }
  int k = 0;
#pragma unroll
  for (int t = 1; t < 13; ++t) if (bid >= p.j[t].start) k = t;
  const TrJob jb = p.j[k];
  const int local = bid - jb.start;
  const int bx = local % jb.gx, by = local / jb.gx;
  const int tx = threadIdx.x & 31, ty = threadIdx.x >> 5;
  const int r0 = by * 32, c0 = bx * 32;
#pragma unroll
  for (int i = 0; i < 4; ++i) {
    int r = r0 + ty + i * 8, c = c0 + tx;
    tile[ty + i * 8][tx] = (r < jb.R && c < jb.Cc) ? jb.src[(size_t)r * jb.Cc + c] : 0.f;
  }
  __syncthreads();
#pragma unroll
  for (int i = 0; i < 4; ++i) {
    int c = c0 + ty + i * 8, r = r0 + tx;
    if (c < jb.Cc && r < jb.Rpad) jb.dst[(size_t)c * jb.ldd + r] = f2b(tile[tx][ty + i * 8]);
  }
}

// ---------------------------------------------------------------------------
// WKV6 chunked scan, chunk L=32. w input is ALREADY lw = -exp(w).
// ---------------------------------------------------------------------------
#define S32 68   // LDS row stride (floats) for 32-row tiles

__global__ __launch_bounds__(256)
void wkv_a32(const float* __restrict__ r, const float* __restrict__ k,
             const float* __restrict__ v, const float* __restrict__ w,
             const float* __restrict__ u, float* __restrict__ rp,
             float* __restrict__ y, float* __restrict__ U, float* __restrict__ G)
{
  __shared__ float rw[32 * S32];
  __shared__ float kk[32 * S32];
  __shared__ float vv[32 * S32];
  __shared__ float Ps[32 * S32];
  __shared__ float red[256];
  __shared__ float diag[32];
  __shared__ float Gl[64];

  const int blk = blockIdx.x;
  const int bh = blk >> 5, c = blk & 31;
  const int b = bh >> 5, h = bh & 31;
  const int tid = threadIdx.x;
  const size_t gbase = ((size_t)(b * T_ + c * 32)) * C_ + h * 64;

  {
    const int t = tid >> 3, q = tid & 7;
    const size_t g = gbase + (size_t)t * C_ + q * 8;
    const int l = t * S32 + q * 8;
    *(float4*)(rw + l)     = *(const float4*)(r + g);
    *(float4*)(rw + l + 4) = *(const float4*)(r + g + 4);
    *(float4*)(kk + l)     = *(const float4*)(k + g);
    *(float4*)(kk + l + 4) = *(const float4*)(k + g + 4);
    *(float4*)(vv + l)     = *(const float4*)(v + g);
    *(float4*)(vv + l + 4) = *(const float4*)(v + g + 4);
    *(float4*)(Ps + l)     = *(const float4*)(w + g);
    *(float4*)(Ps + l + 4) = *(const float4*)(w + g + 4);
  }
  __syncthreads();

  // segmented prefix over t (4 segments of 8), per-j
  {
    const int seg = tid >> 6, j = tid & 63;
    float loc = 0.f;
#pragma unroll
    for (int tt = 0; tt < 8; ++tt) loc += Ps[(seg * 8 + tt) * S32 + j];
    red[seg * 64 + j] = loc;
  }
  __syncthreads();
  {
    const int seg = tid >> 6, j = tid & 63;
    float cs = 0.f;
    for (int s = 0; s < seg; ++s) cs += red[s * 64 + j];
    const float uj = u[h * 64 + j];
#pragma unroll
    for (int tt = 0; tt < 8; ++tt) {
      const int a = (seg * 8 + tt) * S32 + j;
      float lw = Ps[a];
      float rv = rw[a] * __expf(cs);
      rw[a] = rv;
      cs += lw;
      float kv = kk[a] * __expf(-cs);
      kk[a] = kv;
      Ps[a] = rv * kv * uj * __expf(lw);   // D (exact)
    }
    if (seg == 3) {
      float Gj = __expf(cs);
      Gl[j] = Gj;
      G[((size_t)bh * 32 + c) * 64 + j] = Gj;
    }
  }
  __syncthreads();

  // diag[t] = sum_j D[t][j]
  {
    const int t = tid & 31, q = tid >> 5;
    float s = 0.f;
#pragma unroll
    for (int jj = 0; jj < 8; ++jj) s += Ps[t * S32 + q * 8 + jj];
    red[q * 32 + t] = s;
  }
  __syncthreads();
  if (tid < 32) {
    float d = 0.f;
#pragma unroll
    for (int q = 0; q < 8; ++q) d += red[q * 32 + tid];
    diag[tid] = d;
  }
  __syncthreads();

  // scores: 2x2 tiles over 16x16 thread grid, lower-tri
  {
    const int tq = tid >> 4, sq = tid & 15;
    float a00 = 0.f, a01 = 0.f, a10 = 0.f, a11 = 0.f;
    if (sq <= tq) {
      for (int j = 0; j < 64; j += 4) {
        float4 r0 = *(const float4*)(rw + (2 * tq + 0) * S32 + j);
        float4 r1 = *(const float4*)(rw + (2 * tq + 1) * S32 + j);
        float4 k0 = *(const float4*)(kk + (2 * sq + 0) * S32 + j);
        float4 k1 = *(const float4*)(kk + (2 * sq + 1) * S32 + j);
        a00 += r0.x * k0.x + r0.y * k0.y + r0.z * k0.z + r0.w * k0.w;
        a01 += r0.x * k1.x + r0.y * k1.y + r0.z * k1.z + r0.w * k1.w;
        a10 += r1.x * k0.x + r1.y * k0.y + r1.z * k0.z + r1.w * k0.w;
        a11 += r1.x * k1.x + r1.y * k1.y + r1.z * k1.z + r1.w * k1.w;
      }
    }
    __syncthreads();
    if (sq <= tq) {
      const float av[2][2] = {{a00, a01}, {a10, a11}};
#pragma unroll
      for (int tt = 0; tt < 2; ++tt)
#pragma unroll
        for (int ss = 0; ss < 2; ++ss) {
          int t = 2 * tq + tt, s = 2 * sq + ss;
          Ps[t * S32 + s] = (s < t) ? av[tt][ss] : (s == t ? diag[t] : 0.f);
        }
    }
  }
  __syncthreads();

  // O_intra[t][i] = sum_{s<=t} P[t][s] * v[s][i]  -> y
  {
    const int tq = tid >> 4, iq = tid & 15;
    float o0[4] = {0.f, 0.f, 0.f, 0.f}, o1[4] = {0.f, 0.f, 0.f, 0.f};
    const int tmax = 2 * tq + 1;
    for (int s = 0; s <= tmax; ++s) {
      float4 vx = *(const float4*)(vv + s * S32 + iq * 4);
      float p0 = Ps[(2 * tq + 0) * S32 + s];
      float p1 = Ps[(2 * tq + 1) * S32 + s];
      o0[0] += p0 * vx.x; o0[1] += p0 * vx.y; o0[2] += p0 * vx.z; o0[3] += p0 * vx.w;
      o1[0] += p1 * vx.x; o1[1] += p1 * vx.y; o1[2] += p1 * vx.z; o1[3] += p1 * vx.w;
    }
    float4 w0 = {o0[0], o0[1], o0[2], o0[3]};
    float4 w1 = {o1[0], o1[1], o1[2], o1[3]};
    *(float4*)(y + gbase + (size_t)(2 * tq + 0) * C_ + iq * 4) = w0;
    *(float4*)(y + gbase + (size_t)(2 * tq + 1) * C_ + iq * 4) = w1;
  }

  // U[j][i] = G[j] * sum_s k~[s][j] * v[s][i]
  {
    const int jq = tid >> 4, iq = tid & 15;
    float ua[4][4] = {{0.f}};
    for (int s = 0; s < 32; ++s) {
      float4 kx = *(const float4*)(kk + s * S32 + jq * 4);
      float4 vx = *(const float4*)(vv + s * S32 + iq * 4);
      ua[0][0] += kx.x * vx.x; ua[0][1] += kx.x * vx.y; ua[0][2] += kx.x * vx.z; ua[0][3] += kx.x * vx.w;
      ua[1][0] += kx.y * vx.x; ua[1][1] += kx.y * vx.y; ua[1][2] += kx.y * vx.z; ua[1][3] += kx.y * vx.w;
      ua[2][0] += kx.z * vx.x; ua[2][1] += kx.z * vx.y; ua[2][2] += kx.z * vx.z; ua[2][3] += kx.z * vx.w;
      ua[3][0] += kx.w * vx.x; ua[3][1] += kx.w * vx.y; ua[3][2] += kx.w * vx.z; ua[3][3] += kx.w * vx.w;
    }
    const size_t ub = ((size_t)bh * 32 + c) * 4096;
#pragma unroll
    for (int jj = 0; jj < 4; ++jj) {
      float g = Gl[jq * 4 + jj];
      float4 uv = {ua[jj][0] * g, ua[jj][1] * g, ua[jj][2] * g, ua[jj][3] * g};
      *(float4*)(U + ub + (size_t)(jq * 4 + jj) * 64 + iq * 4) = uv;
    }
  }

  // write r' back (for phase C)
  {
    const int t = tid >> 3, q = tid & 7;
    const size_t g = gbase + (size_t)t * C_ + q * 8;
    const int l = t * S32 + q * 8;
    *(float4*)(rp + g)     = *(const float4*)(rw + l);
    *(float4*)(rp + g + 4) = *(const float4*)(rw + l + 4);
  }
}

// ---------------------------------------------------------------------------
// State scan: S_{c+1} = G_c*S_c + U_c. 256 blocks (bh x j-quarter), one
// float4 of i per thread, no LDS, no barriers.
// ---------------------------------------------------------------------------
__global__ __launch_bounds__(256)
void wkv_b32(const float* __restrict__ U, const float* __restrict__ G,
             float* __restrict__ Sbuf)
{
  const int bh = blockIdx.x >> 2, jq = blockIdx.x & 3;
  const int tid = threadIdx.x;
  const int j = jq * 16 + (tid >> 4);
  const int i = (tid & 15) * 4;
  float4 S = {0.f, 0.f, 0.f, 0.f};
  for (int c = 0; c < 32; ++c) {
    const size_t cb = ((size_t)bh * 32 + c);
    float g = G[cb * 64 + j];
    const size_t idx = cb * 4096 + (size_t)j * 64 + i;
    *(float4*)(Sbuf + idx) = S;
    float4 uv = *(const float4*)(U + idx);
    S.x = g * S.x + uv.x; S.y = g * S.y + uv.y;
    S.z = g * S.z + uv.z; S.w = g * S.w + uv.w;
  }
}

// ---------------------------------------------------------------------------
// Phase C + fused GroupNorm*silu(g) -> bf16 ygb.
// ---------------------------------------------------------------------------
__global__ __launch_bounds__(256)
void wkv_c32(const float* __restrict__ rp, const float* __restrict__ Sbuf,
             const float* __restrict__ y, const float* __restrict__ gpre,
             const float* __restrict__ lng, const float* __restrict__ lnb,
             bfu16* __restrict__ yg)
{
  __shared__ float Sl[64 * S32];
  __shared__ float rl[32 * S32];
  const int blk = blockIdx.x;
  const int bh = blk >> 5, c = blk & 31;
  const int b = bh >> 5, h = bh & 31;
  const int tid = threadIdx.x;
  const size_t gbase = ((size_t)(b * T_ + c * 32)) * C_ + h * 64;
  {
    const int j = tid >> 2, q = tid & 3;     // S: 64 rows x 64 cols
    const size_t sb = ((size_t)bh * 32 + c) * 4096 + (size_t)j * 64 + q * 16;
    const int l = j * S32 + q * 16;
#pragma unroll
    for (int p = 0; p < 4; ++p)
      *(float4*)(Sl + l + p * 4) = *(const float4*)(Sbuf + sb + p * 4);
    const int t = tid >> 3, q8 = tid & 7;    // r': 32 rows x 64 cols
    const size_t gr = gbase + (size_t)t * C_ + q8 * 8;
    const int lr = t * S32 + q8 * 8;
    *(float4*)(rl + lr)     = *(const float4*)(rp + gr);
    *(float4*)(rl + lr + 4) = *(const float4*)(rp + gr + 4);
  }
  __syncthreads();
  const int tq = tid >> 4, iq = tid & 15;
  float o0[4] = {0.f, 0.f, 0.f, 0.f}, o1[4] = {0.f, 0.f, 0.f, 0.f};
  for (int j = 0; j < 64; ++j) {
    float4 sv = *(const float4*)(Sl + j * S32 + iq * 4);
    float r0 = rl[(2 * tq + 0) * S32 + j];
    float r1 = rl[(2 * tq + 1) * S32 + j];
    o0[0] += r0 * sv.x; o0[1] += r0 * sv.y; o0[2] += r0 * sv.z; o0[3] += r0 * sv.w;
    o1[0] += r1 * sv.x; o1[1] += r1 * sv.y; o1[2] += r1 * sv.z; o1[3] += r1 * sv.w;
  }
#pragma unroll
  for (int rr = 0; rr < 2; ++rr) {
    float* o = rr ? o1 : o0;
    const size_t rowb = gbase + (size_t)(2 * tq + rr) * C_;
    float4 yi = *(const float4*)(y + rowb + iq * 4);
    float yv[4] = {yi.x + o[0], yi.y + o[1], yi.z + o[2], yi.w + o[3]};
    float s = yv[0] + yv[1] + yv[2] + yv[3];
    float sq = yv[0] * yv[0] + yv[1] * yv[1] + yv[2] * yv[2] + yv[3] * yv[3];
#pragma unroll
    for (int m = 1; m < 16; m <<= 1) {
      s  += __shfl_xor(s, m, 64);
      sq += __shfl_xor(sq, m, 64);
    }
    float mu  = s * (1.f / 64.f);
    float var = sq * (1.f / 64.f) - mu * mu;
    float rs  = rsqrtf(var + EPS_GN);
    float4 gp = *(const float4*)(gpre + rowb + iq * 4);
    const float gpv[4] = {gp.x, gp.y, gp.z, gp.w};
    uint32_t pk[2];
    ushort hw[4];
#pragma unroll
    for (int e = 0; e < 4; ++e) {
      int cidx = h * 64 + iq * 4 + e;
      float yn = (yv[e] - mu) * rs * lng[cidx] + lnb[cidx];
      float gs = gpv[e] / (1.f + __expf(-gpv[e]));
      hw[e] = f2b(yn * gs);
    }
    pk[0] = (uint32_t)hw[0] | ((uint32_t)hw[1] << 16);
    pk[1] = (uint32_t)hw[2] | ((uint32_t)hw[3] << 16);
    *(uint2*)(yg + rowb + iq * 4) = make_uint2(pk[0], pk[1]);
  }
}

// ---------------------------------------------------------------------------
extern "C" void kernel_launch(void* const* d_in, const int* in_sizes, int n_in,
                              void* d_out, int out_size, void* d_ws, size_t ws_size,
                              hipStream_t stream)
{
  const float* x      = (const float*)d_in[0];
  const float* maa_x  = (const float*)d_in[1];
  const float* maa_w  = (const float*)d_in[2];
  const float* maa_k  = (const float*)d_in[3];
  const float* maa_v  = (const float*)d_in[4];
  const float* maa_r  = (const float*)d_in[5];
  const float* maa_g  = (const float*)d_in[6];
  const float* tdec   = (const float*)d_in[7];
  const float* u      = (const float*)d_in[8];
  const float* maa_w1 = (const float*)d_in[9];
  const float* maa_w2 = (const float*)d_in[10];
  const float* td_w1  = (const float*)d_in[11];
  const float* td_w2  = (const float*)d_in[12];
  const float* lng = (const float*)d_in[18];
  const float* lnb = (const float*)d_in[19];
  float* out = (float*)d_out;

  char* wsp = (char*)d_ws;
  auto alloc = [&](size_t bytes) -> char* {
    char* p = wsp;
    wsp += (bytes + 255) & ~(size_t)255;
    return p;
  };

  bfu16* WT0 = (bfu16*)alloc((size_t)5 * 2048 * 2048 * 2);  // WT[z] = WT0 + z*4M
  bfu16* w1T  = (bfu16*)alloc((size_t)256 * 2048 * 2);
  bfu16* tw1T = (bfu16*)alloc((size_t)128 * 2048 * 2);
  bfu16* tw2T = (bfu16*)alloc((size_t)2048 * 64 * 2);
  bfu16* w2T  = (bfu16*)alloc((size_t)5 * 2048 * 64 * 2);
  float* ybuf = (float*)alloc((size_t)BT_ * C_ * 4);
  bfu16* xxh  = (bfu16*)alloc((size_t)BT_ * C_ * 2);
  bfu16* xxx  = (bfu16*)alloc((size_t)BT_ * C_ * 2);
  bfu16* xh   = (bfu16*)alloc((size_t)BT_ * C_ * 2);
  bfu16* mtan = (bfu16*)alloc((size_t)5 * BT_ * 64 * 2);
  bfu16* xmix0 = (bfu16*)alloc((size_t)5 * BT_ * C_ * 2); // xmix[f] = xmix0 + f*BT*C
  float* rbuf = (float*)alloc((size_t)4 * BT_ * C_ * 4);  // r,k,v,g contiguous
  float* kbuf = rbuf + (size_t)BT_ * C_;
  float* vbuf = kbuf + (size_t)BT_ * C_;
  float* gbuf = vbuf + (size_t)BT_ * C_;
  float* wbuf = (float*)alloc((size_t)BT_ * C_ * 4);
  bfu16* wtan = (bfu16*)alloc((size_t)BT_ * 64 * 2);
  float* Sbuf = (float*)alloc((size_t)64 * 32 * 4096 * 4);  // 32 MB
  float* Gbuf = (float*)alloc((size_t)64 * 32 * 64 * 4);    // 512 KB
  // Aliases (dead-by-then, stream-ordered):
  bfu16* ygb  = xxx;
  float* Ubuf = (float*)(xmix0 + (size_t)1 * BT_ * C_);  // 32MB over xmix[1..4]
  bfu16* part1 = (bfu16*)rbuf;  // m-path bf16 partials [8][BT][256] (pre-GEMM)
  bfu16* part3 = (bfu16*)wbuf;  // w-path bf16 partials [16][BT][128] (pre-MODE4)
  bfu16* partW = (bfu16*)rbuf;  // Wo bf16 partials [4][2048][2048] (post-wkv_c)

  // mtan K-pad must stay zero (pad cols multiply real B rows)
  hipMemsetAsync(mtan, 0, (size_t)5 * BT_ * 64 * 2, stream);

  dim3 tb(256);

  // ---- all weight transposes + prep_xx, one launch ----
  {
    TrAllP p{};
    int s = 0;
    for (int i = 0; i < 5; ++i) {
      p.j[i] = TrJob{ (const float*)d_in[13 + i], WT0 + (size_t)i * 2048 * 2048,
                      2048, 2048, 2048, 2048, 64, s };
      s += 64 * 64;
    }
    p.j[5] = TrJob{ maa_w1, w1T, 2048, 160, 2048, 2048, 5, s };  s += 5 * 64;
    p.j[6] = TrJob{ td_w1, tw1T, 2048, 64, 2048, 2048, 2, s };   s += 2 * 64;
    p.j[7] = TrJob{ td_w2, tw2T, 64, 2048, 64, 64, 64, s };      s += 64 * 2;
    for (int f = 0; f < 5; ++f) {
      p.j[8 + f] = TrJob{ maa_w2 + (size_t)f * 32 * 2048, w2T + (size_t)f * 2048 * 64,
                          32, 2048, 64, 64, 64, s };
      s += 64 * 2;
    }
    p.x = x; p.maa_x = maa_x; p.xxh = xxh; p.xxx = xxx; p.xh = xh;
    p.prepStart = s;
    s += (BT_ * C_ / 4) / 256;   // 4096 prep blocks
    transpose_all<<<dim3(s), tb, 0, stream>>>(p);
  }

  // ---- m-path: split-K GEMM (xxx @ maa_w1), bf16 partials ----
  {
    GemmP p{}; p.A = xxx; p.Bt = w1T; p.ldk = 2048; p.kIters = 4; p.kChunk = 256;
    p.ldo = 256; p.pStride = (size_t)BT_ * 256; p.ob = part1;
    gemm_k<6><<<dim3(2, 16, 8), tb, 0, stream>>>(p);
  }
  redk_tanh<0, 8><<<dim3(BT_ * 160 / 256), tb, 0, stream>>>(part1, (size_t)BT_ * 256, 256, 160, mtan);

  // ---- token-mix: batched-5 (mtan[f] @ w2T[f]) with xh+xxh epilogue ----
  {
    GemmP p{}; p.A = mtan; p.Bt = w2T; p.ldk = 64; p.kIters = 1;
    p.aStr = (size_t)BT_ * 64; p.bStr = (size_t)2048 * 64; p.oStr = (size_t)BT_ * C_;
    p.ob = xmix0; p.xh = xh; p.xxh = xxh;
    p.vArr[0] = maa_w; p.vArr[1] = maa_k; p.vArr[2] = maa_v; p.vArr[3] = maa_r; p.vArr[4] = maa_g;
    gemm_k<7><<<dim3(16, 16, 5), tb, 0, stream>>>(p);
  }

  // ---- r,k,v,g: batched-4 256^2 swizzled GEMMs (frozen champion) ----
  {
    G256P p{}; p.Bt = WT0; p.ldk = 2048; p.nkt = 32; p.kSplit = 1;
    p.bStr = (size_t)2048 * 2048; p.oStr = (size_t)BT_ * C_; p.of = rbuf;
    p.aArr[0] = xmix0 + (size_t)3 * BT_ * C_;  // xr
    p.aArr[1] = xmix0 + (size_t)1 * BT_ * C_;  // xk
    p.aArr[2] = xmix0 + (size_t)2 * BT_ * C_;  // xv
    p.aArr[3] = xmix0 + (size_t)4 * BT_ * C_;  // xg
    gemm256<0><<<dim3(8, 8, 4), dim3(512), 131072, stream>>>(p);
  }

  // ---- w-path: split-K thin GEMM (xw @ td_w1), 16 chunks, bf16 partials ----
  {
    GemmP p{}; p.A = xmix0; p.Bt = tw1T; p.ldk = 2048; p.kIters = 2; p.kChunk = 128;
    p.ldo = 128; p.pStride = (size_t)BT_ * 128; p.ob = part3;
    gemm_k<6><<<dim3(1, 16, 16), tb, 0, stream>>>(p);
  }
  redk_tanh<1, 16><<<dim3(BT_ * 64 / 256), tb, 0, stream>>>(part3, (size_t)BT_ * 128, 128, 64, wtan);

  // ---- w-path: wbuf = lw = -exp(tdec + wtan @ td_w2)  (fused) ----
  {
    GemmP p{}; p.A = wtan; p.Bt = tw2T; p.ldk = 64; p.kIters = 1;
    p.of = wbuf; p.ldo = 2048; p.vArr[0] = tdec;
    gemm_k<4><<<dim3(16, 16, 1), tb, 0, stream>>>(p);
  }

  // ---- chunked WKV6 (L=32) + fused GroupNorm*silu ----
  wkv_a32<<<dim3(2048), tb, 0, stream>>>(rbuf, kbuf, vbuf, wbuf, u, rbuf, ybuf, Ubuf, Gbuf);
  wkv_b32<<<dim3(256),  tb, 0, stream>>>(Ubuf, Gbuf, Sbuf);
  wkv_c32<<<dim3(2048), tb, 0, stream>>>(rbuf, Sbuf, ybuf, gbuf, lng, lnb, ygb);

  // ---- out = yg @ Wo  (256^2 frozen schedule, K-split 4, bf16 partials) ----
  {
    G256P p{}; p.Bt = WT0 + (size_t)4 * 2048 * 2048; p.ldk = 2048;
    p.nkt = 8; p.kSplit = 4;
    p.bStr = 0; p.oStr = (size_t)2048 * 2048; p.ob = partW;
    p.aArr[0] = ygb;
    gemm256<1><<<dim3(8, 8, 4), dim3(512), 131072, stream>>>(p);
  }
  redk_sum4<<<dim3(4096), tb, 0, stream>>>(partW, out);
}

// Round 14
// 283.058 us; speedup vs baseline: 1.1527x; 1.0399x over previous
//
#include <hip/hip_runtime.h>
#include <cstdint>
#include <cstddef>

// Problem constants (fixed by the reference)
#define B_  2
#define T_  1024
#define C_  2048
#define H_  32
#define BT_ (B_*T_)
static constexpr float EPS_GN = 1e-5f * 64.0f;

using short8 = __attribute__((ext_vector_type(8))) short;
using f32x4  = __attribute__((ext_vector_type(4))) float;
typedef unsigned short bfu16;

__device__ __forceinline__ bfu16 f2b(float f) {
  uint32_t x = __float_as_uint(f);
  uint32_t r = (x + 0x7FFFu + ((x >> 16) & 1u)) >> 16;
  return (bfu16)r;
}
__device__ __forceinline__ float b2f(bfu16 h) {
  return __uint_as_float(((uint32_t)h) << 16);
}
__device__ __forceinline__ float b2fu(uint32_t w) {   // low half of packed
  return __uint_as_float(w << 16);
}

__device__ __forceinline__ void gload16(const bfu16* g, bfu16* l) {
  __builtin_amdgcn_global_load_lds((__attribute__((address_space(1))) void*)g,
                                   (__attribute__((address_space(3))) void*)l,
                                   16, 0, 0);
}

// ---------------------------------------------------------------------------
// gemm256 (round-7 proven schedule, FROZEN): 256x256 tile, BK=64, 512 thr
// (8 waves 2Mx4N), dbuf LDS 128KB. STAGE_A(next); vmcnt(4); barrier; per-ks
// {STAGE_B(next) at ks==1; ds_read frags; MFMA}; barrier.
// LDS XOR-swizzle: source col ^((row&7)<<3), read col ^((lane&7)<<3).
// XCD-aware bijective block swizzle (nwg % 8 == 0 required).
// OB=0: f32 output (p.of). OB=1: bf16 output (p.ob) -- split-K partials.
// ---------------------------------------------------------------------------
struct G256P {
  const bfu16* Bt; float* of; bfu16* ob;
  size_t bStr, oStr;
  int ldk, nkt, kSplit;
  const bfu16* aArr[4];
};

template<int OB>
__global__ __launch_bounds__(512, 2)
void gemm256(G256P p)
{
  extern __shared__ __align__(16) bfu16 sm[];   // A0,A1,B0,B1 each 256*64
  const int tid  = threadIdx.x;
  const int nwg = gridDim.x * gridDim.y * gridDim.z;
  int lin = blockIdx.x + gridDim.x * (blockIdx.y + gridDim.y * blockIdx.z);
  lin = (lin & 7) * (nwg >> 3) + (lin >> 3);
  const int bx = lin % gridDim.x;
  const int by = (lin / gridDim.x) % gridDim.y;
  const int z  = lin / (gridDim.x * gridDim.y);
  const int m0   = by * 256, n0 = bx * 256;
  const int lane = tid & 63;
  const int wv   = tid >> 6;
  const int wm   = wv >> 2, wn = wv & 3;
  const int ldk  = p.ldk;

  const bfu16* A;
  size_t koff;
  if (p.kSplit > 1) { A = p.aArr[0]; koff = (size_t)z * p.nkt * 64; }
  else              { A = p.aArr[z]; koff = 0; }
  const bfu16* Bt = p.Bt + (size_t)z * p.bStr;

  const int srow = tid >> 3;        // 0..63
  const int scol = (tid & 7) * 8;   // 0..56
  const int sswz = (srow & 7) << 3; // source-side inverse swizzle
  const bfu16* gA = A  + (size_t)(m0 + srow) * ldk + koff + (scol ^ sswz);
  const bfu16* gB = Bt + (size_t)(n0 + srow) * ldk + koff + (scol ^ sswz);

  auto STAGE_A = [&](bfu16* dst, int kt) {
    const bfu16* g = gA + (size_t)kt * 64;
    bfu16* l = dst + srow * 64 + scol;
#pragma unroll
    for (int it = 0; it < 4; ++it)
      gload16(g + (size_t)it * 64 * ldk, l + it * 4096);
  };
  auto STAGE_B = [&](bfu16* dst, int kt) {
    const bfu16* g = gB + (size_t)kt * 64;
    bfu16* l = dst + srow * 64 + scol;
#pragma unroll
    for (int it = 0; it < 4; ++it)
      gload16(g + (size_t)it * 64 * ldk, l + it * 4096);
  };

  f32x4 acc[8][4];
  const f32x4 zero = {0.f, 0.f, 0.f, 0.f};
#pragma unroll
  for (int i = 0; i < 8; ++i)
#pragma unroll
    for (int j = 0; j < 4; ++j) acc[i][j] = zero;

  STAGE_A(sm, 0);
  STAGE_B(sm + 32768, 0);           // 8 outstanding

  const int rswz = (lane & 7) << 3; // read-side swizzle

  for (int kt = 0; kt < p.nkt; ++kt) {
    bfu16* curA = sm + (kt & 1) * 16384;
    bfu16* curB = sm + 32768 + (kt & 1) * 16384;
    bfu16* nxtA = sm + ((kt & 1) ^ 1) * 16384;
    bfu16* nxtB = sm + 32768 + ((kt & 1) ^ 1) * 16384;
    const bool more = (kt + 1 < p.nkt);
    if (more) {
      STAGE_A(nxtA, kt + 1);                       // 12 outstanding
      asm volatile("s_waitcnt vmcnt(4)" ::: "memory");  // cur buf landed
    } else {
      asm volatile("s_waitcnt vmcnt(0)" ::: "memory");
    }
    __builtin_amdgcn_s_barrier();

#pragma unroll
    for (int ks = 0; ks < 2; ++ks) {
      if (ks == 1 && more) STAGE_B(nxtB, kt + 1);
      const int ko = (ks * 32 + (lane >> 4) * 8) ^ rswz;
      short8 a[8], b[4];
#pragma unroll
      for (int i = 0; i < 8; ++i)
        a[i] = *(const short8*)(curA + (wm * 128 + i * 16 + (lane & 15)) * 64 + ko);
#pragma unroll
      for (int j = 0; j < 4; ++j)
        b[j] = *(const short8*)(curB + (wn * 64 + j * 16 + (lane & 15)) * 64 + ko);
      __builtin_amdgcn_s_setprio(1);
#pragma unroll
      for (int i = 0; i < 8; ++i)
#pragma unroll
        for (int j = 0; j < 4; ++j)
          acc[i][j] = __builtin_amdgcn_mfma_f32_16x16x32_bf16(a[i], b[j], acc[i][j], 0, 0, 0);
      __builtin_amdgcn_s_setprio(0);
    }
    __builtin_amdgcn_s_barrier();
  }

  const int cb = n0 + wn * 64 + (lane & 15);
  const int rb = m0 + wm * 128 + ((lane >> 4) << 2);
  if constexpr (OB == 0) {
    float* o = p.of + (size_t)z * p.oStr;
#pragma unroll
    for (int i = 0; i < 8; ++i)
#pragma unroll
      for (int j = 0; j < 4; ++j) {
        int col = cb + j * 16;
#pragma unroll
        for (int q = 0; q < 4; ++q)
          o[(size_t)(rb + i * 16 + q) * 2048 + col] = acc[i][j][q];
      }
  } else {
    bfu16* o = p.ob + (size_t)z * p.oStr;
#pragma unroll
    for (int i = 0; i < 8; ++i)
#pragma unroll
      for (int j = 0; j < 4; ++j) {
        int col = cb + j * 16;
#pragma unroll
        for (int q = 0; q < 4; ++q)
          o[(size_t)(rb + i * 16 + q) * 2048 + col] = f2b(acc[i][j][q]);
      }
  }
}

// ---------------------------------------------------------------------------
// 128x128 GEMM for the small/odd shapes.
// MODE 4: of = -exp(vArr[0][col] + acc)   (fused lw = -exp(w))
// MODE 6: split-K bf16 partials
// MODE 7: batched-5 token-mix epilogue (x and xx both bf16)
// ---------------------------------------------------------------------------
struct GemmP {
  const bfu16* A; const bfu16* Bt;
  float* of; bfu16* ob;
  const bfu16* xh; const bfu16* xxh;
  int ldk, kIters, kChunk, ldo;
  size_t pStride, aStr, bStr, oStr;
  const float* vArr[5];
};

template<int MODE>
__global__ __launch_bounds__(256)
void gemm_k(GemmP p)
{
  __shared__ alignas(16) bfu16 As[128*64];
  __shared__ alignas(16) bfu16 Bs[128*64];
  const int tid  = threadIdx.x;
  const int z    = blockIdx.z;
  const int m0   = blockIdx.y * 128, n0 = blockIdx.x * 128;
  const int lane = tid & 63;
  const int wv   = tid >> 6;
  const int wr   = (wv >> 1) * 64, wc = (wv & 1) * 64;

  const bfu16* A  = p.A;
  const bfu16* Bt = p.Bt;
  size_t koff = 0;
  if constexpr (MODE == 7) { A += (size_t)z * p.aStr; Bt += (size_t)z * p.bStr; }
  if constexpr (MODE == 6) { koff = (size_t)z * p.kChunk; }

  f32x4 acc[4][4];
  const f32x4 zero = {0.f, 0.f, 0.f, 0.f};
#pragma unroll
  for (int i = 0; i < 4; ++i)
#pragma unroll
    for (int j = 0; j < 4; ++j) acc[i][j] = zero;

  const int srow = tid >> 3;
  const int scol = (tid & 7) * 8;
  const int ldk  = p.ldk;

  for (int kb = 0; kb < p.kIters; ++kb) {
    const bfu16* ga = A  + (size_t)m0 * ldk + koff + kb * 64;
    const bfu16* gb = Bt + (size_t)n0 * ldk + koff + kb * 64;
#pragma unroll
    for (int it = 0; it < 4; ++it) {
      int r = it * 32 + srow;
      gload16(ga + (size_t)r * ldk + scol, As + r * 64 + scol);
      gload16(gb + (size_t)r * ldk + scol, Bs + r * 64 + scol);
    }
    __syncthreads();
#pragma unroll
    for (int kk = 0; kk < 2; ++kk) {
      const int ko = kk * 32 + (lane >> 4) * 8;
      short8 a[4], b[4];
#pragma unroll
      for (int i = 0; i < 4; ++i)
        a[i] = *(const short8*)(As + (wr + i * 16 + (lane & 15)) * 64 + ko);
#pragma unroll
      for (int j = 0; j < 4; ++j)
        b[j] = *(const short8*)(Bs + (wc + j * 16 + (lane & 15)) * 64 + ko);
#pragma unroll
      for (int i = 0; i < 4; ++i)
#pragma unroll
        for (int j = 0; j < 4; ++j)
          acc[i][j] = __builtin_amdgcn_mfma_f32_16x16x32_bf16(a[i], b[j], acc[i][j], 0, 0, 0);
    }
    __syncthreads();
  }

  const int cb = n0 + wc + (lane & 15);
  const int rb = m0 + wr + ((lane >> 4) << 2);
#pragma unroll
  for (int i = 0; i < 4; ++i) {
#pragma unroll
    for (int j = 0; j < 4; ++j) {
      int col = cb + j * 16;
#pragma unroll
      for (int q = 0; q < 4; ++q) {
        int row = rb + i * 16 + q;
        float v = acc[i][j][q];
        if constexpr (MODE == 4) {
          p.of[(size_t)row * p.ldo + col] = -__expf(p.vArr[0][col] + v);
        } else if constexpr (MODE == 6) {
          p.ob[(size_t)z * p.pStride + (size_t)row * p.ldo + col] = f2b(v);
        } else if constexpr (MODE == 7) {
          size_t idx = (size_t)row * C_ + col;
          (p.ob + (size_t)z * p.oStr)[idx] =
              f2b(b2f(p.xh[idx]) + b2f(p.xxh[idx]) * (p.vArr[z][col] + v));
        }
      }
    }
  }
}

// ---------------------------------------------------------------------------
// split-K reduce (bf16 partials) + tanh -> bf16.
// OUT=0: mtan scatter [f][row][d]; OUT=1: wtan.  NS = K-chunk count.
// ---------------------------------------------------------------------------
template<int OUT, int NS>
__global__ __launch_bounds__(256)
void redk_tanh(const bfu16* __restrict__ part, size_t pStr, int ldo, int ncols,
               bfu16* __restrict__ out)
{
  int id = blockIdx.x * 256 + threadIdx.x;
  int row = id / ncols, col = id % ncols;
  if (row >= BT_) return;
  float v = 0.f;
#pragma unroll
  for (int s = 0; s < NS; ++s) v += b2f(part[(size_t)s * pStr + (size_t)row * ldo + col]);
  bfu16 tv = f2b(tanhf(v));
  if constexpr (OUT == 0)
    out[((size_t)(col >> 5) * BT_ + row) * 64 + (col & 31)] = tv;
  else
    out[(size_t)row * 64 + col] = tv;
}

// sum of 4 bf16 partial planes -> f32 out
__global__ __launch_bounds__(256)
void redk_sum4(const bfu16* __restrict__ p0, float* __restrict__ out)
{
  size_t i = ((size_t)blockIdx.x * 256 + threadIdx.x) * 4;
  const size_t str = (size_t)2048 * 2048;
  uint2 a = *(const uint2*)(p0 + i);
  uint2 b = *(const uint2*)(p0 + str + i);
  uint2 c = *(const uint2*)(p0 + 2 * str + i);
  uint2 d = *(const uint2*)(p0 + 3 * str + i);
  float4 r;
  r.x = b2fu(a.x & 0xffffu) + b2fu(b.x & 0xffffu) + b2fu(c.x & 0xffffu) + b2fu(d.x & 0xffffu);
  r.y = b2fu(a.x >> 16)     + b2fu(b.x >> 16)     + b2fu(c.x >> 16)     + b2fu(d.x >> 16);
  r.z = b2fu(a.y & 0xffffu) + b2fu(b.y & 0xffffu) + b2fu(c.y & 0xffffu) + b2fu(d.y & 0xffffu);
  r.w = b2fu(a.y >> 16)     + b2fu(b.y >> 16)     + b2fu(c.y >> 16)     + b2fu(d.y >> 16);
  *(float4*)(out + i) = r;
}

// ---------------------------------------------------------------------------
// All weight transposes (13 jobs) + prep_xx (blocks >= prepStart) in ONE
// launch. Transpose: f32 [R][Cc] -> bf16 dst[c*ldd+r], rows [R,Rpad) zeroed.
// Prep: xx = shift(x)-x (bf16); xxx = bf16(x+xx*maa_x); xh = bf16(x).
// ---------------------------------------------------------------------------
struct TrJob { const float* src; bfu16* dst; int R, Cc, Rpad, ldd, gx, start; };
struct TrAllP {
  TrJob j[13];
  const float* x; const float* maa_x;
  bfu16* xxh; bfu16* xxx; bfu16* xh;
  int prepStart;
};

__global__ __launch_bounds__(256)
void transpose_all(TrAllP p)
{
  __shared__ float tile[32][33];
  const int bid = blockIdx.x;
  if (bid >= p.prepStart) {
    size_t i = ((size_t)(bid - p.prepStart) * 256 + threadIdx.x) * 4;
    int c  = (int)(i & (C_ - 1));
    int bt = (int)(i >> 11);
    int t  = bt & (T_ - 1);
    float4 xv = *(const float4*)(p.x + i);
    float4 xp = {0.f, 0.f, 0.f, 0.f};
    if (t > 0) xp = *(const float4*)(p.x + i - C_);
    float4 mx = *(const float4*)(p.maa_x + c);
    float dx = xp.x - xv.x, dy = xp.y - xv.y, dz = xp.z - xv.z, dw = xp.w - xv.w;
    uint2 w0;
    w0.x = (uint32_t)f2b(dx) | ((uint32_t)f2b(dy) << 16);
    w0.y = (uint32_t)f2b(dz) | ((uint32_t)f2b(dw) << 16);
    *(uint2*)(p.xxh + i) = w0;
    uint2 w1;
    w1.x = (uint32_t)f2b(xv.x + dx * mx.x) | ((uint32_t)f2b(xv.y + dy * mx.y) << 16);
    w1.y = (uint32_t)f2b(xv.z + dz * mx.z) | ((uint32_t)f2b(xv.w + dw * mx.w) << 16);
    *(uint2*)(p.xxx + i) = w1;
    uint2 w2;
    w2.x = (uint32_t)f2b(xv.x) | ((uint32_t)f2b(xv.y) << 16);
    w2.y = (uint32_t)f2b(xv.z) | ((uint32_t)f2b(xv.w) << 16);
    *(uint2*)(p.xh + i) = w2;
    return;
  }
  int k = 0;
#pragma unroll
  for (int t = 1; t < 13; ++t) if (bid >= p.j[t].start) k = t;
  const TrJob jb = p.j[k];
  const int local = bid - jb.start;
  const int bx = local % jb.gx, by = local / jb.gx;
  const int tx = threadIdx.x & 31, ty = threadIdx.x >> 5;
  const int r0 = by * 32, c0 = bx * 32;
#pragma unroll
  for (int i = 0; i < 4; ++i) {
    int r = r0 + ty + i * 8, c = c0 + tx;
    tile[ty + i * 8][tx] = (r < jb.R && c < jb.Cc) ? jb.src[(size_t)r * jb.Cc + c] : 0.f;
  }
  __syncthreads();
#pragma unroll
  for (int i = 0; i < 4; ++i) {
    int c = c0 + ty + i * 8, r = r0 + tx;
    if (c < jb.Cc && r < jb.Rpad) jb.dst[(size_t)c * jb.ldd + r] = f2b(tile[tx][ty + i * 8]);
  }
}

// ---------------------------------------------------------------------------
// WKV6 chunked scan, chunk L=32. w input is ALREADY lw = -exp(w).
// U output stored bf16 (inter-chunk contribution only; intra stays f32).
// ---------------------------------------------------------------------------
#define S32 68   // LDS row stride (floats) for 32-row tiles

__global__ __launch_bounds__(256)
void wkv_a32(const float* __restrict__ r, const float* __restrict__ k,
             const float* __restrict__ v, const float* __restrict__ w,
             const float* __restrict__ u, float* __restrict__ rp,
             float* __restrict__ y, bfu16* __restrict__ U, float* __restrict__ G)
{
  __shared__ float rw[32 * S32];
  __shared__ float kk[32 * S32];
  __shared__ float vv[32 * S32];
  __shared__ float Ps[32 * S32];
  __shared__ float red[256];
  __shared__ float diag[32];
  __shared__ float Gl[64];

  const int blk = blockIdx.x;
  const int bh = blk >> 5, c = blk & 31;
  const int b = bh >> 5, h = bh & 31;
  const int tid = threadIdx.x;
  const size_t gbase = ((size_t)(b * T_ + c * 32)) * C_ + h * 64;

  {
    const int t = tid >> 3, q = tid & 7;
    const size_t g = gbase + (size_t)t * C_ + q * 8;
    const int l = t * S32 + q * 8;
    *(float4*)(rw + l)     = *(const float4*)(r + g);
    *(float4*)(rw + l + 4) = *(const float4*)(r + g + 4);
    *(float4*)(kk + l)     = *(const float4*)(k + g);
    *(float4*)(kk + l + 4) = *(const float4*)(k + g + 4);
    *(float4*)(vv + l)     = *(const float4*)(v + g);
    *(float4*)(vv + l + 4) = *(const float4*)(v + g + 4);
    *(float4*)(Ps + l)     = *(const float4*)(w + g);
    *(float4*)(Ps + l + 4) = *(const float4*)(w + g + 4);
  }
  __syncthreads();

  // segmented prefix over t (4 segments of 8), per-j
  {
    const int seg = tid >> 6, j = tid & 63;
    float loc = 0.f;
#pragma unroll
    for (int tt = 0; tt < 8; ++tt) loc += Ps[(seg * 8 + tt) * S32 + j];
    red[seg * 64 + j] = loc;
  }
  __syncthreads();
  {
    const int seg = tid >> 6, j = tid & 63;
    float cs = 0.f;
    for (int s = 0; s < seg; ++s) cs += red[s * 64 + j];
    const float uj = u[h * 64 + j];
#pragma unroll
    for (int tt = 0; tt < 8; ++tt) {
      const int a = (seg * 8 + tt) * S32 + j;
      float lw = Ps[a];
      float rv = rw[a] * __expf(cs);
      rw[a] = rv;
      cs += lw;
      float kv = kk[a] * __expf(-cs);
      kk[a] = kv;
      Ps[a] = rv * kv * uj * __expf(lw);   // D (exact)
    }
    if (seg == 3) {
      float Gj = __expf(cs);
      Gl[j] = Gj;
      G[((size_t)bh * 32 + c) * 64 + j] = Gj;
    }
  }
  __syncthreads();

  // diag[t] = sum_j D[t][j]
  {
    const int t = tid & 31, q = tid >> 5;
    float s = 0.f;
#pragma unroll
    for (int jj = 0; jj < 8; ++jj) s += Ps[t * S32 + q * 8 + jj];
    red[q * 32 + t] = s;
  }
  __syncthreads();
  if (tid < 32) {
    float d = 0.f;
#pragma unroll
    for (int q = 0; q < 8; ++q) d += red[q * 32 + tid];
    diag[tid] = d;
  }
  __syncthreads();

  // scores: 2x2 tiles over 16x16 thread grid, lower-tri
  {
    const int tq = tid >> 4, sq = tid & 15;
    float a00 = 0.f, a01 = 0.f, a10 = 0.f, a11 = 0.f;
    if (sq <= tq) {
      for (int j = 0; j < 64; j += 4) {
        float4 r0 = *(const float4*)(rw + (2 * tq + 0) * S32 + j);
        float4 r1 = *(const float4*)(rw + (2 * tq + 1) * S32 + j);
        float4 k0 = *(const float4*)(kk + (2 * sq + 0) * S32 + j);
        float4 k1 = *(const float4*)(kk + (2 * sq + 1) * S32 + j);
        a00 += r0.x * k0.x + r0.y * k0.y + r0.z * k0.z + r0.w * k0.w;
        a01 += r0.x * k1.x + r0.y * k1.y + r0.z * k1.z + r0.w * k1.w;
        a10 += r1.x * k0.x + r1.y * k0.y + r1.z * k0.z + r1.w * k0.w;
        a11 += r1.x * k1.x + r1.y * k1.y + r1.z * k1.z + r1.w * k1.w;
      }
    }
    __syncthreads();
    if (sq <= tq) {
      const float av[2][2] = {{a00, a01}, {a10, a11}};
#pragma unroll
      for (int tt = 0; tt < 2; ++tt)
#pragma unroll
        for (int ss = 0; ss < 2; ++ss) {
          int t = 2 * tq + tt, s = 2 * sq + ss;
          Ps[t * S32 + s] = (s < t) ? av[tt][ss] : (s == t ? diag[t] : 0.f);
        }
    }
  }
  __syncthreads();

  // O_intra[t][i] = sum_{s<=t} P[t][s] * v[s][i]  -> y
  {
    const int tq = tid >> 4, iq = tid & 15;
    float o0[4] = {0.f, 0.f, 0.f, 0.f}, o1[4] = {0.f, 0.f, 0.f, 0.f};
    const int tmax = 2 * tq + 1;
    for (int s = 0; s <= tmax; ++s) {
      float4 vx = *(const float4*)(vv + s * S32 + iq * 4);
      float p0 = Ps[(2 * tq + 0) * S32 + s];
      float p1 = Ps[(2 * tq + 1) * S32 + s];
      o0[0] += p0 * vx.x; o0[1] += p0 * vx.y; o0[2] += p0 * vx.z; o0[3] += p0 * vx.w;
      o1[0] += p1 * vx.x; o1[1] += p1 * vx.y; o1[2] += p1 * vx.z; o1[3] += p1 * vx.w;
    }
    float4 w0 = {o0[0], o0[1], o0[2], o0[3]};
    float4 w1 = {o1[0], o1[1], o1[2], o1[3]};
    *(float4*)(y + gbase + (size_t)(2 * tq + 0) * C_ + iq * 4) = w0;
    *(float4*)(y + gbase + (size_t)(2 * tq + 1) * C_ + iq * 4) = w1;
  }

  // U[j][i] = G[j] * sum_s k~[s][j] * v[s][i]  (stored bf16)
  {
    const int jq = tid >> 4, iq = tid & 15;
    float ua[4][4] = {{0.f}};
    for (int s = 0; s < 32; ++s) {
      float4 kx = *(const float4*)(kk + s * S32 + jq * 4);
      float4 vx = *(const float4*)(vv + s * S32 + iq * 4);
      ua[0][0] += kx.x * vx.x; ua[0][1] += kx.x * vx.y; ua[0][2] += kx.x * vx.z; ua[0][3] += kx.x * vx.w;
      ua[1][0] += kx.y * vx.x; ua[1][1] += kx.y * vx.y; ua[1][2] += kx.y * vx.z; ua[1][3] += kx.y * vx.w;
      ua[2][0] += kx.z * vx.x; ua[2][1] += kx.z * vx.y; ua[2][2] += kx.z * vx.z; ua[2][3] += kx.z * vx.w;
      ua[3][0] += kx.w * vx.x; ua[3][1] += kx.w * vx.y; ua[3][2] += kx.w * vx.z; ua[3][3] += kx.w * vx.w;
    }
    const size_t ub = ((size_t)bh * 32 + c) * 4096;
#pragma unroll
    for (int jj = 0; jj < 4; ++jj) {
      float g = Gl[jq * 4 + jj];
      uint2 uvp;
      uvp.x = (uint32_t)f2b(ua[jj][0] * g) | ((uint32_t)f2b(ua[jj][1] * g) << 16);
      uvp.y = (uint32_t)f2b(ua[jj][2] * g) | ((uint32_t)f2b(ua[jj][3] * g) << 16);
      *(uint2*)(U + ub + (size_t)(jq * 4 + jj) * 64 + iq * 4) = uvp;
    }
  }

  // write r' back (for phase C)
  {
    const int t = tid >> 3, q = tid & 7;
    const size_t g = gbase + (size_t)t * C_ + q * 8;
    const int l = t * S32 + q * 8;
    *(float4*)(rp + g)     = *(const float4*)(rw + l);
    *(float4*)(rp + g + 4) = *(const float4*)(rw + l + 4);
  }
}

// ---------------------------------------------------------------------------
// State scan: S_{c+1} = G_c*S_c + U_c. 256 blocks (bh x j-quarter), f32
// accumulation in registers; U read bf16, S written bf16.
// ---------------------------------------------------------------------------
__global__ __launch_bounds__(256)
void wkv_b32(const bfu16* __restrict__ U, const float* __restrict__ G,
             bfu16* __restrict__ Sbuf)
{
  const int bh = blockIdx.x >> 2, jq = blockIdx.x & 3;
  const int tid = threadIdx.x;
  const int j = jq * 16 + (tid >> 4);
  const int i = (tid & 15) * 4;
  float4 S = {0.f, 0.f, 0.f, 0.f};
  for (int c = 0; c < 32; ++c) {
    const size_t cb = ((size_t)bh * 32 + c);
    float g = G[cb * 64 + j];
    const size_t idx = cb * 4096 + (size_t)j * 64 + i;
    uint2 sp;
    sp.x = (uint32_t)f2b(S.x) | ((uint32_t)f2b(S.y) << 16);
    sp.y = (uint32_t)f2b(S.z) | ((uint32_t)f2b(S.w) << 16);
    *(uint2*)(Sbuf + idx) = sp;
    uint2 uv = *(const uint2*)(U + idx);
    S.x = g * S.x + b2fu(uv.x & 0xffffu);
    S.y = g * S.y + b2fu(uv.x >> 16);
    S.z = g * S.z + b2fu(uv.y & 0xffffu);
    S.w = g * S.w + b2fu(uv.y >> 16);
  }
}

// ---------------------------------------------------------------------------
// Phase C + fused GroupNorm*silu(g) -> bf16 ygb.  S read bf16.
// ---------------------------------------------------------------------------
__global__ __launch_bounds__(256)
void wkv_c32(const float* __restrict__ rp, const bfu16* __restrict__ Sbuf,
             const float* __restrict__ y, const float* __restrict__ gpre,
             const float* __restrict__ lng, const float* __restrict__ lnb,
             bfu16* __restrict__ yg)
{
  __shared__ float Sl[64 * S32];
  __shared__ float rl[32 * S32];
  const int blk = blockIdx.x;
  const int bh = blk >> 5, c = blk & 31;
  const int b = bh >> 5, h = bh & 31;
  const int tid = threadIdx.x;
  const size_t gbase = ((size_t)(b * T_ + c * 32)) * C_ + h * 64;
  {
    const int j = tid >> 2, q = tid & 3;     // S: 64 rows x 64 cols bf16
    const size_t sb = ((size_t)bh * 32 + c) * 4096 + (size_t)j * 64 + q * 16;
    const int l = j * S32 + q * 16;
    uint4 s0 = *(const uint4*)(Sbuf + sb);       // 8 bf16
    uint4 s1 = *(const uint4*)(Sbuf + sb + 8);   // 8 bf16
    Sl[l + 0]  = b2fu(s0.x & 0xffffu); Sl[l + 1]  = b2fu(s0.x >> 16);
    Sl[l + 2]  = b2fu(s0.y & 0xffffu); Sl[l + 3]  = b2fu(s0.y >> 16);
    Sl[l + 4]  = b2fu(s0.z & 0xffffu); Sl[l + 5]  = b2fu(s0.z >> 16);
    Sl[l + 6]  = b2fu(s0.w & 0xffffu); Sl[l + 7]  = b2fu(s0.w >> 16);
    Sl[l + 8]  = b2fu(s1.x & 0xffffu); Sl[l + 9]  = b2fu(s1.x >> 16);
    Sl[l + 10] = b2fu(s1.y & 0xffffu); Sl[l + 11] = b2fu(s1.y >> 16);
    Sl[l + 12] = b2fu(s1.z & 0xffffu); Sl[l + 13] = b2fu(s1.z >> 16);
    Sl[l + 14] = b2fu(s1.w & 0xffffu); Sl[l + 15] = b2fu(s1.w >> 16);
    const int t = tid >> 3, q8 = tid & 7;    // r': 32 rows x 64 cols f32
    const size_t gr = gbase + (size_t)t * C_ + q8 * 8;
    const int lr = t * S32 + q8 * 8;
    *(float4*)(rl + lr)     = *(const float4*)(rp + gr);
    *(float4*)(rl + lr + 4) = *(const float4*)(rp + gr + 4);
  }
  __syncthreads();
  const int tq = tid >> 4, iq = tid & 15;
  float o0[4] = {0.f, 0.f, 0.f, 0.f}, o1[4] = {0.f, 0.f, 0.f, 0.f};
  for (int j = 0; j < 64; ++j) {
    float4 sv = *(const float4*)(Sl + j * S32 + iq * 4);
    float r0 = rl[(2 * tq + 0) * S32 + j];
    float r1 = rl[(2 * tq + 1) * S32 + j];
    o0[0] += r0 * sv.x; o0[1] += r0 * sv.y; o0[2] += r0 * sv.z; o0[3] += r0 * sv.w;
    o1[0] += r1 * sv.x; o1[1] += r1 * sv.y; o1[2] += r1 * sv.z; o1[3] += r1 * sv.w;
  }
#pragma unroll
  for (int rr = 0; rr < 2; ++rr) {
    float* o = rr ? o1 : o0;
    const size_t rowb = gbase + (size_t)(2 * tq + rr) * C_;
    float4 yi = *(const float4*)(y + rowb + iq * 4);
    float yv[4] = {yi.x + o[0], yi.y + o[1], yi.z + o[2], yi.w + o[3]};
    float s = yv[0] + yv[1] + yv[2] + yv[3];
    float sq = yv[0] * yv[0] + yv[1] * yv[1] + yv[2] * yv[2] + yv[3] * yv[3];
#pragma unroll
    for (int m = 1; m < 16; m <<= 1) {
      s  += __shfl_xor(s, m, 64);
      sq += __shfl_xor(sq, m, 64);
    }
    float mu  = s * (1.f / 64.f);
    float var = sq * (1.f / 64.f) - mu * mu;
    float rs  = rsqrtf(var + EPS_GN);
    float4 gp = *(const float4*)(gpre + rowb + iq * 4);
    const float gpv[4] = {gp.x, gp.y, gp.z, gp.w};
    uint32_t pk[2];
    ushort hw[4];
#pragma unroll
    for (int e = 0; e < 4; ++e) {
      int cidx = h * 64 + iq * 4 + e;
      float yn = (yv[e] - mu) * rs * lng[cidx] + lnb[cidx];
      float gs = gpv[e] / (1.f + __expf(-gpv[e]));
      hw[e] = f2b(yn * gs);
    }
    pk[0] = (uint32_t)hw[0] | ((uint32_t)hw[1] << 16);
    pk[1] = (uint32_t)hw[2] | ((uint32_t)hw[3] << 16);
    *(uint2*)(yg + rowb + iq * 4) = make_uint2(pk[0], pk[1]);
  }
}

// ---------------------------------------------------------------------------
extern "C" void kernel_launch(void* const* d_in, const int* in_sizes, int n_in,
                              void* d_out, int out_size, void* d_ws, size_t ws_size,
                              hipStream_t stream)
{
  const float* x      = (const float*)d_in[0];
  const float* maa_x  = (const float*)d_in[1];
  const float* maa_w  = (const float*)d_in[2];
  const float* maa_k  = (const float*)d_in[3];
  const float* maa_v  = (const float*)d_in[4];
  const float* maa_r  = (const float*)d_in[5];
  const float* maa_g  = (const float*)d_in[6];
  const float* tdec   = (const float*)d_in[7];
  const float* u      = (const float*)d_in[8];
  const float* maa_w1 = (const float*)d_in[9];
  const float* maa_w2 = (const float*)d_in[10];
  const float* td_w1  = (const float*)d_in[11];
  const float* td_w2  = (const float*)d_in[12];
  const float* lng = (const float*)d_in[18];
  const float* lnb = (const float*)d_in[19];
  float* out = (float*)d_out;

  char* wsp = (char*)d_ws;
  auto alloc = [&](size_t bytes) -> char* {
    char* p = wsp;
    wsp += (bytes + 255) & ~(size_t)255;
    return p;
  };

  bfu16* WT0 = (bfu16*)alloc((size_t)5 * 2048 * 2048 * 2);  // WT[z] = WT0 + z*4M
  bfu16* w1T  = (bfu16*)alloc((size_t)256 * 2048 * 2);
  bfu16* tw1T = (bfu16*)alloc((size_t)128 * 2048 * 2);
  bfu16* tw2T = (bfu16*)alloc((size_t)2048 * 64 * 2);
  bfu16* w2T  = (bfu16*)alloc((size_t)5 * 2048 * 64 * 2);
  float* ybuf = (float*)alloc((size_t)BT_ * C_ * 4);
  bfu16* xxh  = (bfu16*)alloc((size_t)BT_ * C_ * 2);
  bfu16* xxx  = (bfu16*)alloc((size_t)BT_ * C_ * 2);
  bfu16* xh   = (bfu16*)alloc((size_t)BT_ * C_ * 2);
  bfu16* mtan = (bfu16*)alloc((size_t)5 * BT_ * 64 * 2);
  bfu16* xmix0 = (bfu16*)alloc((size_t)5 * BT_ * C_ * 2); // xmix[f] = xmix0 + f*BT*C
  float* rbuf = (float*)alloc((size_t)4 * BT_ * C_ * 4);  // r,k,v,g contiguous
  float* kbuf = rbuf + (size_t)BT_ * C_;
  float* vbuf = kbuf + (size_t)BT_ * C_;
  float* gbuf = vbuf + (size_t)BT_ * C_;
  float* wbuf = (float*)alloc((size_t)BT_ * C_ * 4);
  bfu16* wtan = (bfu16*)alloc((size_t)BT_ * 64 * 2);
  bfu16* Sbuf = (bfu16*)alloc((size_t)64 * 32 * 4096 * 2);  // 16 MB bf16
  float* Gbuf = (float*)alloc((size_t)64 * 32 * 64 * 4);    // 512 KB
  // Aliases (dead-by-then, stream-ordered):
  bfu16* ygb  = xxx;
  bfu16* Ubuf = xmix0 + (size_t)1 * BT_ * C_;   // 16MB bf16 over xmix[1..2]
  bfu16* part1 = (bfu16*)rbuf;  // m-path bf16 partials [8][BT][256] (pre-GEMM)
  bfu16* part3 = (bfu16*)wbuf;  // w-path bf16 partials [16][BT][128] (pre-MODE4)
  bfu16* partW = (bfu16*)rbuf;  // Wo bf16 partials [4][2048][2048] (post-wkv_c)

  dim3 tb(256);

  // ---- all weight transposes + prep_xx, one launch ----
  // (no memsets needed: mtan/w1T/tw1T pad regions stay 0xAA = finite bf16;
  //  they only multiply zeroed B rows or feed partial cols never reduced)
  {
    TrAllP p{};
    int s = 0;
    for (int i = 0; i < 5; ++i) {
      p.j[i] = TrJob{ (const float*)d_in[13 + i], WT0 + (size_t)i * 2048 * 2048,
                      2048, 2048, 2048, 2048, 64, s };
      s += 64 * 64;
    }
    p.j[5] = TrJob{ maa_w1, w1T, 2048, 160, 2048, 2048, 5, s };  s += 5 * 64;
    p.j[6] = TrJob{ td_w1, tw1T, 2048, 64, 2048, 2048, 2, s };   s += 2 * 64;
    p.j[7] = TrJob{ td_w2, tw2T, 64, 2048, 64, 64, 64, s };      s += 64 * 2;
    for (int f = 0; f < 5; ++f) {
      p.j[8 + f] = TrJob{ maa_w2 + (size_t)f * 32 * 2048, w2T + (size_t)f * 2048 * 64,
                          32, 2048, 64, 64, 64, s };
      s += 64 * 2;
    }
    p.x = x; p.maa_x = maa_x; p.xxh = xxh; p.xxx = xxx; p.xh = xh;
    p.prepStart = s;
    s += (BT_ * C_ / 4) / 256;   // 4096 prep blocks
    transpose_all<<<dim3(s), tb, 0, stream>>>(p);
  }

  // ---- m-path: split-K GEMM (xxx @ maa_w1), bf16 partials ----
  {
    GemmP p{}; p.A = xxx; p.Bt = w1T; p.ldk = 2048; p.kIters = 4; p.kChunk = 256;
    p.ldo = 256; p.pStride = (size_t)BT_ * 256; p.ob = part1;
    gemm_k<6><<<dim3(2, 16, 8), tb, 0, stream>>>(p);
  }
  redk_tanh<0, 8><<<dim3(BT_ * 160 / 256), tb, 0, stream>>>(part1, (size_t)BT_ * 256, 256, 160, mtan);

  // ---- token-mix: batched-5 (mtan[f] @ w2T[f]) with xh+xxh epilogue ----
  {
    GemmP p{}; p.A = mtan; p.Bt = w2T; p.ldk = 64; p.kIters = 1;
    p.aStr = (size_t)BT_ * 64; p.bStr = (size_t)2048 * 64; p.oStr = (size_t)BT_ * C_;
    p.ob = xmix0; p.xh = xh; p.xxh = xxh;
    p.vArr[0] = maa_w; p.vArr[1] = maa_k; p.vArr[2] = maa_v; p.vArr[3] = maa_r; p.vArr[4] = maa_g;
    gemm_k<7><<<dim3(16, 16, 5), tb, 0, stream>>>(p);
  }

  // ---- r,k,v,g: batched-4 256^2 swizzled GEMMs (frozen champion) ----
  {
    G256P p{}; p.Bt = WT0; p.ldk = 2048; p.nkt = 32; p.kSplit = 1;
    p.bStr = (size_t)2048 * 2048; p.oStr = (size_t)BT_ * C_; p.of = rbuf;
    p.aArr[0] = xmix0 + (size_t)3 * BT_ * C_;  // xr
    p.aArr[1] = xmix0 + (size_t)1 * BT_ * C_;  // xk
    p.aArr[2] = xmix0 + (size_t)2 * BT_ * C_;  // xv
    p.aArr[3] = xmix0 + (size_t)4 * BT_ * C_;  // xg
    gemm256<0><<<dim3(8, 8, 4), dim3(512), 131072, stream>>>(p);
  }

  // ---- w-path: split-K thin GEMM (xw @ td_w1), 16 chunks, bf16 partials ----
  {
    GemmP p{}; p.A = xmix0; p.Bt = tw1T; p.ldk = 2048; p.kIters = 2; p.kChunk = 128;
    p.ldo = 128; p.pStride = (size_t)BT_ * 128; p.ob = part3;
    gemm_k<6><<<dim3(1, 16, 16), tb, 0, stream>>>(p);
  }
  redk_tanh<1, 16><<<dim3(BT_ * 64 / 256), tb, 0, stream>>>(part3, (size_t)BT_ * 128, 128, 64, wtan);

  // ---- w-path: wbuf = lw = -exp(tdec + wtan @ td_w2)  (fused) ----
  {
    GemmP p{}; p.A = wtan; p.Bt = tw2T; p.ldk = 64; p.kIters = 1;
    p.of = wbuf; p.ldo = 2048; p.vArr[0] = tdec;
    gemm_k<4><<<dim3(16, 16, 1), tb, 0, stream>>>(p);
  }

  // ---- chunked WKV6 (L=32) + fused GroupNorm*silu ----
  wkv_a32<<<dim3(2048), tb, 0, stream>>>(rbuf, kbuf, vbuf, wbuf, u, rbuf, ybuf, Ubuf, Gbuf);
  wkv_b32<<<dim3(256),  tb, 0, stream>>>(Ubuf, Gbuf, Sbuf);
  wkv_c32<<<dim3(2048), tb, 0, stream>>>(rbuf, Sbuf, ybuf, gbuf, lng, lnb, ygb);

  // ---- out = yg @ Wo  (256^2 frozen schedule, K-split 4, bf16 partials) ----
  {
    G256P p{}; p.Bt = WT0 + (size_t)4 * 2048 * 2048; p.ldk = 2048;
    p.nkt = 8; p.kSplit = 4;
    p.bStr = 0; p.oStr = (size_t)2048 * 2048; p.ob = partW;
    p.aArr[0] = ygb;
    gemm256<1><<<dim3(8, 8, 4), dim3(512), 131072, stream>>>(p);
  }
  redk_sum4<<<dim3(4096), tb, 0, stream>>>(partW, out);
}

// Round 15
// 273.744 us; speedup vs baseline: 1.1920x; 1.0340x over previous
//
#include <hip/hip_runtime.h>
#include <cstdint>
#include <cstddef>

// Problem constants (fixed by the reference)
#define B_  2
#define T_  1024
#define C_  2048
#define H_  32
#define BT_ (B_*T_)
static constexpr float EPS_GN = 1e-5f * 64.0f;

using short8 = __attribute__((ext_vector_type(8))) short;
using f32x4  = __attribute__((ext_vector_type(4))) float;
typedef unsigned short bfu16;

__device__ __forceinline__ bfu16 f2b(float f) {
  uint32_t x = __float_as_uint(f);
  uint32_t r = (x + 0x7FFFu + ((x >> 16) & 1u)) >> 16;
  return (bfu16)r;
}
__device__ __forceinline__ float b2f(bfu16 h) {
  return __uint_as_float(((uint32_t)h) << 16);
}
__device__ __forceinline__ float b2fu(uint32_t w) {   // low half of packed
  return __uint_as_float(w << 16);
}

__device__ __forceinline__ void gload16(const bfu16* g, bfu16* l) {
  __builtin_amdgcn_global_load_lds((__attribute__((address_space(1))) void*)g,
                                   (__attribute__((address_space(3))) void*)l,
                                   16, 0, 0);
}

// ---------------------------------------------------------------------------
// gemm256 (round-7 proven schedule, FROZEN): 256x256 tile, BK=64, 512 thr
// (8 waves 2Mx4N), dbuf LDS 128KB. STAGE_A(next); vmcnt(4); barrier; per-ks
// {STAGE_B(next) at ks==1; ds_read frags; MFMA}; barrier.
// LDS XOR-swizzle: source col ^((row&7)<<3), read col ^((lane&7)<<3).
// XCD-aware bijective block swizzle (nwg % 8 == 0 required).
// OB=0: f32 output (p.of). OB=1: bf16 output (p.ob).
// ---------------------------------------------------------------------------
struct G256P {
  const bfu16* Bt; float* of; bfu16* ob;
  size_t bStr, oStr;
  int ldk, nkt, kSplit;
  const bfu16* aArr[4];
};

template<int OB>
__global__ __launch_bounds__(512, 2)
void gemm256(G256P p)
{
  extern __shared__ __align__(16) bfu16 sm[];   // A0,A1,B0,B1 each 256*64
  const int tid  = threadIdx.x;
  const int nwg = gridDim.x * gridDim.y * gridDim.z;
  int lin = blockIdx.x + gridDim.x * (blockIdx.y + gridDim.y * blockIdx.z);
  lin = (lin & 7) * (nwg >> 3) + (lin >> 3);
  const int bx = lin % gridDim.x;
  const int by = (lin / gridDim.x) % gridDim.y;
  const int z  = lin / (gridDim.x * gridDim.y);
  const int m0   = by * 256, n0 = bx * 256;
  const int lane = tid & 63;
  const int wv   = tid >> 6;
  const int wm   = wv >> 2, wn = wv & 3;
  const int ldk  = p.ldk;

  const bfu16* A;
  size_t koff;
  if (p.kSplit > 1) { A = p.aArr[0]; koff = (size_t)z * p.nkt * 64; }
  else              { A = p.aArr[z]; koff = 0; }
  const bfu16* Bt = p.Bt + (size_t)z * p.bStr;

  const int srow = tid >> 3;        // 0..63
  const int scol = (tid & 7) * 8;   // 0..56
  const int sswz = (srow & 7) << 3; // source-side inverse swizzle
  const bfu16* gA = A  + (size_t)(m0 + srow) * ldk + koff + (scol ^ sswz);
  const bfu16* gB = Bt + (size_t)(n0 + srow) * ldk + koff + (scol ^ sswz);

  auto STAGE_A = [&](bfu16* dst, int kt) {
    const bfu16* g = gA + (size_t)kt * 64;
    bfu16* l = dst + srow * 64 + scol;
#pragma unroll
    for (int it = 0; it < 4; ++it)
      gload16(g + (size_t)it * 64 * ldk, l + it * 4096);
  };
  auto STAGE_B = [&](bfu16* dst, int kt) {
    const bfu16* g = gB + (size_t)kt * 64;
    bfu16* l = dst + srow * 64 + scol;
#pragma unroll
    for (int it = 0; it < 4; ++it)
      gload16(g + (size_t)it * 64 * ldk, l + it * 4096);
  };

  f32x4 acc[8][4];
  const f32x4 zero = {0.f, 0.f, 0.f, 0.f};
#pragma unroll
  for (int i = 0; i < 8; ++i)
#pragma unroll
    for (int j = 0; j < 4; ++j) acc[i][j] = zero;

  STAGE_A(sm, 0);
  STAGE_B(sm + 32768, 0);           // 8 outstanding

  const int rswz = (lane & 7) << 3; // read-side swizzle

  for (int kt = 0; kt < p.nkt; ++kt) {
    bfu16* curA = sm + (kt & 1) * 16384;
    bfu16* curB = sm + 32768 + (kt & 1) * 16384;
    bfu16* nxtA = sm + ((kt & 1) ^ 1) * 16384;
    bfu16* nxtB = sm + 32768 + ((kt & 1) ^ 1) * 16384;
    const bool more = (kt + 1 < p.nkt);
    if (more) {
      STAGE_A(nxtA, kt + 1);                       // 12 outstanding
      asm volatile("s_waitcnt vmcnt(4)" ::: "memory");  // cur buf landed
    } else {
      asm volatile("s_waitcnt vmcnt(0)" ::: "memory");
    }
    __builtin_amdgcn_s_barrier();

#pragma unroll
    for (int ks = 0; ks < 2; ++ks) {
      if (ks == 1 && more) STAGE_B(nxtB, kt + 1);
      const int ko = (ks * 32 + (lane >> 4) * 8) ^ rswz;
      short8 a[8], b[4];
#pragma unroll
      for (int i = 0; i < 8; ++i)
        a[i] = *(const short8*)(curA + (wm * 128 + i * 16 + (lane & 15)) * 64 + ko);
#pragma unroll
      for (int j = 0; j < 4; ++j)
        b[j] = *(const short8*)(curB + (wn * 64 + j * 16 + (lane & 15)) * 64 + ko);
      __builtin_amdgcn_s_setprio(1);
#pragma unroll
      for (int i = 0; i < 8; ++i)
#pragma unroll
        for (int j = 0; j < 4; ++j)
          acc[i][j] = __builtin_amdgcn_mfma_f32_16x16x32_bf16(a[i], b[j], acc[i][j], 0, 0, 0);
      __builtin_amdgcn_s_setprio(0);
    }
    __builtin_amdgcn_s_barrier();
  }

  const int cb = n0 + wn * 64 + (lane & 15);
  const int rb = m0 + wm * 128 + ((lane >> 4) << 2);
  if constexpr (OB == 0) {
    float* o = p.of + (size_t)z * p.oStr;
#pragma unroll
    for (int i = 0; i < 8; ++i)
#pragma unroll
      for (int j = 0; j < 4; ++j) {
        int col = cb + j * 16;
#pragma unroll
        for (int q = 0; q < 4; ++q)
          o[(size_t)(rb + i * 16 + q) * 2048 + col] = acc[i][j][q];
      }
  } else {
    bfu16* o = p.ob + (size_t)z * p.oStr;
#pragma unroll
    for (int i = 0; i < 8; ++i)
#pragma unroll
      for (int j = 0; j < 4; ++j) {
        int col = cb + j * 16;
#pragma unroll
        for (int q = 0; q < 4; ++q)
          o[(size_t)(rb + i * 16 + q) * 2048 + col] = f2b(acc[i][j][q]);
      }
  }
}

// ---------------------------------------------------------------------------
// 128x128 GEMM for the small/odd shapes.
// MODE 4: of = -exp(vArr[0][col] + acc)   (fused lw = -exp(w))
// MODE 6: split-K bf16 partials
// MODE 7: batched-5 token-mix epilogue (x and xx both bf16)
// ---------------------------------------------------------------------------
struct GemmP {
  const bfu16* A; const bfu16* Bt;
  float* of; bfu16* ob;
  const bfu16* xh; const bfu16* xxh;
  int ldk, kIters, kChunk, ldo;
  size_t pStride, aStr, bStr, oStr;
  const float* vArr[5];
};

template<int MODE>
__global__ __launch_bounds__(256)
void gemm_k(GemmP p)
{
  __shared__ alignas(16) bfu16 As[128*64];
  __shared__ alignas(16) bfu16 Bs[128*64];
  const int tid  = threadIdx.x;
  const int z    = blockIdx.z;
  const int m0   = blockIdx.y * 128, n0 = blockIdx.x * 128;
  const int lane = tid & 63;
  const int wv   = tid >> 6;
  const int wr   = (wv >> 1) * 64, wc = (wv & 1) * 64;

  const bfu16* A  = p.A;
  const bfu16* Bt = p.Bt;
  size_t koff = 0;
  if constexpr (MODE == 7) { A += (size_t)z * p.aStr; Bt += (size_t)z * p.bStr; }
  if constexpr (MODE == 6) { koff = (size_t)z * p.kChunk; }

  f32x4 acc[4][4];
  const f32x4 zero = {0.f, 0.f, 0.f, 0.f};
#pragma unroll
  for (int i = 0; i < 4; ++i)
#pragma unroll
    for (int j = 0; j < 4; ++j) acc[i][j] = zero;

  const int srow = tid >> 3;
  const int scol = (tid & 7) * 8;
  const int ldk  = p.ldk;

  for (int kb = 0; kb < p.kIters; ++kb) {
    const bfu16* ga = A  + (size_t)m0 * ldk + koff + kb * 64;
    const bfu16* gb = Bt + (size_t)n0 * ldk + koff + kb * 64;
#pragma unroll
    for (int it = 0; it < 4; ++it) {
      int r = it * 32 + srow;
      gload16(ga + (size_t)r * ldk + scol, As + r * 64 + scol);
      gload16(gb + (size_t)r * ldk + scol, Bs + r * 64 + scol);
    }
    __syncthreads();
#pragma unroll
    for (int kk = 0; kk < 2; ++kk) {
      const int ko = kk * 32 + (lane >> 4) * 8;
      short8 a[4], b[4];
#pragma unroll
      for (int i = 0; i < 4; ++i)
        a[i] = *(const short8*)(As + (wr + i * 16 + (lane & 15)) * 64 + ko);
#pragma unroll
      for (int j = 0; j < 4; ++j)
        b[j] = *(const short8*)(Bs + (wc + j * 16 + (lane & 15)) * 64 + ko);
#pragma unroll
      for (int i = 0; i < 4; ++i)
#pragma unroll
        for (int j = 0; j < 4; ++j)
          acc[i][j] = __builtin_amdgcn_mfma_f32_16x16x32_bf16(a[i], b[j], acc[i][j], 0, 0, 0);
    }
    __syncthreads();
  }

  const int cb = n0 + wc + (lane & 15);
  const int rb = m0 + wr + ((lane >> 4) << 2);
#pragma unroll
  for (int i = 0; i < 4; ++i) {
#pragma unroll
    for (int j = 0; j < 4; ++j) {
      int col = cb + j * 16;
#pragma unroll
      for (int q = 0; q < 4; ++q) {
        int row = rb + i * 16 + q;
        float v = acc[i][j][q];
        if constexpr (MODE == 4) {
          p.of[(size_t)row * p.ldo + col] = -__expf(p.vArr[0][col] + v);
        } else if constexpr (MODE == 6) {
          p.ob[(size_t)z * p.pStride + (size_t)row * p.ldo + col] = f2b(v);
        } else if constexpr (MODE == 7) {
          size_t idx = (size_t)row * C_ + col;
          (p.ob + (size_t)z * p.oStr)[idx] =
              f2b(b2f(p.xh[idx]) + b2f(p.xxh[idx]) * (p.vArr[z][col] + v));
        }
      }
    }
  }
}

// ---------------------------------------------------------------------------
// split-K reduce (bf16 partials) + tanh -> bf16.
// OUT=0: mtan scatter [f][row][d]; OUT=1: wtan.  NS = K-chunk count.
// ---------------------------------------------------------------------------
template<int OUT, int NS>
__global__ __launch_bounds__(256)
void redk_tanh(const bfu16* __restrict__ part, size_t pStr, int ldo, int ncols,
               bfu16* __restrict__ out)
{
  int id = blockIdx.x * 256 + threadIdx.x;
  int row = id / ncols, col = id % ncols;
  if (row >= BT_) return;
  float v = 0.f;
#pragma unroll
  for (int s = 0; s < NS; ++s) v += b2f(part[(size_t)s * pStr + (size_t)row * ldo + col]);
  bfu16 tv = f2b(tanhf(v));
  if constexpr (OUT == 0)
    out[((size_t)(col >> 5) * BT_ + row) * 64 + (col & 31)] = tv;
  else
    out[(size_t)row * 64 + col] = tv;
}

// sum of 4 bf16 partial planes -> f32 out
__global__ __launch_bounds__(256)
void redk_sum4(const bfu16* __restrict__ p0, float* __restrict__ out)
{
  size_t i = ((size_t)blockIdx.x * 256 + threadIdx.x) * 4;
  const size_t str = (size_t)2048 * 2048;
  uint2 a = *(const uint2*)(p0 + i);
  uint2 b = *(const uint2*)(p0 + str + i);
  uint2 c = *(const uint2*)(p0 + 2 * str + i);
  uint2 d = *(const uint2*)(p0 + 3 * str + i);
  float4 r;
  r.x = b2fu(a.x & 0xffffu) + b2fu(b.x & 0xffffu) + b2fu(c.x & 0xffffu) + b2fu(d.x & 0xffffu);
  r.y = b2fu(a.x >> 16)     + b2fu(b.x >> 16)     + b2fu(c.x >> 16)     + b2fu(d.x >> 16);
  r.z = b2fu(a.y & 0xffffu) + b2fu(b.y & 0xffffu) + b2fu(c.y & 0xffffu) + b2fu(d.y & 0xffffu);
  r.w = b2fu(a.y >> 16)     + b2fu(b.y >> 16)     + b2fu(c.y >> 16)     + b2fu(d.y >> 16);
  *(float4*)(out + i) = r;
}

// ---------------------------------------------------------------------------
// All weight transposes (13 jobs) + prep_xx (blocks >= prepStart) in ONE
// launch. Transpose: f32 [R][Cc] -> bf16 dst[c*ldd+r], rows [R,Rpad) zeroed.
// Prep: xx = shift(x)-x (bf16); xxx = bf16(x+xx*maa_x); xh = bf16(x).
// ---------------------------------------------------------------------------
struct TrJob { const float* src; bfu16* dst; int R, Cc, Rpad, ldd, gx, start; };
struct TrAllP {
  TrJob j[13];
  const float* x; const float* maa_x;
  bfu16* xxh; bfu16* xxx; bfu16* xh;
  int prepStart;
};

__global__ __launch_bounds__(256)
void transpose_all(TrAllP p)
{
  __shared__ float tile[32][33];
  const int bid = blockIdx.x;
  if (bid >= p.prepStart) {
    size_t i = ((size_t)(bid - p.prepStart) * 256 + threadIdx.x) * 4;
    int c  = (int)(i & (C_ - 1));
    int bt = (int)(i >> 11);
    int t  = bt & (T_ - 1);
    float4 xv = *(const float4*)(p.x + i);
    float4 xp = {0.f, 0.f, 0.f, 0.f};
    if (t > 0) xp = *(const float4*)(p.x + i - C_);
    float4 mx = *(const float4*)(p.maa_x + c);
    float dx = xp.x - xv.x, dy = xp.y - xv.y, dz = xp.z - xv.z, dw = xp.w - xv.w;
    uint2 w0;
    w0.x = (uint32_t)f2b(dx) | ((uint32_t)f2b(dy) << 16);
    w0.y = (uint32_t)f2b(dz) | ((uint32_t)f2b(dw) << 16);
    *(uint2*)(p.xxh + i) = w0;
    uint2 w1;
    w1.x = (uint32_t)f2b(xv.x + dx * mx.x) | ((uint32_t)f2b(xv.y + dy * mx.y) << 16);
    w1.y = (uint32_t)f2b(xv.z + dz * mx.z) | ((uint32_t)f2b(xv.w + dw * mx.w) << 16);
    *(uint2*)(p.xxx + i) = w1;
    uint2 w2;
    w2.x = (uint32_t)f2b(xv.x) | ((uint32_t)f2b(xv.y) << 16);
    w2.y = (uint32_t)f2b(xv.z) | ((uint32_t)f2b(xv.w) << 16);
    *(uint2*)(p.xh + i) = w2;
    return;
  }
  int k = 0;
#pragma unroll
  for (int t = 1; t < 13; ++t) if (bid >= p.j[t].start) k = t;
  const TrJob jb = p.j[k];
  const int local = bid - jb.start;
  const int bx = local % jb.gx, by = local / jb.gx;
  const int tx = threadIdx.x & 31, ty = threadIdx.x >> 5;
  const int r0 = by * 32, c0 = bx * 32;
#pragma unroll
  for (int i = 0; i < 4; ++i) {
    int r = r0 + ty + i * 8, c = c0 + tx;
    tile[ty + i * 8][tx] = (r < jb.R && c < jb.Cc) ? jb.src[(size_t)r * jb.Cc + c] : 0.f;
  }
  __syncthreads();
#pragma unroll
  for (int i = 0; i < 4; ++i) {
    int c = c0 + ty + i * 8, r = r0 + tx;
    if (c < jb.Cc && r < jb.Rpad) jb.dst[(size_t)c * jb.ldd + r] = f2b(tile[tx][ty + i * 8]);
  }
}

// ---------------------------------------------------------------------------
// WKV6 chunked scan, chunk L=32. w input is ALREADY lw = -exp(w) (f32).
// r,k,v inputs bf16; rp (r') and y_intra outputs bf16; U bf16.
// ---------------------------------------------------------------------------
#define S32 68   // LDS row stride (floats) for 32-row tiles

__global__ __launch_bounds__(256)
void wkv_a32(const bfu16* __restrict__ r, const bfu16* __restrict__ k,
             const bfu16* __restrict__ v, const float* __restrict__ w,
             const float* __restrict__ u, bfu16* __restrict__ rp,
             bfu16* __restrict__ y, bfu16* __restrict__ U, float* __restrict__ G)
{
  __shared__ float rw[32 * S32];
  __shared__ float kk[32 * S32];
  __shared__ float vv[32 * S32];
  __shared__ float Ps[32 * S32];
  __shared__ float red[256];
  __shared__ float diag[32];
  __shared__ float Gl[64];

  const int blk = blockIdx.x;
  const int bh = blk >> 5, c = blk & 31;
  const int b = bh >> 5, h = bh & 31;
  const int tid = threadIdx.x;
  const size_t gbase = ((size_t)(b * T_ + c * 32)) * C_ + h * 64;

  {
    const int t = tid >> 3, q = tid & 7;
    const size_t g = gbase + (size_t)t * C_ + q * 8;
    const int l = t * S32 + q * 8;
    uint4 rv4 = *(const uint4*)(r + g);
    rw[l+0] = b2fu(rv4.x & 0xffffu); rw[l+1] = b2fu(rv4.x >> 16);
    rw[l+2] = b2fu(rv4.y & 0xffffu); rw[l+3] = b2fu(rv4.y >> 16);
    rw[l+4] = b2fu(rv4.z & 0xffffu); rw[l+5] = b2fu(rv4.z >> 16);
    rw[l+6] = b2fu(rv4.w & 0xffffu); rw[l+7] = b2fu(rv4.w >> 16);
    uint4 kv4 = *(const uint4*)(k + g);
    kk[l+0] = b2fu(kv4.x & 0xffffu); kk[l+1] = b2fu(kv4.x >> 16);
    kk[l+2] = b2fu(kv4.y & 0xffffu); kk[l+3] = b2fu(kv4.y >> 16);
    kk[l+4] = b2fu(kv4.z & 0xffffu); kk[l+5] = b2fu(kv4.z >> 16);
    kk[l+6] = b2fu(kv4.w & 0xffffu); kk[l+7] = b2fu(kv4.w >> 16);
    uint4 vv4 = *(const uint4*)(v + g);
    vv[l+0] = b2fu(vv4.x & 0xffffu); vv[l+1] = b2fu(vv4.x >> 16);
    vv[l+2] = b2fu(vv4.y & 0xffffu); vv[l+3] = b2fu(vv4.y >> 16);
    vv[l+4] = b2fu(vv4.z & 0xffffu); vv[l+5] = b2fu(vv4.z >> 16);
    vv[l+6] = b2fu(vv4.w & 0xffffu); vv[l+7] = b2fu(vv4.w >> 16);
    *(float4*)(Ps + l)     = *(const float4*)(w + g);
    *(float4*)(Ps + l + 4) = *(const float4*)(w + g + 4);
  }
  __syncthreads();

  // segmented prefix over t (4 segments of 8), per-j
  {
    const int seg = tid >> 6, j = tid & 63;
    float loc = 0.f;
#pragma unroll
    for (int tt = 0; tt < 8; ++tt) loc += Ps[(seg * 8 + tt) * S32 + j];
    red[seg * 64 + j] = loc;
  }
  __syncthreads();
  {
    const int seg = tid >> 6, j = tid & 63;
    float cs = 0.f;
    for (int s = 0; s < seg; ++s) cs += red[s * 64 + j];
    const float uj = u[h * 64 + j];
#pragma unroll
    for (int tt = 0; tt < 8; ++tt) {
      const int a = (seg * 8 + tt) * S32 + j;
      float lw = Ps[a];
      float rv = rw[a] * __expf(cs);
      rw[a] = rv;
      cs += lw;
      float kv = kk[a] * __expf(-cs);
      kk[a] = kv;
      Ps[a] = rv * kv * uj * __expf(lw);   // D (exact)
    }
    if (seg == 3) {
      float Gj = __expf(cs);
      Gl[j] = Gj;
      G[((size_t)bh * 32 + c) * 64 + j] = Gj;
    }
  }
  __syncthreads();

  // diag[t] = sum_j D[t][j]
  {
    const int t = tid & 31, q = tid >> 5;
    float s = 0.f;
#pragma unroll
    for (int jj = 0; jj < 8; ++jj) s += Ps[t * S32 + q * 8 + jj];
    red[q * 32 + t] = s;
  }
  __syncthreads();
  if (tid < 32) {
    float d = 0.f;
#pragma unroll
    for (int q = 0; q < 8; ++q) d += red[q * 32 + tid];
    diag[tid] = d;
  }
  __syncthreads();

  // scores: 2x2 tiles over 16x16 thread grid, lower-tri
  {
    const int tq = tid >> 4, sq = tid & 15;
    float a00 = 0.f, a01 = 0.f, a10 = 0.f, a11 = 0.f;
    if (sq <= tq) {
      for (int j = 0; j < 64; j += 4) {
        float4 r0 = *(const float4*)(rw + (2 * tq + 0) * S32 + j);
        float4 r1 = *(const float4*)(rw + (2 * tq + 1) * S32 + j);
        float4 k0 = *(const float4*)(kk + (2 * sq + 0) * S32 + j);
        float4 k1 = *(const float4*)(kk + (2 * sq + 1) * S32 + j);
        a00 += r0.x * k0.x + r0.y * k0.y + r0.z * k0.z + r0.w * k0.w;
        a01 += r0.x * k1.x + r0.y * k1.y + r0.z * k1.z + r0.w * k1.w;
        a10 += r1.x * k0.x + r1.y * k0.y + r1.z * k0.z + r1.w * k0.w;
        a11 += r1.x * k1.x + r1.y * k1.y + r1.z * k1.z + r1.w * k1.w;
      }
    }
    __syncthreads();
    if (sq <= tq) {
      const float av[2][2] = {{a00, a01}, {a10, a11}};
#pragma unroll
      for (int tt = 0; tt < 2; ++tt)
#pragma unroll
        for (int ss = 0; ss < 2; ++ss) {
          int t = 2 * tq + tt, s = 2 * sq + ss;
          Ps[t * S32 + s] = (s < t) ? av[tt][ss] : (s == t ? diag[t] : 0.f);
        }
    }
  }
  __syncthreads();

  // O_intra[t][i] = sum_{s<=t} P[t][s] * v[s][i]  -> y (bf16)
  {
    const int tq = tid >> 4, iq = tid & 15;
    float o0[4] = {0.f, 0.f, 0.f, 0.f}, o1[4] = {0.f, 0.f, 0.f, 0.f};
    const int tmax = 2 * tq + 1;
    for (int s = 0; s <= tmax; ++s) {
      float4 vx = *(const float4*)(vv + s * S32 + iq * 4);
      float p0 = Ps[(2 * tq + 0) * S32 + s];
      float p1 = Ps[(2 * tq + 1) * S32 + s];
      o0[0] += p0 * vx.x; o0[1] += p0 * vx.y; o0[2] += p0 * vx.z; o0[3] += p0 * vx.w;
      o1[0] += p1 * vx.x; o1[1] += p1 * vx.y; o1[2] += p1 * vx.z; o1[3] += p1 * vx.w;
    }
    uint2 y0, y1;
    y0.x = (uint32_t)f2b(o0[0]) | ((uint32_t)f2b(o0[1]) << 16);
    y0.y = (uint32_t)f2b(o0[2]) | ((uint32_t)f2b(o0[3]) << 16);
    y1.x = (uint32_t)f2b(o1[0]) | ((uint32_t)f2b(o1[1]) << 16);
    y1.y = (uint32_t)f2b(o1[2]) | ((uint32_t)f2b(o1[3]) << 16);
    *(uint2*)(y + gbase + (size_t)(2 * tq + 0) * C_ + iq * 4) = y0;
    *(uint2*)(y + gbase + (size_t)(2 * tq + 1) * C_ + iq * 4) = y1;
  }

  // U[j][i] = G[j] * sum_s k~[s][j] * v[s][i]  (stored bf16)
  {
    const int jq = tid >> 4, iq = tid & 15;
    float ua[4][4] = {{0.f}};
    for (int s = 0; s < 32; ++s) {
      float4 kx = *(const float4*)(kk + s * S32 + jq * 4);
      float4 vx = *(const float4*)(vv + s * S32 + iq * 4);
      ua[0][0] += kx.x * vx.x; ua[0][1] += kx.x * vx.y; ua[0][2] += kx.x * vx.z; ua[0][3] += kx.x * vx.w;
      ua[1][0] += kx.y * vx.x; ua[1][1] += kx.y * vx.y; ua[1][2] += kx.y * vx.z; ua[1][3] += kx.y * vx.w;
      ua[2][0] += kx.z * vx.x; ua[2][1] += kx.z * vx.y; ua[2][2] += kx.z * vx.z; ua[2][3] += kx.z * vx.w;
      ua[3][0] += kx.w * vx.x; ua[3][1] += kx.w * vx.y; ua[3][2] += kx.w * vx.z; ua[3][3] += kx.w * vx.w;
    }
    const size_t ub = ((size_t)bh * 32 + c) * 4096;
#pragma unroll
    for (int jj = 0; jj < 4; ++jj) {
      float g = Gl[jq * 4 + jj];
      uint2 uvp;
      uvp.x = (uint32_t)f2b(ua[jj][0] * g) | ((uint32_t)f2b(ua[jj][1] * g) << 16);
      uvp.y = (uint32_t)f2b(ua[jj][2] * g) | ((uint32_t)f2b(ua[jj][3] * g) << 16);
      *(uint2*)(U + ub + (size_t)(jq * 4 + jj) * 64 + iq * 4) = uvp;
    }
  }

  // write r' back bf16 (in-place over r; own rows only)
  {
    const int t = tid >> 3, q = tid & 7;
    const size_t g = gbase + (size_t)t * C_ + q * 8;
    const int l = t * S32 + q * 8;
    uint4 rp4;
    rp4.x = (uint32_t)f2b(rw[l+0]) | ((uint32_t)f2b(rw[l+1]) << 16);
    rp4.y = (uint32_t)f2b(rw[l+2]) | ((uint32_t)f2b(rw[l+3]) << 16);
    rp4.z = (uint32_t)f2b(rw[l+4]) | ((uint32_t)f2b(rw[l+5]) << 16);
    rp4.w = (uint32_t)f2b(rw[l+6]) | ((uint32_t)f2b(rw[l+7]) << 16);
    *(uint4*)(rp + g) = rp4;
  }
}

// ---------------------------------------------------------------------------
// State scan: S_{c+1} = G_c*S_c + U_c. 256 blocks (bh x j-quarter), f32
// accumulation in registers; U read bf16, S written bf16.
// ---------------------------------------------------------------------------
__global__ __launch_bounds__(256)
void wkv_b32(const bfu16* __restrict__ U, const float* __restrict__ G,
             bfu16* __restrict__ Sbuf)
{
  const int bh = blockIdx.x >> 2, jq = blockIdx.x & 3;
  const int tid = threadIdx.x;
  const int j = jq * 16 + (tid >> 4);
  const int i = (tid & 15) * 4;
  float4 S = {0.f, 0.f, 0.f, 0.f};
  for (int c = 0; c < 32; ++c) {
    const size_t cb = ((size_t)bh * 32 + c);
    float g = G[cb * 64 + j];
    const size_t idx = cb * 4096 + (size_t)j * 64 + i;
    uint2 sp;
    sp.x = (uint32_t)f2b(S.x) | ((uint32_t)f2b(S.y) << 16);
    sp.y = (uint32_t)f2b(S.z) | ((uint32_t)f2b(S.w) << 16);
    *(uint2*)(Sbuf + idx) = sp;
    uint2 uv = *(const uint2*)(U + idx);
    S.x = g * S.x + b2fu(uv.x & 0xffffu);
    S.y = g * S.y + b2fu(uv.x >> 16);
    S.z = g * S.z + b2fu(uv.y & 0xffffu);
    S.w = g * S.w + b2fu(uv.y >> 16);
  }
}

// ---------------------------------------------------------------------------
// Phase C + fused GroupNorm*silu(g) -> bf16 ygb.
// S, rp, y, gpre all read bf16.
// ---------------------------------------------------------------------------
__global__ __launch_bounds__(256)
void wkv_c32(const bfu16* __restrict__ rp, const bfu16* __restrict__ Sbuf,
             const bfu16* __restrict__ y, const bfu16* __restrict__ gpre,
             const float* __restrict__ lng, const float* __restrict__ lnb,
             bfu16* __restrict__ yg)
{
  __shared__ float Sl[64 * S32];
  __shared__ float rl[32 * S32];
  const int blk = blockIdx.x;
  const int bh = blk >> 5, c = blk & 31;
  const int b = bh >> 5, h = bh & 31;
  const int tid = threadIdx.x;
  const size_t gbase = ((size_t)(b * T_ + c * 32)) * C_ + h * 64;
  {
    const int j = tid >> 2, q = tid & 3;     // S: 64 rows x 64 cols bf16
    const size_t sb = ((size_t)bh * 32 + c) * 4096 + (size_t)j * 64 + q * 16;
    const int l = j * S32 + q * 16;
    uint4 s0 = *(const uint4*)(Sbuf + sb);       // 8 bf16
    uint4 s1 = *(const uint4*)(Sbuf + sb + 8);   // 8 bf16
    Sl[l + 0]  = b2fu(s0.x & 0xffffu); Sl[l + 1]  = b2fu(s0.x >> 16);
    Sl[l + 2]  = b2fu(s0.y & 0xffffu); Sl[l + 3]  = b2fu(s0.y >> 16);
    Sl[l + 4]  = b2fu(s0.z & 0xffffu); Sl[l + 5]  = b2fu(s0.z >> 16);
    Sl[l + 6]  = b2fu(s0.w & 0xffffu); Sl[l + 7]  = b2fu(s0.w >> 16);
    Sl[l + 8]  = b2fu(s1.x & 0xffffu); Sl[l + 9]  = b2fu(s1.x >> 16);
    Sl[l + 10] = b2fu(s1.y & 0xffffu); Sl[l + 11] = b2fu(s1.y >> 16);
    Sl[l + 12] = b2fu(s1.z & 0xffffu); Sl[l + 13] = b2fu(s1.z >> 16);
    Sl[l + 14] = b2fu(s1.w & 0xffffu); Sl[l + 15] = b2fu(s1.w >> 16);
    const int t = tid >> 3, q8 = tid & 7;    // r': 32 rows x 64 cols bf16
    const size_t gr = gbase + (size_t)t * C_ + q8 * 8;
    const int lr = t * S32 + q8 * 8;
    uint4 rv4 = *(const uint4*)(rp + gr);
    rl[lr+0] = b2fu(rv4.x & 0xffffu); rl[lr+1] = b2fu(rv4.x >> 16);
    rl[lr+2] = b2fu(rv4.y & 0xffffu); rl[lr+3] = b2fu(rv4.y >> 16);
    rl[lr+4] = b2fu(rv4.z & 0xffffu); rl[lr+5] = b2fu(rv4.z >> 16);
    rl[lr+6] = b2fu(rv4.w & 0xffffu); rl[lr+7] = b2fu(rv4.w >> 16);
  }
  __syncthreads();
  const int tq = tid >> 4, iq = tid & 15;
  float o0[4] = {0.f, 0.f, 0.f, 0.f}, o1[4] = {0.f, 0.f, 0.f, 0.f};
  for (int j = 0; j < 64; ++j) {
    float4 sv = *(const float4*)(Sl + j * S32 + iq * 4);
    float r0 = rl[(2 * tq + 0) * S32 + j];
    float r1 = rl[(2 * tq + 1) * S32 + j];
    o0[0] += r0 * sv.x; o0[1] += r0 * sv.y; o0[2] += r0 * sv.z; o0[3] += r0 * sv.w;
    o1[0] += r1 * sv.x; o1[1] += r1 * sv.y; o1[2] += r1 * sv.z; o1[3] += r1 * sv.w;
  }
#pragma unroll
  for (int rr = 0; rr < 2; ++rr) {
    float* o = rr ? o1 : o0;
    const size_t rowb = gbase + (size_t)(2 * tq + rr) * C_;
    uint2 yi2 = *(const uint2*)(y + rowb + iq * 4);
    float yv[4] = { b2fu(yi2.x & 0xffffu) + o[0], b2fu(yi2.x >> 16) + o[1],
                    b2fu(yi2.y & 0xffffu) + o[2], b2fu(yi2.y >> 16) + o[3] };
    float s = yv[0] + yv[1] + yv[2] + yv[3];
    float sq = yv[0] * yv[0] + yv[1] * yv[1] + yv[2] * yv[2] + yv[3] * yv[3];
#pragma unroll
    for (int m = 1; m < 16; m <<= 1) {
      s  += __shfl_xor(s, m, 64);
      sq += __shfl_xor(sq, m, 64);
    }
    float mu  = s * (1.f / 64.f);
    float var = sq * (1.f / 64.f) - mu * mu;
    float rs  = rsqrtf(var + EPS_GN);
    uint2 gp2 = *(const uint2*)(gpre + rowb + iq * 4);
    const float gpv[4] = { b2fu(gp2.x & 0xffffu), b2fu(gp2.x >> 16),
                           b2fu(gp2.y & 0xffffu), b2fu(gp2.y >> 16) };
    uint32_t pk[2];
    ushort hw[4];
#pragma unroll
    for (int e = 0; e < 4; ++e) {
      int cidx = h * 64 + iq * 4 + e;
      float yn = (yv[e] - mu) * rs * lng[cidx] + lnb[cidx];
      float gs = gpv[e] / (1.f + __expf(-gpv[e]));
      hw[e] = f2b(yn * gs);
    }
    pk[0] = (uint32_t)hw[0] | ((uint32_t)hw[1] << 16);
    pk[1] = (uint32_t)hw[2] | ((uint32_t)hw[3] << 16);
    *(uint2*)(yg + rowb + iq * 4) = make_uint2(pk[0], pk[1]);
  }
}

// ---------------------------------------------------------------------------
extern "C" void kernel_launch(void* const* d_in, const int* in_sizes, int n_in,
                              void* d_out, int out_size, void* d_ws, size_t ws_size,
                              hipStream_t stream)
{
  const float* x      = (const float*)d_in[0];
  const float* maa_x  = (const float*)d_in[1];
  const float* maa_w  = (const float*)d_in[2];
  const float* maa_k  = (const float*)d_in[3];
  const float* maa_v  = (const float*)d_in[4];
  const float* maa_r  = (const float*)d_in[5];
  const float* maa_g  = (const float*)d_in[6];
  const float* tdec   = (const float*)d_in[7];
  const float* u      = (const float*)d_in[8];
  const float* maa_w1 = (const float*)d_in[9];
  const float* maa_w2 = (const float*)d_in[10];
  const float* td_w1  = (const float*)d_in[11];
  const float* td_w2  = (const float*)d_in[12];
  const float* lng = (const float*)d_in[18];
  const float* lnb = (const float*)d_in[19];
  float* out = (float*)d_out;

  char* wsp = (char*)d_ws;
  auto alloc = [&](size_t bytes) -> char* {
    char* p = wsp;
    wsp += (bytes + 255) & ~(size_t)255;
    return p;
  };

  bfu16* WT0 = (bfu16*)alloc((size_t)5 * 2048 * 2048 * 2);  // WT[z] = WT0 + z*4M
  bfu16* w1T  = (bfu16*)alloc((size_t)256 * 2048 * 2);
  bfu16* tw1T = (bfu16*)alloc((size_t)128 * 2048 * 2);
  bfu16* tw2T = (bfu16*)alloc((size_t)2048 * 64 * 2);
  bfu16* w2T  = (bfu16*)alloc((size_t)5 * 2048 * 64 * 2);
  float* ybuf = (float*)alloc((size_t)BT_ * C_ * 4);
  bfu16* xxh  = (bfu16*)alloc((size_t)BT_ * C_ * 2);
  bfu16* xxx  = (bfu16*)alloc((size_t)BT_ * C_ * 2);
  bfu16* xh   = (bfu16*)alloc((size_t)BT_ * C_ * 2);
  bfu16* mtan = (bfu16*)alloc((size_t)5 * BT_ * 64 * 2);
  bfu16* xmix0 = (bfu16*)alloc((size_t)5 * BT_ * C_ * 2); // xmix[f] = xmix0 + f*BT*C
  float* rbuf = (float*)alloc((size_t)4 * BT_ * C_ * 4);  // alias pool
  float* wbuf = (float*)alloc((size_t)BT_ * C_ * 4);      // lw (f32, precision)
  bfu16* wtan = (bfu16*)alloc((size_t)BT_ * 64 * 2);
  bfu16* Sbuf = (bfu16*)alloc((size_t)64 * 32 * 4096 * 2);  // 16 MB bf16
  float* Gbuf = (float*)alloc((size_t)64 * 32 * 64 * 4);    // 512 KB
  // bf16 r,k,v,g (32 MB) in first half of rbuf pool:
  bfu16* rB = (bfu16*)rbuf;
  bfu16* kB = rB + (size_t)BT_ * C_;
  bfu16* vB = kB + (size_t)BT_ * C_;
  bfu16* gB = vB + (size_t)BT_ * C_;
  // Aliases (dead-by-then, stream-ordered):
  bfu16* ygb  = xxx;
  bfu16* yB   = (bfu16*)ybuf;                   // y_intra bf16 (8 MB of ybuf)
  bfu16* Ubuf = xmix0 + (size_t)1 * BT_ * C_;   // 16MB bf16 over xmix[1..2]
  bfu16* part1 = (bfu16*)rbuf;  // m-path bf16 partials (pre-rkvg GEMM)
  bfu16* part3 = (bfu16*)wbuf;  // w-path bf16 partials (pre-MODE4)
  bfu16* partW = (bfu16*)(rbuf + (size_t)2 * BT_ * C_);  // Wo partials 32MB
                                 // (over v,g + beyond; post-wkv_c, g consumed)

  dim3 tb(256);

  // ---- all weight transposes + prep_xx, one launch ----
  {
    TrAllP p{};
    int s = 0;
    for (int i = 0; i < 5; ++i) {
      p.j[i] = TrJob{ (const float*)d_in[13 + i], WT0 + (size_t)i * 2048 * 2048,
                      2048, 2048, 2048, 2048, 64, s };
      s += 64 * 64;
    }
    p.j[5] = TrJob{ maa_w1, w1T, 2048, 160, 2048, 2048, 5, s };  s += 5 * 64;
    p.j[6] = TrJob{ td_w1, tw1T, 2048, 64, 2048, 2048, 2, s };   s += 2 * 64;
    p.j[7] = TrJob{ td_w2, tw2T, 64, 2048, 64, 64, 64, s };      s += 64 * 2;
    for (int f = 0; f < 5; ++f) {
      p.j[8 + f] = TrJob{ maa_w2 + (size_t)f * 32 * 2048, w2T + (size_t)f * 2048 * 64,
                          32, 2048, 64, 64, 64, s };
      s += 64 * 2;
    }
    p.x = x; p.maa_x = maa_x; p.xxh = xxh; p.xxx = xxx; p.xh = xh;
    p.prepStart = s;
    s += (BT_ * C_ / 4) / 256;   // 4096 prep blocks
    transpose_all<<<dim3(s), tb, 0, stream>>>(p);
  }

  // ---- m-path: split-K GEMM (xxx @ maa_w1), bf16 partials ----
  {
    GemmP p{}; p.A = xxx; p.Bt = w1T; p.ldk = 2048; p.kIters = 4; p.kChunk = 256;
    p.ldo = 256; p.pStride = (size_t)BT_ * 256; p.ob = part1;
    gemm_k<6><<<dim3(2, 16, 8), tb, 0, stream>>>(p);
  }
  redk_tanh<0, 8><<<dim3(BT_ * 160 / 256), tb, 0, stream>>>(part1, (size_t)BT_ * 256, 256, 160, mtan);

  // ---- token-mix: batched-5 (mtan[f] @ w2T[f]) with xh+xxh epilogue ----
  {
    GemmP p{}; p.A = mtan; p.Bt = w2T; p.ldk = 64; p.kIters = 1;
    p.aStr = (size_t)BT_ * 64; p.bStr = (size_t)2048 * 64; p.oStr = (size_t)BT_ * C_;
    p.ob = xmix0; p.xh = xh; p.xxh = xxh;
    p.vArr[0] = maa_w; p.vArr[1] = maa_k; p.vArr[2] = maa_v; p.vArr[3] = maa_r; p.vArr[4] = maa_g;
    gemm_k<7><<<dim3(16, 16, 5), tb, 0, stream>>>(p);
  }

  // ---- r,k,v,g: batched-4 256^2 swizzled GEMMs, bf16 output ----
  {
    G256P p{}; p.Bt = WT0; p.ldk = 2048; p.nkt = 32; p.kSplit = 1;
    p.bStr = (size_t)2048 * 2048; p.oStr = (size_t)BT_ * C_; p.ob = rB;
    p.aArr[0] = xmix0 + (size_t)3 * BT_ * C_;  // xr
    p.aArr[1] = xmix0 + (size_t)1 * BT_ * C_;  // xk
    p.aArr[2] = xmix0 + (size_t)2 * BT_ * C_;  // xv
    p.aArr[3] = xmix0 + (size_t)4 * BT_ * C_;  // xg
    gemm256<1><<<dim3(8, 8, 4), dim3(512), 131072, stream>>>(p);
  }

  // ---- w-path: split-K thin GEMM (xw @ td_w1), 16 chunks, bf16 partials ----
  {
    GemmP p{}; p.A = xmix0; p.Bt = tw1T; p.ldk = 2048; p.kIters = 2; p.kChunk = 128;
    p.ldo = 128; p.pStride = (size_t)BT_ * 128; p.ob = part3;
    gemm_k<6><<<dim3(1, 16, 16), tb, 0, stream>>>(p);
  }
  redk_tanh<1, 16><<<dim3(BT_ * 64 / 256), tb, 0, stream>>>(part3, (size_t)BT_ * 128, 128, 64, wtan);

  // ---- w-path: wbuf = lw = -exp(tdec + wtan @ td_w2)  (fused, f32) ----
  {
    GemmP p{}; p.A = wtan; p.Bt = tw2T; p.ldk = 64; p.kIters = 1;
    p.of = wbuf; p.ldo = 2048; p.vArr[0] = tdec;
    gemm_k<4><<<dim3(16, 16, 1), tb, 0, stream>>>(p);
  }

  // ---- chunked WKV6 (L=32) + fused GroupNorm*silu ----
  wkv_a32<<<dim3(2048), tb, 0, stream>>>(rB, kB, vB, wbuf, u, rB, yB, Ubuf, Gbuf);
  wkv_b32<<<dim3(256),  tb, 0, stream>>>(Ubuf, Gbuf, Sbuf);
  wkv_c32<<<dim3(2048), tb, 0, stream>>>(rB, Sbuf, yB, gB, lng, lnb, ygb);

  // ---- out = yg @ Wo  (256^2 frozen schedule, K-split 4, bf16 partials) ----
  {
    G256P p{}; p.Bt = WT0 + (size_t)4 * 2048 * 2048; p.ldk = 2048;
    p.nkt = 8; p.kSplit = 4;
    p.bStr = 0; p.oStr = (size_t)2048 * 2048; p.ob = partW;
    p.aArr[0] = ygb;
    gemm256<1><<<dim3(8, 8, 4), dim3(512), 131072, stream>>>(p);
  }
  redk_sum4<<<dim3(4096), tb, 0, stream>>>(partW, out);
}

// Round 16
// 273.614 us; speedup vs baseline: 1.1925x; 1.0005x over previous
//
#include <hip/hip_runtime.h>
#include <cstdint>
#include <cstddef>

// Problem constants (fixed by the reference)
#define B_  2
#define T_  1024
#define C_  2048
#define H_  32
#define BT_ (B_*T_)
static constexpr float EPS_GN = 1e-5f * 64.0f;

using short8 = __attribute__((ext_vector_type(8))) short;
using f32x4  = __attribute__((ext_vector_type(4))) float;
typedef unsigned short bfu16;

__device__ __forceinline__ bfu16 f2b(float f) {
  uint32_t x = __float_as_uint(f);
  uint32_t r = (x + 0x7FFFu + ((x >> 16) & 1u)) >> 16;
  return (bfu16)r;
}
__device__ __forceinline__ float b2f(bfu16 h) {
  return __uint_as_float(((uint32_t)h) << 16);
}
__device__ __forceinline__ float b2fu(uint32_t w) {   // low half of packed
  return __uint_as_float(w << 16);
}

__device__ __forceinline__ void gload16(const bfu16* g, bfu16* l) {
  __builtin_amdgcn_global_load_lds((__attribute__((address_space(1))) void*)g,
                                   (__attribute__((address_space(3))) void*)l,
                                   16, 0, 0);
}

// ---------------------------------------------------------------------------
// gemm256 (round-7 proven schedule, FROZEN): 256x256 tile, BK=64, 512 thr
// (8 waves 2Mx4N), dbuf LDS 128KB. STAGE_A(next); vmcnt(4); barrier; per-ks
// {STAGE_B(next) at ks==1; ds_read frags; MFMA}; barrier.
// LDS XOR-swizzle: source col ^((row&7)<<3), read col ^((lane&7)<<3).
// XCD-aware bijective block swizzle (nwg % 8 == 0 required).
// OB=0: f32 output (p.of). OB=1: bf16 output (p.ob).
// ---------------------------------------------------------------------------
struct G256P {
  const bfu16* Bt; float* of; bfu16* ob;
  size_t bStr, oStr;
  int ldk, nkt, kSplit;
  const bfu16* aArr[4];
};

template<int OB>
__global__ __launch_bounds__(512, 2)
void gemm256(G256P p)
{
  extern __shared__ __align__(16) bfu16 sm[];   // A0,A1,B0,B1 each 256*64
  const int tid  = threadIdx.x;
  const int nwg = gridDim.x * gridDim.y * gridDim.z;
  int lin = blockIdx.x + gridDim.x * (blockIdx.y + gridDim.y * blockIdx.z);
  lin = (lin & 7) * (nwg >> 3) + (lin >> 3);
  const int bx = lin % gridDim.x;
  const int by = (lin / gridDim.x) % gridDim.y;
  const int z  = lin / (gridDim.x * gridDim.y);
  const int m0   = by * 256, n0 = bx * 256;
  const int lane = tid & 63;
  const int wv   = tid >> 6;
  const int wm   = wv >> 2, wn = wv & 3;
  const int ldk  = p.ldk;

  const bfu16* A;
  size_t koff;
  if (p.kSplit > 1) { A = p.aArr[0]; koff = (size_t)z * p.nkt * 64; }
  else              { A = p.aArr[z]; koff = 0; }
  const bfu16* Bt = p.Bt + (size_t)z * p.bStr;

  const int srow = tid >> 3;        // 0..63
  const int scol = (tid & 7) * 8;   // 0..56
  const int sswz = (srow & 7) << 3; // source-side inverse swizzle
  const bfu16* gA = A  + (size_t)(m0 + srow) * ldk + koff + (scol ^ sswz);
  const bfu16* gB = Bt + (size_t)(n0 + srow) * ldk + koff + (scol ^ sswz);

  auto STAGE_A = [&](bfu16* dst, int kt) {
    const bfu16* g = gA + (size_t)kt * 64;
    bfu16* l = dst + srow * 64 + scol;
#pragma unroll
    for (int it = 0; it < 4; ++it)
      gload16(g + (size_t)it * 64 * ldk, l + it * 4096);
  };
  auto STAGE_B = [&](bfu16* dst, int kt) {
    const bfu16* g = gB + (size_t)kt * 64;
    bfu16* l = dst + srow * 64 + scol;
#pragma unroll
    for (int it = 0; it < 4; ++it)
      gload16(g + (size_t)it * 64 * ldk, l + it * 4096);
  };

  f32x4 acc[8][4];
  const f32x4 zero = {0.f, 0.f, 0.f, 0.f};
#pragma unroll
  for (int i = 0; i < 8; ++i)
#pragma unroll
    for (int j = 0; j < 4; ++j) acc[i][j] = zero;

  STAGE_A(sm, 0);
  STAGE_B(sm + 32768, 0);           // 8 outstanding

  const int rswz = (lane & 7) << 3; // read-side swizzle

  for (int kt = 0; kt < p.nkt; ++kt) {
    bfu16* curA = sm + (kt & 1) * 16384;
    bfu16* curB = sm + 32768 + (kt & 1) * 16384;
    bfu16* nxtA = sm + ((kt & 1) ^ 1) * 16384;
    bfu16* nxtB = sm + 32768 + ((kt & 1) ^ 1) * 16384;
    const bool more = (kt + 1 < p.nkt);
    if (more) {
      STAGE_A(nxtA, kt + 1);                       // 12 outstanding
      asm volatile("s_waitcnt vmcnt(4)" ::: "memory");  // cur buf landed
    } else {
      asm volatile("s_waitcnt vmcnt(0)" ::: "memory");
    }
    __builtin_amdgcn_s_barrier();

#pragma unroll
    for (int ks = 0; ks < 2; ++ks) {
      if (ks == 1 && more) STAGE_B(nxtB, kt + 1);
      const int ko = (ks * 32 + (lane >> 4) * 8) ^ rswz;
      short8 a[8], b[4];
#pragma unroll
      for (int i = 0; i < 8; ++i)
        a[i] = *(const short8*)(curA + (wm * 128 + i * 16 + (lane & 15)) * 64 + ko);
#pragma unroll
      for (int j = 0; j < 4; ++j)
        b[j] = *(const short8*)(curB + (wn * 64 + j * 16 + (lane & 15)) * 64 + ko);
      __builtin_amdgcn_s_setprio(1);
#pragma unroll
      for (int i = 0; i < 8; ++i)
#pragma unroll
        for (int j = 0; j < 4; ++j)
          acc[i][j] = __builtin_amdgcn_mfma_f32_16x16x32_bf16(a[i], b[j], acc[i][j], 0, 0, 0);
      __builtin_amdgcn_s_setprio(0);
    }
    __builtin_amdgcn_s_barrier();
  }

  const int cb = n0 + wn * 64 + (lane & 15);
  const int rb = m0 + wm * 128 + ((lane >> 4) << 2);
  if constexpr (OB == 0) {
    float* o = p.of + (size_t)z * p.oStr;
#pragma unroll
    for (int i = 0; i < 8; ++i)
#pragma unroll
      for (int j = 0; j < 4; ++j) {
        int col = cb + j * 16;
#pragma unroll
        for (int q = 0; q < 4; ++q)
          o[(size_t)(rb + i * 16 + q) * 2048 + col] = acc[i][j][q];
      }
  } else {
    bfu16* o = p.ob + (size_t)z * p.oStr;
#pragma unroll
    for (int i = 0; i < 8; ++i)
#pragma unroll
      for (int j = 0; j < 4; ++j) {
        int col = cb + j * 16;
#pragma unroll
        for (int q = 0; q < 4; ++q)
          o[(size_t)(rb + i * 16 + q) * 2048 + col] = f2b(acc[i][j][q]);
      }
  }
}

// ---------------------------------------------------------------------------
// 128x128 GEMM for the small/odd shapes.
// MODE 4: of = -exp(vArr[0][col] + acc)   (fused lw = -exp(w))
// MODE 6: split-K bf16 partials
// MODE 7: batched-5 token-mix epilogue (x and xx both bf16)
// ---------------------------------------------------------------------------
struct GemmP {
  const bfu16* A; const bfu16* Bt;
  float* of; bfu16* ob;
  const bfu16* xh; const bfu16* xxh;
  int ldk, kIters, kChunk, ldo;
  size_t pStride, aStr, bStr, oStr;
  const float* vArr[5];
};

template<int MODE>
__global__ __launch_bounds__(256)
void gemm_k(GemmP p)
{
  __shared__ alignas(16) bfu16 As[128*64];
  __shared__ alignas(16) bfu16 Bs[128*64];
  const int tid  = threadIdx.x;
  const int z    = blockIdx.z;
  const int m0   = blockIdx.y * 128, n0 = blockIdx.x * 128;
  const int lane = tid & 63;
  const int wv   = tid >> 6;
  const int wr   = (wv >> 1) * 64, wc = (wv & 1) * 64;

  const bfu16* A  = p.A;
  const bfu16* Bt = p.Bt;
  size_t koff = 0;
  if constexpr (MODE == 7) { A += (size_t)z * p.aStr; Bt += (size_t)z * p.bStr; }
  if constexpr (MODE == 6) { koff = (size_t)z * p.kChunk; }

  f32x4 acc[4][4];
  const f32x4 zero = {0.f, 0.f, 0.f, 0.f};
#pragma unroll
  for (int i = 0; i < 4; ++i)
#pragma unroll
    for (int j = 0; j < 4; ++j) acc[i][j] = zero;

  const int srow = tid >> 3;
  const int scol = (tid & 7) * 8;
  const int ldk  = p.ldk;

  for (int kb = 0; kb < p.kIters; ++kb) {
    const bfu16* ga = A  + (size_t)m0 * ldk + koff + kb * 64;
    const bfu16* gb = Bt + (size_t)n0 * ldk + koff + kb * 64;
#pragma unroll
    for (int it = 0; it < 4; ++it) {
      int r = it * 32 + srow;
      gload16(ga + (size_t)r * ldk + scol, As + r * 64 + scol);
      gload16(gb + (size_t)r * ldk + scol, Bs + r * 64 + scol);
    }
    __syncthreads();
#pragma unroll
    for (int kk = 0; kk < 2; ++kk) {
      const int ko = kk * 32 + (lane >> 4) * 8;
      short8 a[4], b[4];
#pragma unroll
      for (int i = 0; i < 4; ++i)
        a[i] = *(const short8*)(As + (wr + i * 16 + (lane & 15)) * 64 + ko);
#pragma unroll
      for (int j = 0; j < 4; ++j)
        b[j] = *(const short8*)(Bs + (wc + j * 16 + (lane & 15)) * 64 + ko);
#pragma unroll
      for (int i = 0; i < 4; ++i)
#pragma unroll
        for (int j = 0; j < 4; ++j)
          acc[i][j] = __builtin_amdgcn_mfma_f32_16x16x32_bf16(a[i], b[j], acc[i][j], 0, 0, 0);
    }
    __syncthreads();
  }

  const int cb = n0 + wc + (lane & 15);
  const int rb = m0 + wr + ((lane >> 4) << 2);
#pragma unroll
  for (int i = 0; i < 4; ++i) {
#pragma unroll
    for (int j = 0; j < 4; ++j) {
      int col = cb + j * 16;
#pragma unroll
      for (int q = 0; q < 4; ++q) {
        int row = rb + i * 16 + q;
        float v = acc[i][j][q];
        if constexpr (MODE == 4) {
          p.of[(size_t)row * p.ldo + col] = -__expf(p.vArr[0][col] + v);
        } else if constexpr (MODE == 6) {
          p.ob[(size_t)z * p.pStride + (size_t)row * p.ldo + col] = f2b(v);
        } else if constexpr (MODE == 7) {
          size_t idx = (size_t)row * C_ + col;
          (p.ob + (size_t)z * p.oStr)[idx] =
              f2b(b2f(p.xh[idx]) + b2f(p.xxh[idx]) * (p.vArr[z][col] + v));
        }
      }
    }
  }
}

// ---------------------------------------------------------------------------
// split-K reduce (bf16 partials) + tanh -> bf16.
// OUT=0: mtan scatter [f][row][d]; OUT=1: wtan.  NS = K-chunk count.
// ---------------------------------------------------------------------------
template<int OUT, int NS>
__global__ __launch_bounds__(256)
void redk_tanh(const bfu16* __restrict__ part, size_t pStr, int ldo, int ncols,
               bfu16* __restrict__ out)
{
  int id = blockIdx.x * 256 + threadIdx.x;
  int row = id / ncols, col = id % ncols;
  if (row >= BT_) return;
  float v = 0.f;
#pragma unroll
  for (int s = 0; s < NS; ++s) v += b2f(part[(size_t)s * pStr + (size_t)row * ldo + col]);
  bfu16 tv = f2b(tanhf(v));
  if constexpr (OUT == 0)
    out[((size_t)(col >> 5) * BT_ + row) * 64 + (col & 31)] = tv;
  else
    out[(size_t)row * 64 + col] = tv;
}

// sum of 4 bf16 partial planes -> f32 out
__global__ __launch_bounds__(256)
void redk_sum4(const bfu16* __restrict__ p0, float* __restrict__ out)
{
  size_t i = ((size_t)blockIdx.x * 256 + threadIdx.x) * 4;
  const size_t str = (size_t)2048 * 2048;
  uint2 a = *(const uint2*)(p0 + i);
  uint2 b = *(const uint2*)(p0 + str + i);
  uint2 c = *(const uint2*)(p0 + 2 * str + i);
  uint2 d = *(const uint2*)(p0 + 3 * str + i);
  float4 r;
  r.x = b2fu(a.x & 0xffffu) + b2fu(b.x & 0xffffu) + b2fu(c.x & 0xffffu) + b2fu(d.x & 0xffffu);
  r.y = b2fu(a.x >> 16)     + b2fu(b.x >> 16)     + b2fu(c.x >> 16)     + b2fu(d.x >> 16);
  r.z = b2fu(a.y & 0xffffu) + b2fu(b.y & 0xffffu) + b2fu(c.y & 0xffffu) + b2fu(d.y & 0xffffu);
  r.w = b2fu(a.y >> 16)     + b2fu(b.y >> 16)     + b2fu(c.y >> 16)     + b2fu(d.y >> 16);
  *(float4*)(out + i) = r;
}

// ---------------------------------------------------------------------------
// All weight transposes (13 jobs) + prep_xx (blocks >= prepStart) in ONE
// launch. Transpose: f32 [R][Cc] -> bf16 dst[c*ldd+r], rows [R,Rpad) zeroed.
// Write phase vectorized: each thread packs rows (r, r+1) into one u32
// (all jobs have even Rpad and 32-aligned r0; pad rows written as zeros).
// Prep: xx = shift(x)-x (bf16); xxx = bf16(x+xx*maa_x); xh = bf16(x).
// ---------------------------------------------------------------------------
struct TrJob { const float* src; bfu16* dst; int R, Cc, Rpad, ldd, gx, start; };
struct TrAllP {
  TrJob j[13];
  const float* x; const float* maa_x;
  bfu16* xxh; bfu16* xxx; bfu16* xh;
  int prepStart;
};

__global__ __launch_bounds__(256)
void transpose_all(TrAllP p)
{
  __shared__ float tile[32][33];
  const int bid = blockIdx.x;
  if (bid >= p.prepStart) {
    size_t i = ((size_t)(bid - p.prepStart) * 256 + threadIdx.x) * 4;
    int c  = (int)(i & (C_ - 1));
    int bt = (int)(i >> 11);
    int t  = bt & (T_ - 1);
    float4 xv = *(const float4*)(p.x + i);
    float4 xp = {0.f, 0.f, 0.f, 0.f};
    if (t > 0) xp = *(const float4*)(p.x + i - C_);
    float4 mx = *(const float4*)(p.maa_x + c);
    float dx = xp.x - xv.x, dy = xp.y - xv.y, dz = xp.z - xv.z, dw = xp.w - xv.w;
    uint2 w0;
    w0.x = (uint32_t)f2b(dx) | ((uint32_t)f2b(dy) << 16);
    w0.y = (uint32_t)f2b(dz) | ((uint32_t)f2b(dw) << 16);
    *(uint2*)(p.xxh + i) = w0;
    uint2 w1;
    w1.x = (uint32_t)f2b(xv.x + dx * mx.x) | ((uint32_t)f2b(xv.y + dy * mx.y) << 16);
    w1.y = (uint32_t)f2b(xv.z + dz * mx.z) | ((uint32_t)f2b(xv.w + dw * mx.w) << 16);
    *(uint2*)(p.xxx + i) = w1;
    uint2 w2;
    w2.x = (uint32_t)f2b(xv.x) | ((uint32_t)f2b(xv.y) << 16);
    w2.y = (uint32_t)f2b(xv.z) | ((uint32_t)f2b(xv.w) << 16);
    *(uint2*)(p.xh + i) = w2;
    return;
  }
  int k = 0;
#pragma unroll
  for (int t = 1; t < 13; ++t) if (bid >= p.j[t].start) k = t;
  const TrJob jb = p.j[k];
  const int local = bid - jb.start;
  const int bx = local % jb.gx, by = local / jb.gx;
  const int tx = threadIdx.x & 31, ty = threadIdx.x >> 5;
  const int r0 = by * 32, c0 = bx * 32;
#pragma unroll
  for (int i = 0; i < 4; ++i) {
    int r = r0 + ty + i * 8, c = c0 + tx;
    tile[ty + i * 8][tx] = (r < jb.R && c < jb.Cc) ? jb.src[(size_t)r * jb.Cc + c] : 0.f;
  }
  __syncthreads();
  const int cl  = threadIdx.x >> 4;        // 0..15
  const int rp2 = (threadIdx.x & 15) * 2;  // 0,2,..,30
#pragma unroll
  for (int pass = 0; pass < 2; ++pass) {
    int c = c0 + cl + pass * 16;
    int r = r0 + rp2;
    if (c < jb.Cc && r < jb.Rpad) {
      uint32_t val = (uint32_t)f2b(tile[rp2][cl + pass * 16])
                   | ((uint32_t)f2b(tile[rp2 + 1][cl + pass * 16]) << 16);
      *(uint32_t*)(jb.dst + (size_t)c * jb.ldd + r) = val;
    }
  }
}

// ---------------------------------------------------------------------------
// WKV6 chunked scan, chunk L=32. w input is ALREADY lw = -exp(w) (f32).
// r,k,v inputs bf16; rp (r') and y_intra outputs bf16; U bf16.
// ---------------------------------------------------------------------------
#define S32 68   // LDS row stride (floats) for 32-row tiles

__global__ __launch_bounds__(256)
void wkv_a32(const bfu16* __restrict__ r, const bfu16* __restrict__ k,
             const bfu16* __restrict__ v, const float* __restrict__ w,
             const float* __restrict__ u, bfu16* __restrict__ rp,
             bfu16* __restrict__ y, bfu16* __restrict__ U, float* __restrict__ G)
{
  __shared__ float rw[32 * S32];
  __shared__ float kk[32 * S32];
  __shared__ float vv[32 * S32];
  __shared__ float Ps[32 * S32];
  __shared__ float red[256];
  __shared__ float diag[32];
  __shared__ float Gl[64];

  const int blk = blockIdx.x;
  const int bh = blk >> 5, c = blk & 31;
  const int b = bh >> 5, h = bh & 31;
  const int tid = threadIdx.x;
  const size_t gbase = ((size_t)(b * T_ + c * 32)) * C_ + h * 64;

  {
    const int t = tid >> 3, q = tid & 7;
    const size_t g = gbase + (size_t)t * C_ + q * 8;
    const int l = t * S32 + q * 8;
    uint4 rv4 = *(const uint4*)(r + g);
    rw[l+0] = b2fu(rv4.x & 0xffffu); rw[l+1] = b2fu(rv4.x >> 16);
    rw[l+2] = b2fu(rv4.y & 0xffffu); rw[l+3] = b2fu(rv4.y >> 16);
    rw[l+4] = b2fu(rv4.z & 0xffffu); rw[l+5] = b2fu(rv4.z >> 16);
    rw[l+6] = b2fu(rv4.w & 0xffffu); rw[l+7] = b2fu(rv4.w >> 16);
    uint4 kv4 = *(const uint4*)(k + g);
    kk[l+0] = b2fu(kv4.x & 0xffffu); kk[l+1] = b2fu(kv4.x >> 16);
    kk[l+2] = b2fu(kv4.y & 0xffffu); kk[l+3] = b2fu(kv4.y >> 16);
    kk[l+4] = b2fu(kv4.z & 0xffffu); kk[l+5] = b2fu(kv4.z >> 16);
    kk[l+6] = b2fu(kv4.w & 0xffffu); kk[l+7] = b2fu(kv4.w >> 16);
    uint4 vv4 = *(const uint4*)(v + g);
    vv[l+0] = b2fu(vv4.x & 0xffffu); vv[l+1] = b2fu(vv4.x >> 16);
    vv[l+2] = b2fu(vv4.y & 0xffffu); vv[l+3] = b2fu(vv4.y >> 16);
    vv[l+4] = b2fu(vv4.z & 0xffffu); vv[l+5] = b2fu(vv4.z >> 16);
    vv[l+6] = b2fu(vv4.w & 0xffffu); vv[l+7] = b2fu(vv4.w >> 16);
    *(float4*)(Ps + l)     = *(const float4*)(w + g);
    *(float4*)(Ps + l + 4) = *(const float4*)(w + g + 4);
  }
  __syncthreads();

  // segmented prefix over t (4 segments of 8), per-j
  {
    const int seg = tid >> 6, j = tid & 63;
    float loc = 0.f;
#pragma unroll
    for (int tt = 0; tt < 8; ++tt) loc += Ps[(seg * 8 + tt) * S32 + j];
    red[seg * 64 + j] = loc;
  }
  __syncthreads();
  {
    const int seg = tid >> 6, j = tid & 63;
    float cs = 0.f;
    for (int s = 0; s < seg; ++s) cs += red[s * 64 + j];
    const float uj = u[h * 64 + j];
#pragma unroll
    for (int tt = 0; tt < 8; ++tt) {
      const int a = (seg * 8 + tt) * S32 + j;
      float lw = Ps[a];
      float rv = rw[a] * __expf(cs);
      rw[a] = rv;
      cs += lw;
      float kv = kk[a] * __expf(-cs);
      kk[a] = kv;
      Ps[a] = rv * kv * uj * __expf(lw);   // D (exact)
    }
    if (seg == 3) {
      float Gj = __expf(cs);
      Gl[j] = Gj;
      G[((size_t)bh * 32 + c) * 64 + j] = Gj;
    }
  }
  __syncthreads();

  // diag[t] = sum_j D[t][j]
  {
    const int t = tid & 31, q = tid >> 5;
    float s = 0.f;
#pragma unroll
    for (int jj = 0; jj < 8; ++jj) s += Ps[t * S32 + q * 8 + jj];
    red[q * 32 + t] = s;
  }
  __syncthreads();
  if (tid < 32) {
    float d = 0.f;
#pragma unroll
    for (int q = 0; q < 8; ++q) d += red[q * 32 + tid];
    diag[tid] = d;
  }
  __syncthreads();

  // scores: 2x2 tiles over 16x16 thread grid, lower-tri
  {
    const int tq = tid >> 4, sq = tid & 15;
    float a00 = 0.f, a01 = 0.f, a10 = 0.f, a11 = 0.f;
    if (sq <= tq) {
      for (int j = 0; j < 64; j += 4) {
        float4 r0 = *(const float4*)(rw + (2 * tq + 0) * S32 + j);
        float4 r1 = *(const float4*)(rw + (2 * tq + 1) * S32 + j);
        float4 k0 = *(const float4*)(kk + (2 * sq + 0) * S32 + j);
        float4 k1 = *(const float4*)(kk + (2 * sq + 1) * S32 + j);
        a00 += r0.x * k0.x + r0.y * k0.y + r0.z * k0.z + r0.w * k0.w;
        a01 += r0.x * k1.x + r0.y * k1.y + r0.z * k1.z + r0.w * k1.w;
        a10 += r1.x * k0.x + r1.y * k0.y + r1.z * k0.z + r1.w * k0.w;
        a11 += r1.x * k1.x + r1.y * k1.y + r1.z * k1.z + r1.w * k1.w;
      }
    }
    __syncthreads();
    if (sq <= tq) {
      const float av[2][2] = {{a00, a01}, {a10, a11}};
#pragma unroll
      for (int tt = 0; tt < 2; ++tt)
#pragma unroll
        for (int ss = 0; ss < 2; ++ss) {
          int t = 2 * tq + tt, s = 2 * sq + ss;
          Ps[t * S32 + s] = (s < t) ? av[tt][ss] : (s == t ? diag[t] : 0.f);
        }
    }
  }
  __syncthreads();

  // O_intra[t][i] = sum_{s<=t} P[t][s] * v[s][i]  -> y (bf16)
  {
    const int tq = tid >> 4, iq = tid & 15;
    float o0[4] = {0.f, 0.f, 0.f, 0.f}, o1[4] = {0.f, 0.f, 0.f, 0.f};
    const int tmax = 2 * tq + 1;
    for (int s = 0; s <= tmax; ++s) {
      float4 vx = *(const float4*)(vv + s * S32 + iq * 4);
      float p0 = Ps[(2 * tq + 0) * S32 + s];
      float p1 = Ps[(2 * tq + 1) * S32 + s];
      o0[0] += p0 * vx.x; o0[1] += p0 * vx.y; o0[2] += p0 * vx.z; o0[3] += p0 * vx.w;
      o1[0] += p1 * vx.x; o1[1] += p1 * vx.y; o1[2] += p1 * vx.z; o1[3] += p1 * vx.w;
    }
    uint2 y0, y1;
    y0.x = (uint32_t)f2b(o0[0]) | ((uint32_t)f2b(o0[1]) << 16);
    y0.y = (uint32_t)f2b(o0[2]) | ((uint32_t)f2b(o0[3]) << 16);
    y1.x = (uint32_t)f2b(o1[0]) | ((uint32_t)f2b(o1[1]) << 16);
    y1.y = (uint32_t)f2b(o1[2]) | ((uint32_t)f2b(o1[3]) << 16);
    *(uint2*)(y + gbase + (size_t)(2 * tq + 0) * C_ + iq * 4) = y0;
    *(uint2*)(y + gbase + (size_t)(2 * tq + 1) * C_ + iq * 4) = y1;
  }

  // U[j][i] = G[j] * sum_s k~[s][j] * v[s][i]  (stored bf16)
  {
    const int jq = tid >> 4, iq = tid & 15;
    float ua[4][4] = {{0.f}};
    for (int s = 0; s < 32; ++s) {
      float4 kx = *(const float4*)(kk + s * S32 + jq * 4);
      float4 vx = *(const float4*)(vv + s * S32 + iq * 4);
      ua[0][0] += kx.x * vx.x; ua[0][1] += kx.x * vx.y; ua[0][2] += kx.x * vx.z; ua[0][3] += kx.x * vx.w;
      ua[1][0] += kx.y * vx.x; ua[1][1] += kx.y * vx.y; ua[1][2] += kx.y * vx.z; ua[1][3] += kx.y * vx.w;
      ua[2][0] += kx.z * vx.x; ua[2][1] += kx.z * vx.y; ua[2][2] += kx.z * vx.z; ua[2][3] += kx.z * vx.w;
      ua[3][0] += kx.w * vx.x; ua[3][1] += kx.w * vx.y; ua[3][2] += kx.w * vx.z; ua[3][3] += kx.w * vx.w;
    }
    const size_t ub = ((size_t)bh * 32 + c) * 4096;
#pragma unroll
    for (int jj = 0; jj < 4; ++jj) {
      float g = Gl[jq * 4 + jj];
      uint2 uvp;
      uvp.x = (uint32_t)f2b(ua[jj][0] * g) | ((uint32_t)f2b(ua[jj][1] * g) << 16);
      uvp.y = (uint32_t)f2b(ua[jj][2] * g) | ((uint32_t)f2b(ua[jj][3] * g) << 16);
      *(uint2*)(U + ub + (size_t)(jq * 4 + jj) * 64 + iq * 4) = uvp;
    }
  }

  // write r' back bf16 (in-place over r; own rows only)
  {
    const int t = tid >> 3, q = tid & 7;
    const size_t g = gbase + (size_t)t * C_ + q * 8;
    const int l = t * S32 + q * 8;
    uint4 rp4;
    rp4.x = (uint32_t)f2b(rw[l+0]) | ((uint32_t)f2b(rw[l+1]) << 16);
    rp4.y = (uint32_t)f2b(rw[l+2]) | ((uint32_t)f2b(rw[l+3]) << 16);
    rp4.z = (uint32_t)f2b(rw[l+4]) | ((uint32_t)f2b(rw[l+5]) << 16);
    rp4.w = (uint32_t)f2b(rw[l+6]) | ((uint32_t)f2b(rw[l+7]) << 16);
    *(uint4*)(rp + g) = rp4;
  }
}

// ---------------------------------------------------------------------------
// State scan: S_{c+1} = G_c*S_c + U_c. 256 blocks (bh x j-quarter), f32
// accumulation in registers; U read bf16, S written bf16.
// ---------------------------------------------------------------------------
__global__ __launch_bounds__(256)
void wkv_b32(const bfu16* __restrict__ U, const float* __restrict__ G,
             bfu16* __restrict__ Sbuf)
{
  const int bh = blockIdx.x >> 2, jq = blockIdx.x & 3;
  const int tid = threadIdx.x;
  const int j = jq * 16 + (tid >> 4);
  const int i = (tid & 15) * 4;
  float4 S = {0.f, 0.f, 0.f, 0.f};
  for (int c = 0; c < 32; ++c) {
    const size_t cb = ((size_t)bh * 32 + c);
    float g = G[cb * 64 + j];
    const size_t idx = cb * 4096 + (size_t)j * 64 + i;
    uint2 sp;
    sp.x = (uint32_t)f2b(S.x) | ((uint32_t)f2b(S.y) << 16);
    sp.y = (uint32_t)f2b(S.z) | ((uint32_t)f2b(S.w) << 16);
    *(uint2*)(Sbuf + idx) = sp;
    uint2 uv = *(const uint2*)(U + idx);
    S.x = g * S.x + b2fu(uv.x & 0xffffu);
    S.y = g * S.y + b2fu(uv.x >> 16);
    S.z = g * S.z + b2fu(uv.y & 0xffffu);
    S.w = g * S.w + b2fu(uv.y >> 16);
  }
}

// ---------------------------------------------------------------------------
// Phase C + fused GroupNorm*silu(g) -> bf16 ygb.
// S, rp, y, gpre all read bf16.
// ---------------------------------------------------------------------------
__global__ __launch_bounds__(256)
void wkv_c32(const bfu16* __restrict__ rp, const bfu16* __restrict__ Sbuf,
             const bfu16* __restrict__ y, const bfu16* __restrict__ gpre,
             const float* __restrict__ lng, const float* __restrict__ lnb,
             bfu16* __restrict__ yg)
{
  __shared__ float Sl[64 * S32];
  __shared__ float rl[32 * S32];
  const int blk = blockIdx.x;
  const int bh = blk >> 5, c = blk & 31;
  const int b = bh >> 5, h = bh & 31;
  const int tid = threadIdx.x;
  const size_t gbase = ((size_t)(b * T_ + c * 32)) * C_ + h * 64;
  {
    const int j = tid >> 2, q = tid & 3;     // S: 64 rows x 64 cols bf16
    const size_t sb = ((size_t)bh * 32 + c) * 4096 + (size_t)j * 64 + q * 16;
    const int l = j * S32 + q * 16;
    uint4 s0 = *(const uint4*)(Sbuf + sb);       // 8 bf16
    uint4 s1 = *(const uint4*)(Sbuf + sb + 8);   // 8 bf16
    Sl[l + 0]  = b2fu(s0.x & 0xffffu); Sl[l + 1]  = b2fu(s0.x >> 16);
    Sl[l + 2]  = b2fu(s0.y & 0xffffu); Sl[l + 3]  = b2fu(s0.y >> 16);
    Sl[l + 4]  = b2fu(s0.z & 0xffffu); Sl[l + 5]  = b2fu(s0.z >> 16);
    Sl[l + 6]  = b2fu(s0.w & 0xffffu); Sl[l + 7]  = b2fu(s0.w >> 16);
    Sl[l + 8]  = b2fu(s1.x & 0xffffu); Sl[l + 9]  = b2fu(s1.x >> 16);
    Sl[l + 10] = b2fu(s1.y & 0xffffu); Sl[l + 11] = b2fu(s1.y >> 16);
    Sl[l + 12] = b2fu(s1.z & 0xffffu); Sl[l + 13] = b2fu(s1.z >> 16);
    Sl[l + 14] = b2fu(s1.w & 0xffffu); Sl[l + 15] = b2fu(s1.w >> 16);
    const int t = tid >> 3, q8 = tid & 7;    // r': 32 rows x 64 cols bf16
    const size_t gr = gbase + (size_t)t * C_ + q8 * 8;
    const int lr = t * S32 + q8 * 8;
    uint4 rv4 = *(const uint4*)(rp + gr);
    rl[lr+0] = b2fu(rv4.x & 0xffffu); rl[lr+1] = b2fu(rv4.x >> 16);
    rl[lr+2] = b2fu(rv4.y & 0xffffu); rl[lr+3] = b2fu(rv4.y >> 16);
    rl[lr+4] = b2fu(rv4.z & 0xffffu); rl[lr+5] = b2fu(rv4.z >> 16);
    rl[lr+6] = b2fu(rv4.w & 0xffffu); rl[lr+7] = b2fu(rv4.w >> 16);
  }
  __syncthreads();
  const int tq = tid >> 4, iq = tid & 15;
  float o0[4] = {0.f, 0.f, 0.f, 0.f}, o1[4] = {0.f, 0.f, 0.f, 0.f};
  for (int j = 0; j < 64; ++j) {
    float4 sv = *(const float4*)(Sl + j * S32 + iq * 4);
    float r0 = rl[(2 * tq + 0) * S32 + j];
    float r1 = rl[(2 * tq + 1) * S32 + j];
    o0[0] += r0 * sv.x; o0[1] += r0 * sv.y; o0[2] += r0 * sv.z; o0[3] += r0 * sv.w;
    o1[0] += r1 * sv.x; o1[1] += r1 * sv.y; o1[2] += r1 * sv.z; o1[3] += r1 * sv.w;
  }
#pragma unroll
  for (int rr = 0; rr < 2; ++rr) {
    float* o = rr ? o1 : o0;
    const size_t rowb = gbase + (size_t)(2 * tq + rr) * C_;
    uint2 yi2 = *(const uint2*)(y + rowb + iq * 4);
    float yv[4] = { b2fu(yi2.x & 0xffffu) + o[0], b2fu(yi2.x >> 16) + o[1],
                    b2fu(yi2.y & 0xffffu) + o[2], b2fu(yi2.y >> 16) + o[3] };
    float s = yv[0] + yv[1] + yv[2] + yv[3];
    float sq = yv[0] * yv[0] + yv[1] * yv[1] + yv[2] * yv[2] + yv[3] * yv[3];
#pragma unroll
    for (int m = 1; m < 16; m <<= 1) {
      s  += __shfl_xor(s, m, 64);
      sq += __shfl_xor(sq, m, 64);
    }
    float mu  = s * (1.f / 64.f);
    float var = sq * (1.f / 64.f) - mu * mu;
    float rs  = rsqrtf(var + EPS_GN);
    uint2 gp2 = *(const uint2*)(gpre + rowb + iq * 4);
    const float gpv[4] = { b2fu(gp2.x & 0xffffu), b2fu(gp2.x >> 16),
                           b2fu(gp2.y & 0xffffu), b2fu(gp2.y >> 16) };
    uint32_t pk[2];
    ushort hw[4];
#pragma unroll
    for (int e = 0; e < 4; ++e) {
      int cidx = h * 64 + iq * 4 + e;
      float yn = (yv[e] - mu) * rs * lng[cidx] + lnb[cidx];
      float gs = gpv[e] / (1.f + __expf(-gpv[e]));
      hw[e] = f2b(yn * gs);
    }
    pk[0] = (uint32_t)hw[0] | ((uint32_t)hw[1] << 16);
    pk[1] = (uint32_t)hw[2] | ((uint32_t)hw[3] << 16);
    *(uint2*)(yg + rowb + iq * 4) = make_uint2(pk[0], pk[1]);
  }
}

// ---------------------------------------------------------------------------
extern "C" void kernel_launch(void* const* d_in, const int* in_sizes, int n_in,
                              void* d_out, int out_size, void* d_ws, size_t ws_size,
                              hipStream_t stream)
{
  const float* x      = (const float*)d_in[0];
  const float* maa_x  = (const float*)d_in[1];
  const float* maa_w  = (const float*)d_in[2];
  const float* maa_k  = (const float*)d_in[3];
  const float* maa_v  = (const float*)d_in[4];
  const float* maa_r  = (const float*)d_in[5];
  const float* maa_g  = (const float*)d_in[6];
  const float* tdec   = (const float*)d_in[7];
  const float* u      = (const float*)d_in[8];
  const float* maa_w1 = (const float*)d_in[9];
  const float* maa_w2 = (const float*)d_in[10];
  const float* td_w1  = (const float*)d_in[11];
  const float* td_w2  = (const float*)d_in[12];
  const float* lng = (const float*)d_in[18];
  const float* lnb = (const float*)d_in[19];
  float* out = (float*)d_out;

  char* wsp = (char*)d_ws;
  auto alloc = [&](size_t bytes) -> char* {
    char* p = wsp;
    wsp += (bytes + 255) & ~(size_t)255;
    return p;
  };

  bfu16* WT0 = (bfu16*)alloc((size_t)5 * 2048 * 2048 * 2);  // WT[z] = WT0 + z*4M
  bfu16* w1T  = (bfu16*)alloc((size_t)256 * 2048 * 2);
  bfu16* tw1T = (bfu16*)alloc((size_t)128 * 2048 * 2);
  bfu16* tw2T = (bfu16*)alloc((size_t)2048 * 64 * 2);
  bfu16* w2T  = (bfu16*)alloc((size_t)5 * 2048 * 64 * 2);
  float* ybuf = (float*)alloc((size_t)BT_ * C_ * 4);
  bfu16* xxh  = (bfu16*)alloc((size_t)BT_ * C_ * 2);
  bfu16* xxx  = (bfu16*)alloc((size_t)BT_ * C_ * 2);
  bfu16* xh   = (bfu16*)alloc((size_t)BT_ * C_ * 2);
  bfu16* mtan = (bfu16*)alloc((size_t)5 * BT_ * 64 * 2);
  bfu16* xmix0 = (bfu16*)alloc((size_t)5 * BT_ * C_ * 2); // xmix[f] = xmix0 + f*BT*C
  float* rbuf = (float*)alloc((size_t)4 * BT_ * C_ * 4);  // alias pool
  float* wbuf = (float*)alloc((size_t)BT_ * C_ * 4);      // lw (f32, precision)
  bfu16* wtan = (bfu16*)alloc((size_t)BT_ * 64 * 2);
  bfu16* Sbuf = (bfu16*)alloc((size_t)64 * 32 * 4096 * 2);  // 16 MB bf16
  float* Gbuf = (float*)alloc((size_t)64 * 32 * 64 * 4);    // 512 KB
  // bf16 r,k,v,g (32 MB) in first half of rbuf pool:
  bfu16* rB = (bfu16*)rbuf;
  bfu16* kB = rB + (size_t)BT_ * C_;
  bfu16* vB = kB + (size_t)BT_ * C_;
  bfu16* gB = vB + (size_t)BT_ * C_;
  // Aliases (dead-by-then, stream-ordered):
  bfu16* ygb  = xxx;
  bfu16* yB   = (bfu16*)ybuf;                   // y_intra bf16 (8 MB of ybuf)
  bfu16* Ubuf = xmix0 + (size_t)1 * BT_ * C_;   // 16MB bf16 over xmix[1..2]
  bfu16* part1 = (bfu16*)rbuf;  // m-path bf16 partials (pre-rkvg GEMM)
  bfu16* part3 = (bfu16*)wbuf;  // w-path bf16 partials (pre-MODE4)
  bfu16* partW = (bfu16*)(rbuf + (size_t)2 * BT_ * C_);  // Wo partials 32MB
                                 // (over v,g + beyond; post-wkv_c, g consumed)

  dim3 tb(256);

  // ---- all weight transposes + prep_xx, one launch ----
  {
    TrAllP p{};
    int s = 0;
    for (int i = 0; i < 5; ++i) {
      p.j[i] = TrJob{ (const float*)d_in[13 + i], WT0 + (size_t)i * 2048 * 2048,
                      2048, 2048, 2048, 2048, 64, s };
      s += 64 * 64;
    }
    p.j[5] = TrJob{ maa_w1, w1T, 2048, 160, 2048, 2048, 5, s };  s += 5 * 64;
    p.j[6] = TrJob{ td_w1, tw1T, 2048, 64, 2048, 2048, 2, s };   s += 2 * 64;
    p.j[7] = TrJob{ td_w2, tw2T, 64, 2048, 64, 64, 64, s };      s += 64 * 2;
    for (int f = 0; f < 5; ++f) {
      p.j[8 + f] = TrJob{ maa_w2 + (size_t)f * 32 * 2048, w2T + (size_t)f * 2048 * 64,
                          32, 2048, 64, 64, 64, s };
      s += 64 * 2;
    }
    p.x = x; p.maa_x = maa_x; p.xxh = xxh; p.xxx = xxx; p.xh = xh;
    p.prepStart = s;
    s += (BT_ * C_ / 4) / 256;   // 4096 prep blocks
    transpose_all<<<dim3(s), tb, 0, stream>>>(p);
  }

  // ---- m-path: split-K GEMM (xxx @ maa_w1), bf16 partials ----
  {
    GemmP p{}; p.A = xxx; p.Bt = w1T; p.ldk = 2048; p.kIters = 4; p.kChunk = 256;
    p.ldo = 256; p.pStride = (size_t)BT_ * 256; p.ob = part1;
    gemm_k<6><<<dim3(2, 16, 8), tb, 0, stream>>>(p);
  }
  redk_tanh<0, 8><<<dim3(BT_ * 160 / 256), tb, 0, stream>>>(part1, (size_t)BT_ * 256, 256, 160, mtan);

  // ---- token-mix: batched-5 (mtan[f] @ w2T[f]) with xh+xxh epilogue ----
  {
    GemmP p{}; p.A = mtan; p.Bt = w2T; p.ldk = 64; p.kIters = 1;
    p.aStr = (size_t)BT_ * 64; p.bStr = (size_t)2048 * 64; p.oStr = (size_t)BT_ * C_;
    p.ob = xmix0; p.xh = xh; p.xxh = xxh;
    p.vArr[0] = maa_w; p.vArr[1] = maa_k; p.vArr[2] = maa_v; p.vArr[3] = maa_r; p.vArr[4] = maa_g;
    gemm_k<7><<<dim3(16, 16, 5), tb, 0, stream>>>(p);
  }

  // ---- r,k,v,g: batched-4 256^2 swizzled GEMMs, bf16 output ----
  {
    G256P p{}; p.Bt = WT0; p.ldk = 2048; p.nkt = 32; p.kSplit = 1;
    p.bStr = (size_t)2048 * 2048; p.oStr = (size_t)BT_ * C_; p.ob = rB;
    p.aArr[0] = xmix0 + (size_t)3 * BT_ * C_;  // xr
    p.aArr[1] = xmix0 + (size_t)1 * BT_ * C_;  // xk
    p.aArr[2] = xmix0 + (size_t)2 * BT_ * C_;  // xv
    p.aArr[3] = xmix0 + (size_t)4 * BT_ * C_;  // xg
    gemm256<1><<<dim3(8, 8, 4), dim3(512), 131072, stream>>>(p);
  }

  // ---- w-path: split-K thin GEMM (xw @ td_w1), 16 chunks, bf16 partials ----
  {
    GemmP p{}; p.A = xmix0; p.Bt = tw1T; p.ldk = 2048; p.kIters = 2; p.kChunk = 128;
    p.ldo = 128; p.pStride = (size_t)BT_ * 128; p.ob = part3;
    gemm_k<6><<<dim3(1, 16, 16), tb, 0, stream>>>(p);
  }
  redk_tanh<1, 16><<<dim3(BT_ * 64 / 256), tb, 0, stream>>>(part3, (size_t)BT_ * 128, 128, 64, wtan);

  // ---- w-path: wbuf = lw = -exp(tdec + wtan @ td_w2)  (fused, f32) ----
  {
    GemmP p{}; p.A = wtan; p.Bt = tw2T; p.ldk = 64; p.kIters = 1;
    p.of = wbuf; p.ldo = 2048; p.vArr[0] = tdec;
    gemm_k<4><<<dim3(16, 16, 1), tb, 0, stream>>>(p);
  }

  // ---- chunked WKV6 (L=32) + fused GroupNorm*silu ----
  wkv_a32<<<dim3(2048), tb, 0, stream>>>(rB, kB, vB, wbuf, u, rB, yB, Ubuf, Gbuf);
  wkv_b32<<<dim3(256),  tb, 0, stream>>>(Ubuf, Gbuf, Sbuf);
  wkv_c32<<<dim3(2048), tb, 0, stream>>>(rB, Sbuf, yB, gB, lng, lnb, ygb);

  // ---- out = yg @ Wo  (256^2 frozen schedule, K-split 4, bf16 partials) ----
  {
    G256P p{}; p.Bt = WT0 + (size_t)4 * 2048 * 2048; p.ldk = 2048;
    p.nkt = 8; p.kSplit = 4;
    p.bStr = 0; p.oStr = (size_t)2048 * 2048; p.ob = partW;
    p.aArr[0] = ygb;
    gemm256<1><<<dim3(8, 8, 4), dim3(512), 131072, stream>>>(p);
  }
  redk_sum4<<<dim3(4096), tb, 0, stream>>>(partW, out);
}